// Round 1
// baseline (1440.248 us; speedup 1.0000x reference)
//
#include <hip/hip_runtime.h>

#define DI __device__ __forceinline__

DI float bf2f(unsigned short u){ unsigned int v = ((unsigned int)u)<<16; float f; __builtin_memcpy(&f,&v,4); return f; }
DI unsigned short f2bf(float f){ unsigned int v; __builtin_memcpy(&v,&f,4); v = v + 0x7FFFu + ((v>>16)&1u); return (unsigned short)(v>>16); }

typedef __attribute__((ext_vector_type(8))) short bf16x8;
typedef __attribute__((ext_vector_type(4))) float f32x4;

// ---------------- generic MFMA GEMM ----------------
// C[M,N] = act(A[M,K] @ B + bias). A: bf16 or f32, row-major lda.
// B f32: BTRANS ? stored as B^T [N,K] row-major (ldb = K-stride) : B [K,N] (ldb).
// ACT: 0 none, 1 relu, 2 tanh. Out bf16 or f32 (ldc). z-offsets in elements.
template<bool ABF16, bool BTRANS, int ACT, bool OBF16>
__global__ __launch_bounds__(256,2) void gemm_k(
    const void* __restrict__ Av, const float* __restrict__ Bp,
    const float* __restrict__ bias, void* __restrict__ Cv,
    int M, int N, int K, int lda, int ldb, int ldc,
    long long azs, long long bzs, long long czs, int bias_zs)
{
  __shared__ bf16x8 As[128*8];
  __shared__ bf16x8 Bs[128*8];
  const int z = blockIdx.z;
  const unsigned short* Ab = (const unsigned short*)Av + (long long)z*azs;
  const float*          Af = (const float*)Av          + (long long)z*azs;
  const float* Bz = Bp + (long long)z*bzs;
  const int tid = threadIdx.x;
  const int lane = tid & 63, wid = tid >> 6;
  const int wm = wid >> 1, wn = wid & 1;
  const long long mBase = (long long)blockIdx.y << 7;
  const long long nBase = (long long)blockIdx.x << 7;

  f32x4 acc[4][4];
#pragma unroll
  for (int i=0;i<4;i++)
#pragma unroll
    for (int j=0;j<4;j++)
#pragma unroll
      for (int r=0;r<4;r++) acc[i][j][r] = 0.f;

  const int nkt = (K + 63) >> 6;
  for (int kt=0; kt<nkt; ++kt) {
    const int k0 = kt << 6;
    // ---- stage A: 128 rows x 8 k-groups of 8 ----
#pragma unroll
    for (int it=0; it<4; ++it) {
      const int gid = tid + (it<<8);
      const int row = gid >> 3, g = gid & 7;
      const int kk = k0 + (g<<3);
      const long long m = mBase + row;
      bf16x8 av;
      if (m < M && kk + 8 <= K) {
        if constexpr (ABF16) {
          av = *(const bf16x8*)(Ab + m*(long long)lda + kk);
        } else {
          const float* p = Af + m*(long long)lda + kk;
          const float4 f0 = *(const float4*)p;
          const float4 f1 = *(const float4*)(p+4);
          av[0]=(short)f2bf(f0.x); av[1]=(short)f2bf(f0.y); av[2]=(short)f2bf(f0.z); av[3]=(short)f2bf(f0.w);
          av[4]=(short)f2bf(f1.x); av[5]=(short)f2bf(f1.y); av[6]=(short)f2bf(f1.z); av[7]=(short)f2bf(f1.w);
        }
      } else {
#pragma unroll
        for (int j=0;j<8;j++) {
          float f = 0.f;
          if (m < M && kk+j < K)
            f = ABF16 ? bf2f(Ab[m*(long long)lda + kk + j]) : Af[m*(long long)lda + kk + j];
          av[j] = (short)f2bf(f);
        }
      }
      As[(row<<3) | (g ^ (row&7))] = av;
    }
    // ---- stage B ----
#pragma unroll
    for (int it=0; it<4; ++it) {
      const int gid = tid + (it<<8);
      bf16x8 bv;
      if constexpr (BTRANS) {
        const int n = gid >> 3, g = gid & 7;
        const int kk = k0 + (g<<3);
        const long long gn = nBase + n;
        if (gn < N && kk + 8 <= K) {
          const float* p = Bz + gn*(long long)ldb + kk;
          const float4 f0 = *(const float4*)p;
          const float4 f1 = *(const float4*)(p+4);
          bv[0]=(short)f2bf(f0.x); bv[1]=(short)f2bf(f0.y); bv[2]=(short)f2bf(f0.z); bv[3]=(short)f2bf(f0.w);
          bv[4]=(short)f2bf(f1.x); bv[5]=(short)f2bf(f1.y); bv[6]=(short)f2bf(f1.z); bv[7]=(short)f2bf(f1.w);
        } else {
#pragma unroll
          for (int j=0;j<8;j++) {
            float f=0.f;
            if (gn < N && kk+j < K) f = Bz[gn*(long long)ldb + kk + j];
            bv[j] = (short)f2bf(f);
          }
        }
        Bs[(n<<3) | (g ^ (n&7))] = bv;
      } else {
        const int n = gid & 127, g = gid >> 7;
        const int kk = k0 + (g<<3);
        const long long gn = nBase + n;
#pragma unroll
        for (int j=0;j<8;j++) {
          float f=0.f;
          if (gn < N && kk+j < K) f = Bz[(long long)(kk+j)*ldb + gn];
          bv[j] = (short)f2bf(f);
        }
        Bs[(n<<3) | (g ^ (n&7))] = bv;
      }
    }
    __syncthreads();
    {
      const int q = lane >> 4, r15 = lane & 15;
#pragma unroll
      for (int ks=0; ks<2; ++ks) {
        bf16x8 af[4], bfr[4];
#pragma unroll
        for (int mi=0;mi<4;mi++){
          const int row = (wm<<6) + (mi<<4) + r15;
          af[mi] = As[(row<<3) | (((ks<<2)+q) ^ (row&7))];
        }
#pragma unroll
        for (int ni=0;ni<4;ni++){
          const int col = (wn<<6) + (ni<<4) + r15;
          bfr[ni] = Bs[(col<<3) | (((ks<<2)+q) ^ (col&7))];
        }
#pragma unroll
        for (int mi=0;mi<4;mi++)
#pragma unroll
          for (int ni=0;ni<4;ni++)
            acc[mi][ni] = __builtin_amdgcn_mfma_f32_16x16x32_bf16(af[mi], bfr[ni], acc[mi][ni], 0, 0, 0);
      }
    }
    __syncthreads();
  }
  // ---- epilogue ----
  const int q = lane >> 4, r15 = lane & 15;
#pragma unroll
  for (int ni=0;ni<4;ni++){
    const long long n = nBase + (wn<<6) + (ni<<4) + r15;
    if (n >= N) continue;
    const float bval = bias ? bias[(long long)z*bias_zs + n] : 0.f;
#pragma unroll
    for (int mi=0;mi<4;mi++){
#pragma unroll
      for (int r=0;r<4;r++){
        const long long m = mBase + (wm<<6) + (mi<<4) + (q<<2) + r;
        if (m >= M) continue;
        float v = acc[mi][ni][r] + bval;
        if constexpr (ACT==1) v = fmaxf(v, 0.f);
        else if constexpr (ACT==2) v = tanhf(v);
        const long long idx = (long long)z*czs + m*(long long)ldc + n;
        if constexpr (OBF16) ((unsigned short*)Cv)[idx] = f2bf(v);
        else                 ((float*)Cv)[idx] = v;
      }
    }
  }
}

// ---------------- bilinear-resize weight generation ----------------
// T1[which][k][c] = sum_i Wd[k,i] * W[c,i], antialiased triangle kernel 10000->256
__global__ __launch_bounds__(256) void t1_k(const float* __restrict__ Ew, const float* __restrict__ Fw,
                                            float* __restrict__ t1)
{
  const int k = blockIdx.x, which = blockIdx.y, c = threadIdx.x;
  const float* W = which ? Fw : Ew;
  const float ksc = 39.0625f;              // 10000/256
  const float inv = 1.f/39.0625f;
  const float sf = (k + 0.5f)*ksc - 0.5f;
  int ilo = (int)ceilf(sf - ksc); if (ilo < 0) ilo = 0;
  int ihi = (int)floorf(sf + ksc); if (ihi > 9999) ihi = 9999;
  float acc = 0.f, wsum = 0.f;
  for (int i=ilo; i<=ihi; ++i) {
    const float w = 1.f - fabsf(sf - (float)i)*inv;
    if (w > 0.f) { acc += w * W[c*10000 + i]; wsum += w; }
  }
  t1[(which*256 + k)*256 + c] = acc / wsum;
}

// red[which][c][j] = sum_n Wu[n,c] * X[n,j]  (2-tap half-pixel upsample 256->16384, transposed)
__global__ __launch_bounds__(512) void red_k(const unsigned short* __restrict__ Kb,
                                             const unsigned short* __restrict__ Vb,
                                             float* __restrict__ red)
{
  const int c = blockIdx.x, which = blockIdx.y, j = threadIdx.x;
  const unsigned short* X = which ? Vb : Kb;
  int nlo = 64*c - 32; if (nlo < 0) nlo = 0;
  int nhi = 64*c + 95; if (nhi > 16383) nhi = 16383;
  float acc = 0.f;
  for (int n=nlo; n<=nhi; ++n) {
    float sf = (n + 0.5f)*0.015625f - 0.5f;
    sf = fminf(fmaxf(sf, 0.f), 255.f);
    const int c0 = (int)sf;
    const float f = sf - (float)c0;
    float w = 0.f;
    if (c == c0) w = 1.f - f;
    else if (c == c0+1) w = f;
    if (w != 0.f) acc += w * bf2f(X[(long long)n*512 + j]);
  }
  red[(which*256 + c)*512 + j] = acc;
}

// kc[which][k][j] = sum_c t1[which][k][c] * red[which][c][j]
__global__ __launch_bounds__(512) void kc_k(const float* __restrict__ t1, const float* __restrict__ red,
                                            float* __restrict__ kc)
{
  const int k = blockIdx.x, which = blockIdx.y, j = threadIdx.x;
  const float* T = t1 + (which*256 + k)*256;
  const float* R = red + which*131072;
  float acc = 0.f;
  for (int c=0; c<256; ++c) acc += T[c] * R[c*512 + j];
  kc[(which*256 + k)*512 + j] = acc;
}

// ---------------- attention softmax (rows of 256) ----------------
__global__ __launch_bounds__(256) void softmax256_k(float* __restrict__ S, float scale)
{
  const int lane = threadIdx.x & 63, wid = threadIdx.x >> 6;
  const long long row = ((long long)blockIdx.x << 2) + wid;
  float4* p = (float4*)(S + (row<<8)) + lane;
  float4 v = *p;
  const float a = v.x*scale, b = v.y*scale, c = v.z*scale, d = v.w*scale;
  float m = fmaxf(fmaxf(a,b), fmaxf(c,d));
#pragma unroll
  for (int o=32;o;o>>=1) m = fmaxf(m, __shfl_xor(m, o, 64));
  const float e0=__expf(a-m), e1=__expf(b-m), e2=__expf(c-m), e3=__expf(d-m);
  float s = e0+e1+e2+e3;
#pragma unroll
  for (int o=32;o;o>>=1) s += __shfl_xor(s, o, 64);
  const float inv = 1.f / s;
  *p = make_float4(e0*inv, e1*inv, e2*inv, e3*inv);
}

// ---------------- double layernorm on (attn_out + feat) ----------------
__global__ __launch_bounds__(256) void ln2_k(
    const unsigned short* __restrict__ x1b, const unsigned short* __restrict__ x2b,
    const float* __restrict__ g1, const float* __restrict__ b1,
    const float* __restrict__ g2, const float* __restrict__ b2,
    unsigned short* __restrict__ out)
{
  __shared__ float sred[8];
  const int tid = threadIdx.x, lane = tid & 63, wid = tid >> 6;
  const long long base = (long long)blockIdx.x << 9;
  const float x0 = bf2f(x1b[base+tid])     + bf2f(x2b[base+tid]);
  const float x1 = bf2f(x1b[base+256+tid]) + bf2f(x2b[base+256+tid]);
  float s = x0+x1, qq = x0*x0 + x1*x1;
#pragma unroll
  for (int o=32;o;o>>=1){ s += __shfl_xor(s,o,64); qq += __shfl_xor(qq,o,64); }
  if (lane==0){ sred[wid]=s; sred[4+wid]=qq; }
  __syncthreads();
  float mean = (sred[0]+sred[1]+sred[2]+sred[3]) * (1.f/512.f);
  float var  = (sred[4]+sred[5]+sred[6]+sred[7]) * (1.f/512.f) - mean*mean;
  float rs = rsqrtf(var + 1e-5f);
  const float y0 = (x0-mean)*rs*g1[tid]     + b1[tid];
  const float y1 = (x1-mean)*rs*g1[tid+256] + b1[tid+256];
  __syncthreads();
  s = y0+y1; qq = y0*y0 + y1*y1;
#pragma unroll
  for (int o=32;o;o>>=1){ s += __shfl_xor(s,o,64); qq += __shfl_xor(qq,o,64); }
  if (lane==0){ sred[wid]=s; sred[4+wid]=qq; }
  __syncthreads();
  mean = (sred[0]+sred[1]+sred[2]+sred[3]) * (1.f/512.f);
  var  = (sred[4]+sred[5]+sred[6]+sred[7]) * (1.f/512.f) - mean*mean;
  rs = rsqrtf(var + 1e-5f);
  out[base+tid]     = f2bf((y0-mean)*rs*g2[tid]     + b2[tid]);
  out[base+256+tid] = f2bf((y1-mean)*rs*g2[tid+256] + b2[tid+256]);
}

// ---------------- weighted column sum (partials) ----------------
__global__ __launch_bounds__(256) void wcolsum_k(const unsigned short* __restrict__ att,
                                                 const float* __restrict__ wts, float* __restrict__ part)
{
  const int c = threadIdx.x;
  const long long r0 = (long long)blockIdx.x * 128;
  float a0=0.f, a1=0.f;
  for (int r=0;r<128;r++){
    const float w = wts ? wts[r0+r] : 1.f;
    const unsigned short* p = att + ((r0+r)<<9);
    a0 += w*bf2f(p[c]); a1 += w*bf2f(p[c+256]);
  }
  part[((long long)blockIdx.x<<9)+c]     = a0;
  part[((long long)blockIdx.x<<9)+c+256] = a1;
}

__global__ __launch_bounds__(512) void colfin_k(const float* __restrict__ part, float* __restrict__ out, float scale)
{
  const int c = threadIdx.x;
  float s = 0.f;
  for (int b=0;b<128;b++) s += part[(b<<9)+c];
  out[c] = s*scale;
}

__global__ __launch_bounds__(64) void gates_k(const float* __restrict__ meanv, const float* __restrict__ gw,
                                              const float* __restrict__ gb, float* __restrict__ gates)
{
  __shared__ float tmp[4];
  const int t = threadIdx.x;
  if (t < 4) {
    float a = gb[t];
    for (int d=0; d<512; ++d) a += meanv[d]*gw[d*4+t];
    tmp[t] = a;
  }
  __syncthreads();
  if (t == 0) {
    const float m = fmaxf(fmaxf(tmp[0],tmp[1]),fmaxf(tmp[2],tmp[3]));
    float e[4]; float s=0.f;
    for (int i=0;i<4;i++){ e[i]=__expf(tmp[i]-m); s+=e[i]; }
    for (int i=0;i<4;i++) gates[i] = e[i]/s;
  }
}

// sc[e][n] = dot(Hm[e,n,:], moe_w2[e,:]) + moe_b2[e]  (one wave per (e,n))
__global__ __launch_bounds__(256) void sc_k(const unsigned short* __restrict__ Hm,
    const float* __restrict__ w2, const float* __restrict__ b2, float* __restrict__ sc)
{
  const int lane = threadIdx.x & 63, wid = threadIdx.x >> 6;
  const long long gw = ((long long)blockIdx.x << 2) + wid;
  const int e = (int)(gw & 3);
  const long long n = gw >> 2;
  const unsigned short* p = Hm + ((long long)e << 22) + (n << 8) + (lane << 2);
  const float* w = w2 + (e << 8) + (lane << 2);
  float a = bf2f(p[0])*w[0] + bf2f(p[1])*w[1] + bf2f(p[2])*w[2] + bf2f(p[3])*w[3];
#pragma unroll
  for (int o=32;o;o>>=1) a += __shfl_xor(a,o,64);
  if (lane==0) sc[((long long)e<<14) + n] = a + b2[e];
}

__global__ __launch_bounds__(1024) void moestat_k(const float* __restrict__ sc,
                                                  float* __restrict__ mstat, float* __restrict__ sstat)
{
  __shared__ float red[1024];
  const int e = blockIdx.x, t = threadIdx.x;
  const float* p = sc + e*16384;
  float m = -3.4e38f;
  for (int n=t; n<16384; n+=1024) m = fmaxf(m, p[n]);
  red[t] = m; __syncthreads();
  for (int o=512;o;o>>=1){ if (t<o) red[t]=fmaxf(red[t],red[t+o]); __syncthreads(); }
  m = red[0]; __syncthreads();
  float s = 0.f;
  for (int n=t; n<16384; n+=1024) s += __expf(p[n]-m);
  red[t] = s; __syncthreads();
  for (int o=512;o;o>>=1){ if (t<o) red[t]+=red[t+o]; __syncthreads(); }
  if (t==0){ mstat[e]=m; sstat[e]=red[0]; }
}

__global__ __launch_bounds__(256) void attnw_k(const float* __restrict__ sc, const float* __restrict__ gates,
    const float* __restrict__ mstat, const float* __restrict__ sstat, float* __restrict__ dout)
{
  const int n = blockIdx.x*256 + threadIdx.x;
  float w = 0.f;
#pragma unroll
  for (int e=0;e<4;e++) w += gates[e]*__expf(sc[e*16384+n]-mstat[e]) / sstat[e];
  dout[514 + n] = w;
}

__global__ __launch_bounds__(256) void cls_k(const float* __restrict__ dout_in,
    const float* __restrict__ w1, const float* __restrict__ b1,
    const float* __restrict__ w2, const float* __restrict__ b2,
    const float* __restrict__ w3, const float* __restrict__ b3, float* __restrict__ dout)
{
  __shared__ float bag[512]; __shared__ float c1[256]; __shared__ float c2[128];
  const int tid = threadIdx.x;
  bag[tid] = dout_in[tid]; bag[tid+256] = dout_in[tid+256];
  __syncthreads();
  float a = b1[tid];
  for (int d=0; d<512; ++d) a += bag[d]*w1[d*256+tid];
  c1[tid] = fmaxf(a, 0.f);
  __syncthreads();
  if (tid < 128) {
    float a2 = b2[tid];
    for (int d=0; d<256; ++d) a2 += c1[d]*w2[d*128+tid];
    c2[tid] = fmaxf(a2, 0.f);
  }
  __syncthreads();
  if (tid < 2) {
    float a3 = b3[tid];
    for (int d=0; d<128; ++d) a3 += c2[d]*w3[d*2+tid];
    dout[512 + tid] = a3;
  }
}

extern "C" void kernel_launch(void* const* d_in, const int* in_sizes, int n_in,
                              void* d_out, int out_size, void* d_ws, size_t ws_size,
                              hipStream_t stream)
{
  (void)in_sizes; (void)n_in; (void)out_size; (void)ws_size;
  const float* x      = (const float*)d_in[0];
  const float* enc_w1 = (const float*)d_in[1];
  const float* enc_b1 = (const float*)d_in[2];
  const float* enc_w2 = (const float*)d_in[3];
  const float* enc_b2 = (const float*)d_in[4];
  const float* enc_w3 = (const float*)d_in[5];
  const float* enc_b3 = (const float*)d_in[6];
  const float* q_w    = (const float*)d_in[7];
  const float* q_b    = (const float*)d_in[8];
  const float* k_w    = (const float*)d_in[9];
  const float* k_b    = (const float*)d_in[10];
  const float* v_w    = (const float*)d_in[11];
  const float* v_b    = (const float*)d_in[12];
  const float* o_w    = (const float*)d_in[13];
  const float* o_b    = (const float*)d_in[14];
  const float* E_w    = (const float*)d_in[15];
  const float* F_w    = (const float*)d_in[16];
  const float* ln1_g  = (const float*)d_in[17];
  const float* ln1_b  = (const float*)d_in[18];
  const float* ln2_g  = (const float*)d_in[19];
  const float* ln2_b  = (const float*)d_in[20];
  const float* gate_w = (const float*)d_in[21];
  const float* gate_b = (const float*)d_in[22];
  const float* moe_w1 = (const float*)d_in[23];
  const float* moe_b1 = (const float*)d_in[24];
  const float* moe_w2 = (const float*)d_in[25];
  const float* moe_b2 = (const float*)d_in[26];
  const float* cls_w1 = (const float*)d_in[27];
  const float* cls_b1 = (const float*)d_in[28];
  const float* cls_w2 = (const float*)d_in[29];
  const float* cls_b2 = (const float*)d_in[30];
  const float* cls_w3 = (const float*)d_in[31];
  const float* cls_b3 = (const float*)d_in[32];

  char* ws = (char*)d_ws;
  const size_t MB = 1024*1024;
  unsigned short* Q     = (unsigned short*)(ws + 0);        // 16MB
  unsigned short* Kb    = (unsigned short*)(ws + 16*MB);    // 16MB
  unsigned short* Vb    = (unsigned short*)(ws + 32*MB);    // 16MB
  unsigned short* feat  = (unsigned short*)(ws + 48*MB);    // 16MB
  unsigned short* h1    = (unsigned short*)(ws + 0);        // 32MB (dead before Q)
  unsigned short* h2    = (unsigned short*)(ws + 32*MB);    // 16MB (dead before V)
  float*          S     = (float*)(ws + 64*MB);             // 16MB per-head scores
  unsigned short* ao    = (unsigned short*)(ws + 80*MB);    // 16MB
  unsigned short* attno = (unsigned short*)(ws + 96*MB);    // 16MB
  unsigned short* att   = (unsigned short*)(ws + 112*MB);   // 16MB
  unsigned short* Hm    = (unsigned short*)(ws + 0);        // 32MB (Q,K dead)
  float* t1    = (float*)(ws + 128*MB);                     // 2*256*256
  float* redb  = (float*)(ws + 128*MB + 512*1024);          // 2*256*512
  float* kcb   = (float*)(ws + 128*MB + 1536*1024);         // 2*256*512
  float* colp  = (float*)(ws + 128*MB + 2560*1024);         // 128*512
  float* meanv = (float*)(ws + 128*MB + 2816*1024);         // 512
  float* gatesp= (float*)(ws + 128*MB + 2820*1024);         // 4
  float* scp   = (float*)(ws + 128*MB + 2824*1024);         // 4*16384
  float* mstat = (float*)(ws + 128*MB + 3080*1024);         // 4
  float* sstat = (float*)(ws + 128*MB + 3084*1024);         // 4
  float* bagp  = (float*)(ws + 128*MB + 3088*1024);         // 128*512
  float* dout  = (float*)d_out;

  // encoder
  gemm_k<false,false,1,true><<<dim3(8,128,1),256,0,stream>>>(x,  enc_w1, enc_b1, h1,   16384,1024,2000, 2000,1024,1024, 0,0,0,0);
  gemm_k<true ,false,1,true><<<dim3(4,128,1),256,0,stream>>>(h1, enc_w2, enc_b2, h2,   16384,512,1024,  1024,512,512,   0,0,0,0);
  gemm_k<true ,false,1,true><<<dim3(4,128,1),256,0,stream>>>(h2, enc_w3, enc_b3, feat, 16384,512,512,   512,512,512,    0,0,0,0);
  // QKV
  gemm_k<true ,false,0,true><<<dim3(4,128,1),256,0,stream>>>(feat, q_w, q_b, Q,  16384,512,512, 512,512,512, 0,0,0,0);
  gemm_k<true ,false,0,true><<<dim3(4,128,1),256,0,stream>>>(feat, k_w, k_b, Kb, 16384,512,512, 512,512,512, 0,0,0,0);
  gemm_k<true ,false,0,true><<<dim3(4,128,1),256,0,stream>>>(feat, v_w, v_b, Vb, 16384,512,512, 512,512,512, 0,0,0,0);
  // linformer projections (resize folded analytically)
  t1_k <<<dim3(256,2),256,0,stream>>>(E_w, F_w, t1);
  red_k<<<dim3(256,2),512,0,stream>>>(Kb, Vb, redb);
  kc_k <<<dim3(256,2),512,0,stream>>>(t1, redb, kcb);
  // attention per head: S = Q_h @ Kc_h^T ; softmax ; ao_h = P @ Vc_h
  for (int h=0; h<8; ++h) {
    gemm_k<true ,true ,0,false><<<dim3(2,128,1),256,0,stream>>>(Q + h*64, kcb + h*64, nullptr, S,
                                                                16384,256,64, 512,512,256, 0,0,0,0);
    softmax256_k<<<dim3(4096),256,0,stream>>>(S, 0.125f);
    gemm_k<false,false,0,true ><<<dim3(1,128,1),256,0,stream>>>(S, kcb + 131072 + h*64, nullptr, ao + h*64,
                                                                16384,64,256, 256,512,512, 0,0,0,0);
  }
  // output projection + residual + double LN
  gemm_k<true,false,0,true><<<dim3(4,128,1),256,0,stream>>>(ao, o_w, o_b, attno, 16384,512,512, 512,512,512, 0,0,0,0);
  ln2_k<<<dim3(16384),256,0,stream>>>(attno, feat, ln1_g, ln1_b, ln2_g, ln2_b, att);
  // gates
  wcolsum_k<<<dim3(128),256,0,stream>>>(att, nullptr, colp);
  colfin_k<<<dim3(1),512,0,stream>>>(colp, meanv, 1.f/16384.f);
  gates_k<<<dim3(1),64,0,stream>>>(meanv, gate_w, gate_b, gatesp);
  // MoE expert attention
  gemm_k<true,false,2,true><<<dim3(2,128,4),256,0,stream>>>(att, moe_w1, moe_b1, Hm,
                                                            16384,256,512, 512,256,256, 0, 131072, 4194304, 256);
  sc_k<<<dim3(16384),256,0,stream>>>(Hm, moe_w2, moe_b2, scp);
  moestat_k<<<dim3(4),1024,0,stream>>>(scp, mstat, sstat);
  attnw_k<<<dim3(64),256,0,stream>>>(scp, gatesp, mstat, sstat, dout);
  // bag = attn_weights @ att
  wcolsum_k<<<dim3(128),256,0,stream>>>(att, dout + 514, bagp);
  colfin_k<<<dim3(1),512,0,stream>>>(bagp, dout, 1.f);
  // classifier
  cls_k<<<dim3(1),256,0,stream>>>(dout, cls_w1, cls_b1, cls_w2, cls_b2, cls_w3, cls_b3, dout);
}

// Round 2
// 591.850 us; speedup vs baseline: 2.4335x; 2.4335x over previous
//
#include <hip/hip_runtime.h>

#define DI __device__ __forceinline__

DI float bf2f(unsigned short u){ unsigned int v = ((unsigned int)u)<<16; float f; __builtin_memcpy(&f,&v,4); return f; }
DI unsigned short f2bf(float f){ unsigned int v; __builtin_memcpy(&v,&f,4); v = v + 0x7FFFu + ((v>>16)&1u); return (unsigned short)(v>>16); }

typedef __attribute__((ext_vector_type(8))) short bf16x8;
typedef __attribute__((ext_vector_type(4))) float f32x4;

#define GLD_LDS16(src, dst) __builtin_amdgcn_global_load_lds( \
    (const __attribute__((address_space(1))) void*)(src), \
    (__attribute__((address_space(3))) void*)(dst), 16, 0, 0)

// ---------------- bf16 MFMA GEMM, m97 structure ----------------
// C[M,N] = act(A[M,K] @ Bt^T + bias); A bf16 [M,K] lda, Bt bf16 [N,K] ldb.
// K % 64 == 0, M % 128 == 0, N % 128 == 0 required (no guards).
// MOE: instead of writing C, accumulate sum_n tanh(v)*w2[z,n] into scp[z][m].
template<int ACT, bool MOE>
__global__ __launch_bounds__(256) void gemm2_k(
    const unsigned short* __restrict__ A, const unsigned short* __restrict__ Bt,
    const float* __restrict__ bias, unsigned short* __restrict__ C,
    const float* __restrict__ w2, float* __restrict__ scp,
    int K, int lda, int ldb, int ldc,
    long long azs, long long bzs, int bias_zs)
{
  __shared__ unsigned short As[8192];   // [128 rows][64 k] swizzled chunks
  __shared__ unsigned short Bs[8192];
  const int z = blockIdx.z;
  const unsigned short* Ag = A + (long long)z*azs;
  const unsigned short* Bg = Bt + (long long)z*bzs;
  const int tid = threadIdx.x, lane = tid & 63, wid = tid >> 6;
  const int wm = wid >> 1, wn = wid & 1;
  const long long mBase = (long long)blockIdx.y << 7;
  const long long nBase = (long long)blockIdx.x << 7;
  const int q = lane >> 4, r15 = lane & 15;

  f32x4 acc[4][4];
#pragma unroll
  for (int i=0;i<4;i++)
#pragma unroll
    for (int j=0;j<4;j++)
#pragma unroll
      for (int r=0;r<4;r++) acc[i][j][r] = 0.f;

  const int nkt = K >> 6;
  for (int kt=0; kt<nkt; ++kt) {
    const int k0 = kt << 6;
#pragma unroll
    for (int it=0; it<4; ++it) {
      const int dbase = (it<<8) + (wid<<6);
      const int d = dbase + lane;
      const int row = d >> 3, cc = d & 7, sc = cc ^ (row & 7);
      const unsigned short* srcA = Ag + (mBase + row)*(long long)lda + k0 + (sc<<3);
      GLD_LDS16(srcA, As + (dbase<<3));
      const unsigned short* srcB = Bg + (nBase + row)*(long long)ldb + k0 + (sc<<3);
      GLD_LDS16(srcB, Bs + (dbase<<3));
    }
    __syncthreads();
#pragma unroll
    for (int ks=0; ks<2; ++ks) {
      bf16x8 af[4], bfr[4];
#pragma unroll
      for (int mi=0; mi<4; ++mi) {
        const int row = (wm<<6) + (mi<<4) + r15;
        const int ch = ((ks<<2)+q) ^ (row&7);
        af[mi] = *(const bf16x8*)(As + (row<<6) + (ch<<3));
      }
#pragma unroll
      for (int ni=0; ni<4; ++ni) {
        const int col = (wn<<6) + (ni<<4) + r15;
        const int ch = ((ks<<2)+q) ^ (col&7);
        bfr[ni] = *(const bf16x8*)(Bs + (col<<6) + (ch<<3));
      }
#pragma unroll
      for (int mi=0; mi<4; ++mi)
#pragma unroll
        for (int ni=0; ni<4; ++ni)
          acc[mi][ni] = __builtin_amdgcn_mfma_f32_16x16x32_bf16(af[mi], bfr[ni], acc[mi][ni], 0, 0, 0);
    }
    __syncthreads();
  }

  if constexpr (MOE) {
#pragma unroll
    for (int mi=0; mi<4; ++mi) {
#pragma unroll
      for (int r=0; r<4; ++r) {
        float p = 0.f;
#pragma unroll
        for (int ni=0; ni<4; ++ni) {
          const int n = (int)nBase + (wn<<6) + (ni<<4) + r15;
          const float v = acc[mi][ni][r] + bias[z*bias_zs + n];
          const float t = 1.f - 2.f/(__expf(2.f*v) + 1.f);   // tanh
          p += t * w2[(z<<8) + n];
        }
        p += __shfl_xor(p,1,64); p += __shfl_xor(p,2,64);
        p += __shfl_xor(p,4,64); p += __shfl_xor(p,8,64);
        if (r15 == 0) {
          const long long m = mBase + (wm<<6) + (mi<<4) + (q<<2) + r;
          atomicAdd(scp + ((long long)z<<14) + m, p);
        }
      }
    }
  } else {
#pragma unroll
    for (int ni=0; ni<4; ++ni) {
      const long long n = nBase + (wn<<6) + (ni<<4) + r15;
      const float bval = bias[z*bias_zs + n];
#pragma unroll
      for (int mi=0; mi<4; ++mi) {
#pragma unroll
        for (int r=0; r<4; ++r) {
          const long long m = mBase + (wm<<6) + (mi<<4) + (q<<2) + r;
          float v = acc[mi][ni][r] + bval;
          if constexpr (ACT==1) v = fmaxf(v, 0.f);
          C[m*(long long)ldc + n] = f2bf(v);
        }
      }
    }
  }
}

// ---------------- conversions ----------------
// x [16384][2000] f32 -> xb [16384][2048] bf16 zero-padded
__global__ __launch_bounds__(256) void cvtx_k(const float* __restrict__ x, unsigned short* __restrict__ xb)
{
  const long long id = (long long)blockIdx.x*256 + threadIdx.x;  // chunk of 8
  const long long row = id >> 8; const int c = (int)(id & 255);
  bf16x8 v;
  if (c < 250) {
    const float* p = x + row*2000 + c*8;
    const float4 f0 = *(const float4*)p, f1 = *(const float4*)(p+4);
    v[0]=(short)f2bf(f0.x); v[1]=(short)f2bf(f0.y); v[2]=(short)f2bf(f0.z); v[3]=(short)f2bf(f0.w);
    v[4]=(short)f2bf(f1.x); v[5]=(short)f2bf(f1.y); v[6]=(short)f2bf(f1.z); v[7]=(short)f2bf(f1.w);
  } else {
#pragma unroll
    for (int j=0;j<8;j++) v[j]=0;
  }
  *(bf16x8*)(xb + (id<<3)) = v;
}

// Bt[z][n][Kpad] = bf16(B[z][k][n]), zero pad k>=K. grid (Kpad/64, N/64, Z)
__global__ __launch_bounds__(256) void cvtw_k(const float* __restrict__ B, unsigned short* __restrict__ Bt,
    int K, int N, int Kpad, long long bszi, long long bszo)
{
  __shared__ float tile[64][65];
  const float* Bz = B + (long long)blockIdx.z*bszi;
  unsigned short* Bo = Bt + (long long)blockIdx.z*bszo;
  const int k0 = blockIdx.x<<6, n0 = blockIdx.y<<6;
  const int c = threadIdx.x & 63, rg = threadIdx.x >> 6;
#pragma unroll
  for (int j=0;j<16;j++){
    const int r = (j<<2) + rg;
    const int k = k0 + r;
    tile[r][c] = (k < K) ? Bz[(long long)k*N + n0 + c] : 0.f;
  }
  __syncthreads();
#pragma unroll
  for (int j=0;j<16;j++){
    const int nn = (j<<2) + rg;
    Bo[(long long)(n0+nn)*Kpad + k0 + c] = f2bf(tile[c][nn]);
  }
}

// ---------------- bilinear-resize weight generation (verified round 1) ----------------
__global__ __launch_bounds__(256) void t1_k(const float* __restrict__ Ew, const float* __restrict__ Fw,
                                            float* __restrict__ t1)
{
  const int k = blockIdx.x, which = blockIdx.y, c = threadIdx.x;
  const float* W = which ? Fw : Ew;
  const float ksc = 39.0625f;
  const float inv = 1.f/39.0625f;
  const float sf = (k + 0.5f)*ksc - 0.5f;
  int ilo = (int)ceilf(sf - ksc); if (ilo < 0) ilo = 0;
  int ihi = (int)floorf(sf + ksc); if (ihi > 9999) ihi = 9999;
  float acc = 0.f, wsum = 0.f;
  for (int i=ilo; i<=ihi; ++i) {
    const float w = 1.f - fabsf(sf - (float)i)*inv;
    if (w > 0.f) { acc += w * W[c*10000 + i]; wsum += w; }
  }
  t1[(which*256 + k)*256 + c] = acc / wsum;
}

__global__ __launch_bounds__(512) void red_k(const unsigned short* __restrict__ Kb,
                                             const unsigned short* __restrict__ Vb,
                                             float* __restrict__ red)
{
  const int c = blockIdx.x, which = blockIdx.y, j = threadIdx.x;
  const unsigned short* X = which ? Vb : Kb;
  int nlo = 64*c - 32; if (nlo < 0) nlo = 0;
  int nhi = 64*c + 95; if (nhi > 16383) nhi = 16383;
  float acc = 0.f;
  for (int n=nlo; n<=nhi; ++n) {
    float sf = (n + 0.5f)*0.015625f - 0.5f;
    sf = fminf(fmaxf(sf, 0.f), 255.f);
    const int c0 = (int)sf;
    const float f = sf - (float)c0;
    float w = 0.f;
    if (c == c0) w = 1.f - f;
    else if (c == c0+1) w = f;
    if (w != 0.f) acc += w * bf2f(X[(long long)n*512 + j]);
  }
  red[(which*256 + c)*512 + j] = acc;
}

__global__ __launch_bounds__(512) void kc_k(const float* __restrict__ t1, const float* __restrict__ red,
                                            float* __restrict__ kc)
{
  const int k = blockIdx.x, which = blockIdx.y, j = threadIdx.x;
  const float* T = t1 + (which*256 + k)*256;
  const float* R = red + which*131072;
  float acc = 0.f;
  for (int c=0; c<256; ++c) acc += T[c] * R[c*512 + j];
  kc[(which*256 + k)*512 + j] = acc;
}

// kcb f32 [2][256][512] -> Kc bf16 [8][256][64], Vct bf16 [8][64][256]
__global__ __launch_bounds__(256) void prepkv_k(const float* __restrict__ kcb,
    unsigned short* __restrict__ Kc, unsigned short* __restrict__ Vct)
{
  const int id = blockIdx.x*256 + threadIdx.x;   // 131072
  const int k = id >> 9, j = id & 511;
  const int h = j >> 6, d = j & 63;
  Kc [(h<<14) + (k<<6) + d] = f2bf(kcb[id]);
  Vct[(h<<14) + (d<<8) + k] = f2bf(kcb[131072 + id]);
}

// ---------------- fused linformer attention ----------------
// grid (128 row-blocks, 8 heads), block 256. ao[m][h*64+d], ldc 512.
__global__ __launch_bounds__(256) void attn_k(
    const unsigned short* __restrict__ Qg, const unsigned short* __restrict__ Kc,
    const unsigned short* __restrict__ Vct, unsigned short* __restrict__ ao)
{
  __shared__ unsigned short Ks[16384];   // [256 n][64 k] swizzled
  __shared__ unsigned short Vs[16384];   // [64 d][256 k] swizzled
  __shared__ unsigned short Ps[32768];   // [128 m][256 k] swizzled
  const int h = blockIdx.y;
  const long long mBase = (long long)blockIdx.x << 7;
  const int tid = threadIdx.x, lane = tid & 63, wid = tid >> 6;
  const int q = lane >> 4, r15 = lane & 15;

#pragma unroll
  for (int it=0; it<8; ++it) {
    const int dbase = (it<<8) + (wid<<6);
    const int d = dbase + lane;
    { // Ks: 2048 chunks, row=d>>3
      const int row = d >> 3, cc = d & 7, sc = cc ^ (row & 7);
      GLD_LDS16(Kc + (h<<14) + (row<<6) + (sc<<3), Ks + (dbase<<3));
    }
    { // Vs: 2048 chunks, row=d>>5 (32 chunks/row), swizzle low 3 bits
      const int row = d >> 5, cc = d & 31, sc = (cc & 24) | ((cc ^ (row & 7)) & 7);
      GLD_LDS16(Vct + (h<<14) + (row<<8) + (sc<<3), Vs + (dbase<<3));
    }
  }
  __syncthreads();

  // S = Q @ Kc^T : wave owns rows [wid*32, wid*32+32), all 256 cols
  f32x4 acc[2][16];
#pragma unroll
  for (int mi=0;mi<2;mi++)
#pragma unroll
    for (int ni=0;ni<16;ni++)
#pragma unroll
      for (int r=0;r<4;r++) acc[mi][ni][r] = 0.f;

#pragma unroll
  for (int ks=0; ks<2; ++ks) {
    bf16x8 af[2];
#pragma unroll
    for (int mi=0; mi<2; ++mi) {
      const long long m = mBase + (wid<<5) + (mi<<4) + r15;
      af[mi] = *(const bf16x8*)(Qg + m*512 + (h<<6) + (ks<<5) + (q<<3));
    }
#pragma unroll
    for (int ni=0; ni<16; ++ni) {
      const int col = (ni<<4) + r15;
      const int ch = ((ks<<2)+q) ^ (col&7);
      const bf16x8 bv = *(const bf16x8*)(Ks + (col<<6) + (ch<<3));
      acc[0][ni] = __builtin_amdgcn_mfma_f32_16x16x32_bf16(af[0], bv, acc[0][ni], 0,0,0);
      acc[1][ni] = __builtin_amdgcn_mfma_f32_16x16x32_bf16(af[1], bv, acc[1][ni], 0,0,0);
    }
  }

  // row softmax (scale 1/8), write P (bf16) to swizzled LDS
#pragma unroll
  for (int mi=0; mi<2; ++mi) {
#pragma unroll
    for (int r=0; r<4; ++r) {
      float mx = -3.4e38f;
#pragma unroll
      for (int ni=0; ni<16; ++ni) mx = fmaxf(mx, acc[mi][ni][r]);
      mx = fmaxf(mx, __shfl_xor(mx,1,64)); mx = fmaxf(mx, __shfl_xor(mx,2,64));
      mx = fmaxf(mx, __shfl_xor(mx,4,64)); mx = fmaxf(mx, __shfl_xor(mx,8,64));
      float s = 0.f;
#pragma unroll
      for (int ni=0; ni<16; ++ni) {
        const float e = __expf((acc[mi][ni][r] - mx)*0.125f);
        acc[mi][ni][r] = e; s += e;
      }
      s += __shfl_xor(s,1,64); s += __shfl_xor(s,2,64);
      s += __shfl_xor(s,4,64); s += __shfl_xor(s,8,64);
      const float inv = 1.f / s;
      const int row = (wid<<5) + (mi<<4) + (q<<2) + r;
#pragma unroll
      for (int ni=0; ni<16; ++ni) {
        const int col = (ni<<4) + r15;
        const int ch = col >> 3;
        const int chs = (ch & 24) | ((ch ^ (row & 7)) & 7);
        Ps[(row<<8) + (chs<<3) + (col&7)] = f2bf(acc[mi][ni][r]*inv);
      }
    }
  }
  __syncthreads();

  // O = P @ Vc : K=256 (8 k-steps), N=64 (4 n-tiles)
  f32x4 o[2][4];
#pragma unroll
  for (int mi=0;mi<2;mi++)
#pragma unroll
    for (int ni=0;ni<4;ni++)
#pragma unroll
      for (int r=0;r<4;r++) o[mi][ni][r] = 0.f;

#pragma unroll
  for (int kk=0; kk<8; ++kk) {
    bf16x8 pa[2];
#pragma unroll
    for (int mi=0; mi<2; ++mi) {
      const int row = (wid<<5) + (mi<<4) + r15;
      const int ch = (kk<<2) + q;
      const int chs = (ch & 24) | ((ch ^ (row & 7)) & 7);
      pa[mi] = *(const bf16x8*)(Ps + (row<<8) + (chs<<3));
    }
#pragma unroll
    for (int ni=0; ni<4; ++ni) {
      const int vrow = (ni<<4) + r15;
      const int ch = (kk<<2) + q;
      const int chs = (ch & 24) | ((ch ^ (vrow & 7)) & 7);
      const bf16x8 bv = *(const bf16x8*)(Vs + (vrow<<8) + (chs<<3));
      o[0][ni] = __builtin_amdgcn_mfma_f32_16x16x32_bf16(pa[0], bv, o[0][ni], 0,0,0);
      o[1][ni] = __builtin_amdgcn_mfma_f32_16x16x32_bf16(pa[1], bv, o[1][ni], 0,0,0);
    }
  }
#pragma unroll
  for (int mi=0; mi<2; ++mi)
#pragma unroll
    for (int ni=0; ni<4; ++ni)
#pragma unroll
      for (int r=0; r<4; ++r) {
        const long long m = mBase + (wid<<5) + (mi<<4) + (q<<2) + r;
        ao[m*512 + (h<<6) + (ni<<4) + r15] = f2bf(o[mi][ni][r]);
      }
}

// ---------------- double layernorm on (attn_out + feat) ----------------
__global__ __launch_bounds__(256) void ln2_k(
    const unsigned short* __restrict__ x1b, const unsigned short* __restrict__ x2b,
    const float* __restrict__ g1, const float* __restrict__ b1,
    const float* __restrict__ g2, const float* __restrict__ b2,
    unsigned short* __restrict__ out)
{
  __shared__ float sred[8];
  const int tid = threadIdx.x, lane = tid & 63, wid = tid >> 6;
  const long long base = (long long)blockIdx.x << 9;
  const float x0 = bf2f(x1b[base+tid])     + bf2f(x2b[base+tid]);
  const float x1 = bf2f(x1b[base+256+tid]) + bf2f(x2b[base+256+tid]);
  float s = x0+x1, qq = x0*x0 + x1*x1;
#pragma unroll
  for (int o=32;o;o>>=1){ s += __shfl_xor(s,o,64); qq += __shfl_xor(qq,o,64); }
  if (lane==0){ sred[wid]=s; sred[4+wid]=qq; }
  __syncthreads();
  float mean = (sred[0]+sred[1]+sred[2]+sred[3]) * (1.f/512.f);
  float var  = (sred[4]+sred[5]+sred[6]+sred[7]) * (1.f/512.f) - mean*mean;
  float rs = rsqrtf(var + 1e-5f);
  const float y0 = (x0-mean)*rs*g1[tid]     + b1[tid];
  const float y1 = (x1-mean)*rs*g1[tid+256] + b1[tid+256];
  __syncthreads();
  s = y0+y1; qq = y0*y0 + y1*y1;
#pragma unroll
  for (int o=32;o;o>>=1){ s += __shfl_xor(s,o,64); qq += __shfl_xor(qq,o,64); }
  if (lane==0){ sred[wid]=s; sred[4+wid]=qq; }
  __syncthreads();
  mean = (sred[0]+sred[1]+sred[2]+sred[3]) * (1.f/512.f);
  var  = (sred[4]+sred[5]+sred[6]+sred[7]) * (1.f/512.f) - mean*mean;
  rs = rsqrtf(var + 1e-5f);
  out[base+tid]     = f2bf((y0-mean)*rs*g2[tid]     + b2[tid]);
  out[base+256+tid] = f2bf((y1-mean)*rs*g2[tid+256] + b2[tid+256]);
}

// ---------------- pooling / gates / classifier ----------------
__global__ __launch_bounds__(256) void wcolsum_k(const unsigned short* __restrict__ att,
                                                 const float* __restrict__ wts, float* __restrict__ part)
{
  const int c = threadIdx.x;
  const long long r0 = (long long)blockIdx.x * 128;
  float a0=0.f, a1=0.f;
  for (int r=0;r<128;r++){
    const float w = wts ? wts[r0+r] : 1.f;
    const unsigned short* p = att + ((r0+r)<<9);
    a0 += w*bf2f(p[c]); a1 += w*bf2f(p[c+256]);
  }
  part[((long long)blockIdx.x<<9)+c]     = a0;
  part[((long long)blockIdx.x<<9)+c+256] = a1;
}

__global__ __launch_bounds__(512) void colfin_k(const float* __restrict__ part, float* __restrict__ out, float scale)
{
  const int c = threadIdx.x;
  float s = 0.f;
  for (int b=0;b<128;b++) s += part[(b<<9)+c];
  out[c] = s*scale;
}

__global__ __launch_bounds__(64) void gates_k(const float* __restrict__ meanv, const float* __restrict__ gw,
                                              const float* __restrict__ gb, float* __restrict__ gates)
{
  __shared__ float tmp[4];
  const int t = threadIdx.x;
  if (t < 4) {
    float a = gb[t];
    for (int d=0; d<512; ++d) a += meanv[d]*gw[d*4+t];
    tmp[t] = a;
  }
  __syncthreads();
  if (t == 0) {
    const float m = fmaxf(fmaxf(tmp[0],tmp[1]),fmaxf(tmp[2],tmp[3]));
    float e[4]; float s=0.f;
    for (int i=0;i<4;i++){ e[i]=__expf(tmp[i]-m); s+=e[i]; }
    for (int i=0;i<4;i++) gates[i] = e[i]/s;
  }
}

__global__ __launch_bounds__(256) void zero_k(float4* __restrict__ p)
{
  p[(long long)blockIdx.x*256 + threadIdx.x] = make_float4(0.f,0.f,0.f,0.f);
}

__global__ __launch_bounds__(1024) void moestat_k(const float* __restrict__ sc,
                                                  float* __restrict__ mstat, float* __restrict__ sstat)
{
  __shared__ float red[1024];
  const int e = blockIdx.x, t = threadIdx.x;
  const float* p = sc + e*16384;
  float m = -3.4e38f;
  for (int n=t; n<16384; n+=1024) m = fmaxf(m, p[n]);
  red[t] = m; __syncthreads();
  for (int o=512;o;o>>=1){ if (t<o) red[t]=fmaxf(red[t],red[t+o]); __syncthreads(); }
  m = red[0]; __syncthreads();
  float s = 0.f;
  for (int n=t; n<16384; n+=1024) s += __expf(p[n]-m);
  red[t] = s; __syncthreads();
  for (int o=512;o;o>>=1){ if (t<o) red[t]+=red[t+o]; __syncthreads(); }
  if (t==0){ mstat[e]=m; sstat[e]=red[0]; }
}

__global__ __launch_bounds__(256) void attnw_k(const float* __restrict__ sc, const float* __restrict__ gates,
    const float* __restrict__ mstat, const float* __restrict__ sstat, float* __restrict__ dout)
{
  const int n = blockIdx.x*256 + threadIdx.x;
  float w = 0.f;
#pragma unroll
  for (int e=0;e<4;e++) w += gates[e]*__expf(sc[e*16384+n]-mstat[e]) / sstat[e];
  dout[514 + n] = w;
}

__global__ __launch_bounds__(256) void cls_k(const float* __restrict__ dout_in,
    const float* __restrict__ w1, const float* __restrict__ b1,
    const float* __restrict__ w2, const float* __restrict__ b2,
    const float* __restrict__ w3, const float* __restrict__ b3, float* __restrict__ dout)
{
  __shared__ float bag[512]; __shared__ float c1[256]; __shared__ float c2[128];
  const int tid = threadIdx.x;
  bag[tid] = dout_in[tid]; bag[tid+256] = dout_in[tid+256];
  __syncthreads();
  float a = b1[tid];
  for (int d=0; d<512; ++d) a += bag[d]*w1[d*256+tid];
  c1[tid] = fmaxf(a, 0.f);
  __syncthreads();
  if (tid < 128) {
    float a2 = b2[tid];
    for (int d=0; d<256; ++d) a2 += c1[d]*w2[d*128+tid];
    c2[tid] = fmaxf(a2, 0.f);
  }
  __syncthreads();
  if (tid < 2) {
    float a3 = b3[tid];
    for (int d=0; d<128; ++d) a3 += c2[d]*w3[d*2+tid];
    dout[512 + tid] = a3;
  }
}

extern "C" void kernel_launch(void* const* d_in, const int* in_sizes, int n_in,
                              void* d_out, int out_size, void* d_ws, size_t ws_size,
                              hipStream_t stream)
{
  (void)in_sizes; (void)n_in; (void)out_size; (void)ws_size;
  const float* x      = (const float*)d_in[0];
  const float* enc_w1 = (const float*)d_in[1];
  const float* enc_b1 = (const float*)d_in[2];
  const float* enc_w2 = (const float*)d_in[3];
  const float* enc_b2 = (const float*)d_in[4];
  const float* enc_w3 = (const float*)d_in[5];
  const float* enc_b3 = (const float*)d_in[6];
  const float* q_w    = (const float*)d_in[7];
  const float* q_b    = (const float*)d_in[8];
  const float* k_w    = (const float*)d_in[9];
  const float* k_b    = (const float*)d_in[10];
  const float* v_w    = (const float*)d_in[11];
  const float* v_b    = (const float*)d_in[12];
  const float* o_w    = (const float*)d_in[13];
  const float* o_b    = (const float*)d_in[14];
  const float* E_w    = (const float*)d_in[15];
  const float* F_w    = (const float*)d_in[16];
  const float* ln1_g  = (const float*)d_in[17];
  const float* ln1_b  = (const float*)d_in[18];
  const float* ln2_g  = (const float*)d_in[19];
  const float* ln2_b  = (const float*)d_in[20];
  const float* gate_w = (const float*)d_in[21];
  const float* gate_b = (const float*)d_in[22];
  const float* moe_w1 = (const float*)d_in[23];
  const float* moe_b1 = (const float*)d_in[24];
  const float* moe_w2 = (const float*)d_in[25];
  // d_in[26] = moe_b2: drops out of the row-softmax (shift invariance)
  const float* cls_w1 = (const float*)d_in[27];
  const float* cls_b1 = (const float*)d_in[28];
  const float* cls_w2 = (const float*)d_in[29];
  const float* cls_b2 = (const float*)d_in[30];
  const float* cls_w3 = (const float*)d_in[31];
  const float* cls_b3 = (const float*)d_in[32];

  char* ws = (char*)d_ws;
  const size_t MB = 1024*1024;
  // big bf16 regions (time-multiplexed)
  unsigned short* x_bf  = (unsigned short*)(ws + 0);          // [16384][2048]  64MB
  unsigned short* h1    = (unsigned short*)(ws + 64*MB);      // [16384][1024]  32MB
  unsigned short* h2    = (unsigned short*)(ws + 0);          // [16384][512]   16MB (x_bf dead)
  unsigned short* feat  = (unsigned short*)(ws + 16*MB);      // 16MB
  unsigned short* Qb    = (unsigned short*)(ws + 32*MB);      // 16MB
  unsigned short* Kb    = (unsigned short*)(ws + 48*MB);      // 16MB
  unsigned short* Vb    = (unsigned short*)(ws + 64*MB);      // 16MB (h1 dead)
  unsigned short* ao    = (unsigned short*)(ws + 80*MB);      // 16MB
  unsigned short* attno = (unsigned short*)(ws + 0);          // 16MB (h2 dead)
  unsigned short* att   = (unsigned short*)(ws + 32*MB);      // 16MB (Qb dead)
  // persistent weights / small buffers
  unsigned short* w1t   = (unsigned short*)(ws + 96*MB);                  // [1024][2048] 4MB
  unsigned short* w2t   = (unsigned short*)(ws + 100*MB);                 // [512][1024]  1MB
  unsigned short* w3t   = (unsigned short*)(ws + 101*MB);                 // [512][512] 0.5MB
  unsigned short* qwt   = (unsigned short*)(ws + 101*MB + 512*1024);
  unsigned short* kwt   = (unsigned short*)(ws + 102*MB);
  unsigned short* vwt   = (unsigned short*)(ws + 102*MB + 512*1024);
  unsigned short* owt   = (unsigned short*)(ws + 103*MB);
  unsigned short* mwt   = (unsigned short*)(ws + 103*MB + 512*1024);      // [4][256][512] 1MB
  float*  kcb   = (float*)(ws + 104*MB + 512*1024);                       // [2][256][512] 1MB
  float*  t1b   = (float*)(ws + 105*MB + 512*1024);                       // 0.5MB
  float*  redb  = (float*)(ws + 106*MB);                                  // 1MB
  unsigned short* Kcbf  = (unsigned short*)(ws + 107*MB);                 // 256KB
  unsigned short* Vctbf = (unsigned short*)(ws + 107*MB + 256*1024);      // 256KB
  float*  colp  = (float*)(ws + 107*MB + 512*1024);                       // 256KB
  float*  bagp  = (float*)(ws + 107*MB + 768*1024);                       // 256KB
  float*  meanv = (float*)(ws + 108*MB);
  float*  gatesp= (float*)(ws + 108*MB + 4096);
  float*  scp   = (float*)(ws + 108*MB + 8192);                           // [4][16384] 256KB
  float*  mstat = (float*)(ws + 108*MB + 8192 + 262144);
  float*  sstat = (float*)(ws + 108*MB + 8192 + 262144 + 64);
  float*  dout  = (float*)d_out;

  // ---- conversions ----
  cvtx_k<<<16384,256,0,stream>>>(x, x_bf);
  cvtw_k<<<dim3(32,16,1),256,0,stream>>>(enc_w1, w1t, 2000,1024,2048, 0,0);
  cvtw_k<<<dim3(16, 8,1),256,0,stream>>>(enc_w2, w2t, 1024, 512,1024, 0,0);
  cvtw_k<<<dim3( 8, 8,1),256,0,stream>>>(enc_w3, w3t,  512, 512, 512, 0,0);
  cvtw_k<<<dim3( 8, 8,1),256,0,stream>>>(q_w,    qwt,  512, 512, 512, 0,0);
  cvtw_k<<<dim3( 8, 8,1),256,0,stream>>>(k_w,    kwt,  512, 512, 512, 0,0);
  cvtw_k<<<dim3( 8, 8,1),256,0,stream>>>(v_w,    vwt,  512, 512, 512, 0,0);
  cvtw_k<<<dim3( 8, 8,1),256,0,stream>>>(o_w,    owt,  512, 512, 512, 0,0);
  cvtw_k<<<dim3( 8, 4,4),256,0,stream>>>(moe_w1, mwt,  512, 256, 512, 512*256, 256*512);
  zero_k<<<64,256,0,stream>>>((float4*)scp);

  // ---- encoder ----
  gemm2_k<1,false><<<dim3(8,128,1),256,0,stream>>>(x_bf, w1t, enc_b1, h1,   nullptr,nullptr, 2048,2048,2048,1024, 0,0,0);
  gemm2_k<1,false><<<dim3(4,128,1),256,0,stream>>>(h1,   w2t, enc_b2, h2,   nullptr,nullptr, 1024,1024,1024, 512, 0,0,0);
  gemm2_k<1,false><<<dim3(4,128,1),256,0,stream>>>(h2,   w3t, enc_b3, feat, nullptr,nullptr,  512, 512, 512, 512, 0,0,0);
  // ---- QKV ----
  gemm2_k<0,false><<<dim3(4,128,1),256,0,stream>>>(feat, qwt, q_b, Qb, nullptr,nullptr, 512,512,512,512, 0,0,0);
  gemm2_k<0,false><<<dim3(4,128,1),256,0,stream>>>(feat, kwt, k_b, Kb, nullptr,nullptr, 512,512,512,512, 0,0,0);
  gemm2_k<0,false><<<dim3(4,128,1),256,0,stream>>>(feat, vwt, v_b, Vb, nullptr,nullptr, 512,512,512,512, 0,0,0);
  // ---- linformer projections (resize folded analytically) ----
  t1_k <<<dim3(256,2),256,0,stream>>>(E_w, F_w, t1b);
  red_k<<<dim3(256,2),512,0,stream>>>(Kb, Vb, redb);
  kc_k <<<dim3(256,2),512,0,stream>>>(t1b, redb, kcb);
  prepkv_k<<<512,256,0,stream>>>(kcb, Kcbf, Vctbf);
  // ---- fused attention ----
  attn_k<<<dim3(128,8),256,0,stream>>>(Qb, Kcbf, Vctbf, ao);
  // ---- output projection + residual + double LN ----
  gemm2_k<0,false><<<dim3(4,128,1),256,0,stream>>>(ao, owt, o_b, attno, nullptr,nullptr, 512,512,512,512, 0,0,0);
  ln2_k<<<16384,256,0,stream>>>(attno, feat, ln1_g, ln1_b, ln2_g, ln2_b, att);
  // ---- gates ----
  wcolsum_k<<<128,256,0,stream>>>(att, nullptr, colp);
  colfin_k<<<1,512,0,stream>>>(colp, meanv, 1.f/16384.f);
  gates_k<<<1,64,0,stream>>>(meanv, gate_w, gate_b, gatesp);
  // ---- MoE expert attention (fused tanh+dot into epilogue) ----
  gemm2_k<0,true><<<dim3(2,128,4),256,0,stream>>>(att, mwt, moe_b1, nullptr, moe_w2, scp,
                                                  512,512,512,0, 0, 131072, 256);
  moestat_k<<<4,1024,0,stream>>>(scp, mstat, sstat);
  attnw_k<<<64,256,0,stream>>>(scp, gatesp, mstat, sstat, dout);
  // ---- bag + classifier ----
  wcolsum_k<<<128,256,0,stream>>>(att, dout + 514, bagp);
  colfin_k<<<1,512,0,stream>>>(bagp, dout, 1.f);
  cls_k<<<1,256,0,stream>>>(dout, cls_w1, cls_b1, cls_w2, cls_b2, cls_w3, cls_b3, dout);
}

// Round 3
// 564.845 us; speedup vs baseline: 2.5498x; 1.0478x over previous
//
#include <hip/hip_runtime.h>

#define DI __device__ __forceinline__

DI float bf2f(unsigned short u){ unsigned int v = ((unsigned int)u)<<16; float f; __builtin_memcpy(&f,&v,4); return f; }
DI unsigned short f2bf(float f){ unsigned int v; __builtin_memcpy(&v,&f,4); v = v + 0x7FFFu + ((v>>16)&1u); return (unsigned short)(v>>16); }

typedef __attribute__((ext_vector_type(8))) short bf16x8;
typedef __attribute__((ext_vector_type(4))) float f32x4;

#define GLD_LDS16(src, dst) __builtin_amdgcn_global_load_lds( \
    (const __attribute__((address_space(1))) void*)(src), \
    (__attribute__((address_space(3))) void*)(dst), 16, 0, 0)

// ---------------- bf16 MFMA GEMM, m97 structure + XCD swizzle ----------------
// C[M,N] = act(A[M,K] @ Bt^T + bias); A bf16 [M,K] lda, Bt bf16 [N,K] ldb.
// grid (nx, ny[, z]); nx*ny % 8 == 0 required for the swizzle.
template<int ACT, bool MOE>
__global__ __launch_bounds__(256) void gemm2_k(
    const unsigned short* __restrict__ A, const unsigned short* __restrict__ Bt,
    const float* __restrict__ bias, unsigned short* __restrict__ C,
    const float* __restrict__ w2, float* __restrict__ scp,
    int K, int lda, int ldb, int ldc,
    long long azs, long long bzs, int bias_zs)
{
  __shared__ unsigned short As[8192];   // [128 rows][64 k] swizzled chunks
  __shared__ unsigned short Bs[8192];
  const int z = blockIdx.z;
  const unsigned short* Ag = A + (long long)z*azs;
  const unsigned short* Bg = Bt + (long long)z*bzs;
  const int tid = threadIdx.x, lane = tid & 63, wid = tid >> 6;
  const int wm = wid >> 1, wn = wid & 1;
  // XCD-chunk swizzle (bijective since nwg%8==0): each XCD gets contiguous tiles
  const int nx = gridDim.x;
  const int bid = blockIdx.x + nx*blockIdx.y;
  const int cpx = (nx*gridDim.y) >> 3;
  const int wg = (bid & 7)*cpx + (bid >> 3);
  const long long mBase = (long long)(wg / nx) << 7;
  const long long nBase = (long long)(wg % nx) << 7;
  const int q = lane >> 4, r15 = lane & 15;

  f32x4 acc[4][4];
#pragma unroll
  for (int i=0;i<4;i++)
#pragma unroll
    for (int j=0;j<4;j++)
#pragma unroll
      for (int r=0;r<4;r++) acc[i][j][r] = 0.f;

  const int nkt = K >> 6;
  for (int kt=0; kt<nkt; ++kt) {
    const int k0 = kt << 6;
#pragma unroll
    for (int it=0; it<4; ++it) {
      const int dbase = (it<<8) + (wid<<6);
      const int d = dbase + lane;
      const int row = d >> 3, cc = d & 7, sc = cc ^ (row & 7);
      GLD_LDS16(Ag + (mBase + row)*(long long)lda + k0 + (sc<<3), As + (dbase<<3));
      GLD_LDS16(Bg + (nBase + row)*(long long)ldb + k0 + (sc<<3), Bs + (dbase<<3));
    }
    __syncthreads();
#pragma unroll
    for (int ks=0; ks<2; ++ks) {
      bf16x8 af[4], bfr[4];
#pragma unroll
      for (int mi=0; mi<4; ++mi) {
        const int row = (wm<<6) + (mi<<4) + r15;
        const int ch = ((ks<<2)+q) ^ (row&7);
        af[mi] = *(const bf16x8*)(As + (row<<6) + (ch<<3));
      }
#pragma unroll
      for (int ni=0; ni<4; ++ni) {
        const int col = (wn<<6) + (ni<<4) + r15;
        const int ch = ((ks<<2)+q) ^ (col&7);
        bfr[ni] = *(const bf16x8*)(Bs + (col<<6) + (ch<<3));
      }
#pragma unroll
      for (int mi=0; mi<4; ++mi)
#pragma unroll
        for (int ni=0; ni<4; ++ni)
          acc[mi][ni] = __builtin_amdgcn_mfma_f32_16x16x32_bf16(af[mi], bfr[ni], acc[mi][ni], 0, 0, 0);
    }
    __syncthreads();
  }

  if constexpr (MOE) {
#pragma unroll
    for (int mi=0; mi<4; ++mi) {
#pragma unroll
      for (int r=0; r<4; ++r) {
        float p = 0.f;
#pragma unroll
        for (int ni=0; ni<4; ++ni) {
          const int n = (int)nBase + (wn<<6) + (ni<<4) + r15;
          const float v = acc[mi][ni][r] + bias[z*bias_zs + n];
          const float t = 1.f - 2.f/(__expf(2.f*v) + 1.f);   // tanh
          p += t * w2[(z<<8) + n];
        }
        p += __shfl_xor(p,1,64); p += __shfl_xor(p,2,64);
        p += __shfl_xor(p,4,64); p += __shfl_xor(p,8,64);
        if (r15 == 0) {
          const long long m = mBase + (wm<<6) + (mi<<4) + (q<<2) + r;
          atomicAdd(scp + ((long long)z<<14) + m, p);
        }
      }
    }
  } else {
#pragma unroll
    for (int ni=0; ni<4; ++ni) {
      const long long n = nBase + (wn<<6) + (ni<<4) + r15;
      const float bval = bias[z*bias_zs + n];
#pragma unroll
      for (int mi=0; mi<4; ++mi) {
#pragma unroll
        for (int r=0; r<4; ++r) {
          const long long m = mBase + (wm<<6) + (mi<<4) + (q<<2) + r;
          float v = acc[mi][ni][r] + bval;
          if constexpr (ACT==1) v = fmaxf(v, 0.f);
          C[m*(long long)ldc + n] = f2bf(v);
        }
      }
    }
  }
}

// ---------------- deep-pipelined 256x256 GEMM (enc1) ----------------
// 512 thr (8 waves 2Mx4N), BK=64, double-buffered 128KiB LDS, counted vmcnt,
// raw barriers, setprio around MFMA clusters. Dims: M%256==0, N%256==0, K%64==0.
template<int ACT>
__global__ __launch_bounds__(512,2) void gemm3_k(
    const unsigned short* __restrict__ A, const unsigned short* __restrict__ Bt,
    const float* __restrict__ bias, unsigned short* __restrict__ C,
    int K, int lda, int ldb, int ldc)
{
  __shared__ unsigned short As[2][16384];  // [buf][256 rows][64 k] chunk-swizzled
  __shared__ unsigned short Bs[2][16384];
  const int tid = threadIdx.x, lane = tid & 63, wid = tid >> 6;
  const int wm = wid >> 2, wn = wid & 3;
  const int q = lane >> 4, r15 = lane & 15;
  const int nx = gridDim.x;
  const int bid = blockIdx.x + nx*blockIdx.y;
  const int cpx = (nx*gridDim.y) >> 3;
  const int wg = (bid & 7)*cpx + (bid >> 3);
  const long long mBase = (long long)(wg / nx) << 8;
  const long long nBase = (long long)(wg % nx) << 8;

  f32x4 acc[8][4];
#pragma unroll
  for (int i=0;i<8;i++)
#pragma unroll
    for (int j=0;j<4;j++)
#pragma unroll
      for (int r=0;r<4;r++) acc[i][j][r] = 0.f;

  const int NT = K >> 6;

#define STAGE3(t, b) { \
    const int k0_ = (t) << 6; \
    _Pragma("unroll") \
    for (int i=0;i<4;i++){ \
      const int d = tid + (i<<9); \
      const int row = d>>3, cc = d&7, sc = cc ^ (row&7); \
      GLD_LDS16(A + (mBase+row)*(long long)lda + k0_ + (sc<<3), &As[b][(d<<3)]); \
    } \
    _Pragma("unroll") \
    for (int i=0;i<4;i++){ \
      const int d = tid + (i<<9); \
      const int row = d>>3, cc = d&7, sc = cc ^ (row&7); \
      GLD_LDS16(Bt + (nBase+row)*(long long)ldb + k0_ + (sc<<3), &Bs[b][(d<<3)]); \
    } }

  STAGE3(0, 0);
  for (int t=0; t<NT; ++t) {
    const int b = t & 1;
    // barrier 1: everyone done reading buf b^1 (tile t-1) -> safe to overwrite
    __builtin_amdgcn_s_barrier();
    if (t+1 < NT) {
      STAGE3(t+1, b^1);
      asm volatile("s_waitcnt vmcnt(8)" ::: "memory");  // tile t landed (mine)
    } else {
      asm volatile("s_waitcnt vmcnt(0)" ::: "memory");
    }
    // barrier 2: ALL waves' tile-t loads landed -> buf b fully valid
    __builtin_amdgcn_s_barrier();

    bf16x8 aF[8], bF0[4], bF1[4];
    // phase 0: A m-half0 + B n-half0, MFMA quadrant (m0,n0)
#pragma unroll
    for (int mi=0; mi<4; ++mi)
#pragma unroll
      for (int ks=0; ks<2; ++ks) {
        const int row = (wm<<7) + (mi<<4) + r15;
        const int ch = ((ks<<2)+q) ^ (row&7);
        aF[mi*2+ks] = *(const bf16x8*)&As[b][(row<<6) + (ch<<3)];
      }
#pragma unroll
    for (int ni=0; ni<2; ++ni)
#pragma unroll
      for (int ks=0; ks<2; ++ks) {
        const int col = (wn<<6) + (ni<<4) + r15;
        const int ch = ((ks<<2)+q) ^ (col&7);
        bF0[ni*2+ks] = *(const bf16x8*)&Bs[b][(col<<6) + (ch<<3)];
      }
    __builtin_amdgcn_s_setprio(1);
#pragma unroll
    for (int mi=0; mi<4; ++mi)
#pragma unroll
      for (int ni=0; ni<2; ++ni)
#pragma unroll
        for (int ks=0; ks<2; ++ks)
          acc[mi][ni] = __builtin_amdgcn_mfma_f32_16x16x32_bf16(aF[mi*2+ks], bF0[ni*2+ks], acc[mi][ni], 0,0,0);
    __builtin_amdgcn_s_setprio(0);
    // phase 1: B n-half1, MFMA (m0,n1)
#pragma unroll
    for (int ni=0; ni<2; ++ni)
#pragma unroll
      for (int ks=0; ks<2; ++ks) {
        const int col = (wn<<6) + ((ni+2)<<4) + r15;
        const int ch = ((ks<<2)+q) ^ (col&7);
        bF1[ni*2+ks] = *(const bf16x8*)&Bs[b][(col<<6) + (ch<<3)];
      }
    __builtin_amdgcn_s_setprio(1);
#pragma unroll
    for (int mi=0; mi<4; ++mi)
#pragma unroll
      for (int ni=0; ni<2; ++ni)
#pragma unroll
        for (int ks=0; ks<2; ++ks)
          acc[mi][ni+2] = __builtin_amdgcn_mfma_f32_16x16x32_bf16(aF[mi*2+ks], bF1[ni*2+ks], acc[mi][ni+2], 0,0,0);
    __builtin_amdgcn_s_setprio(0);
    // phase 2: A m-half1, MFMA (m1,n0)
#pragma unroll
    for (int mi=0; mi<4; ++mi)
#pragma unroll
      for (int ks=0; ks<2; ++ks) {
        const int row = (wm<<7) + ((mi+4)<<4) + r15;
        const int ch = ((ks<<2)+q) ^ (row&7);
        aF[mi*2+ks] = *(const bf16x8*)&As[b][(row<<6) + (ch<<3)];
      }
    __builtin_amdgcn_s_setprio(1);
#pragma unroll
    for (int mi=0; mi<4; ++mi)
#pragma unroll
      for (int ni=0; ni<2; ++ni)
#pragma unroll
        for (int ks=0; ks<2; ++ks)
          acc[mi+4][ni] = __builtin_amdgcn_mfma_f32_16x16x32_bf16(aF[mi*2+ks], bF0[ni*2+ks], acc[mi+4][ni], 0,0,0);
    __builtin_amdgcn_s_setprio(0);
    // phase 3: MFMA (m1,n1)
    __builtin_amdgcn_s_setprio(1);
#pragma unroll
    for (int mi=0; mi<4; ++mi)
#pragma unroll
      for (int ni=0; ni<2; ++ni)
#pragma unroll
        for (int ks=0; ks<2; ++ks)
          acc[mi+4][ni+2] = __builtin_amdgcn_mfma_f32_16x16x32_bf16(aF[mi*2+ks], bF1[ni*2+ks], acc[mi+4][ni+2], 0,0,0);
    __builtin_amdgcn_s_setprio(0);
  }
#undef STAGE3

#pragma unroll
  for (int ni=0; ni<4; ++ni) {
    const long long n = nBase + (wn<<6) + (ni<<4) + r15;
    const float bval = bias[n];
#pragma unroll
    for (int mi=0; mi<8; ++mi) {
#pragma unroll
      for (int r=0; r<4; ++r) {
        const long long m = mBase + (wm<<7) + (mi<<4) + (q<<2) + r;
        float v = acc[mi][ni][r] + bval;
        if constexpr (ACT==1) v = fmaxf(v, 0.f);
        C[m*(long long)ldc + n] = f2bf(v);
      }
    }
  }
}

// ---------------- conversions ----------------
__global__ __launch_bounds__(256) void cvtx_k(const float* __restrict__ x, unsigned short* __restrict__ xb)
{
  const long long id = (long long)blockIdx.x*256 + threadIdx.x;  // chunk of 8
  const long long row = id >> 8; const int c = (int)(id & 255);
  bf16x8 v;
  if (c < 250) {
    const float* p = x + row*2000 + c*8;
    const float4 f0 = *(const float4*)p, f1 = *(const float4*)(p+4);
    v[0]=(short)f2bf(f0.x); v[1]=(short)f2bf(f0.y); v[2]=(short)f2bf(f0.z); v[3]=(short)f2bf(f0.w);
    v[4]=(short)f2bf(f1.x); v[5]=(short)f2bf(f1.y); v[6]=(short)f2bf(f1.z); v[7]=(short)f2bf(f1.w);
  } else {
#pragma unroll
    for (int j=0;j<8;j++) v[j]=0;
  }
  *(bf16x8*)(xb + (id<<3)) = v;
}

__global__ __launch_bounds__(256) void cvtw_k(const float* __restrict__ B, unsigned short* __restrict__ Bt,
    int K, int N, int Kpad, long long bszi, long long bszo)
{
  __shared__ float tile[64][65];
  const float* Bz = B + (long long)blockIdx.z*bszi;
  unsigned short* Bo = Bt + (long long)blockIdx.z*bszo;
  const int k0 = blockIdx.x<<6, n0 = blockIdx.y<<6;
  const int c = threadIdx.x & 63, rg = threadIdx.x >> 6;
#pragma unroll
  for (int j=0;j<16;j++){
    const int r = (j<<2) + rg;
    const int k = k0 + r;
    tile[r][c] = (k < K) ? Bz[(long long)k*N + n0 + c] : 0.f;
  }
  __syncthreads();
#pragma unroll
  for (int j=0;j<16;j++){
    const int nn = (j<<2) + rg;
    Bo[(long long)(n0+nn)*Kpad + k0 + c] = f2bf(tile[c][nn]);
  }
}

__global__ __launch_bounds__(512) void catb_k(const float* __restrict__ a, const float* __restrict__ b,
                                              const float* __restrict__ c, float* __restrict__ o)
{
  const int t = threadIdx.x;
  o[t] = a[t]; o[512+t] = b[t]; o[1024+t] = c[t];
}

// ---------------- bilinear-resize weight generation ----------------
__global__ __launch_bounds__(256) void t1_k(const float* __restrict__ Ew, const float* __restrict__ Fw,
                                            float* __restrict__ t1)
{
  const int k = blockIdx.x, which = blockIdx.y, c = threadIdx.x;
  const float* W = which ? Fw : Ew;
  const float ksc = 39.0625f;
  const float inv = 1.f/39.0625f;
  const float sf = (k + 0.5f)*ksc - 0.5f;
  int ilo = (int)ceilf(sf - ksc); if (ilo < 0) ilo = 0;
  int ihi = (int)floorf(sf + ksc); if (ihi > 9999) ihi = 9999;
  float acc = 0.f, wsum = 0.f;
  for (int i=ilo; i<=ihi; ++i) {
    const float w = 1.f - fabsf(sf - (float)i)*inv;
    if (w > 0.f) { acc += w * W[c*10000 + i]; wsum += w; }
  }
  t1[(which*256 + k)*256 + c] = acc / wsum;
}

// reads K/V columns from merged qkv [16384][1536] (K at +512, V at +1024)
__global__ __launch_bounds__(512) void red_k(const unsigned short* __restrict__ qkv,
                                             float* __restrict__ red)
{
  const int c = blockIdx.x, which = blockIdx.y, j = threadIdx.x;
  const unsigned short* X = qkv + (which ? 1024 : 512);
  int nlo = 64*c - 32; if (nlo < 0) nlo = 0;
  int nhi = 64*c + 95; if (nhi > 16383) nhi = 16383;
  float acc = 0.f;
  for (int n=nlo; n<=nhi; ++n) {
    float sf = (n + 0.5f)*0.015625f - 0.5f;
    sf = fminf(fmaxf(sf, 0.f), 255.f);
    const int c0 = (int)sf;
    const float f = sf - (float)c0;
    float w = 0.f;
    if (c == c0) w = 1.f - f;
    else if (c == c0+1) w = f;
    if (w != 0.f) acc += w * bf2f(X[(long long)n*1536 + j]);
  }
  red[(which*256 + c)*512 + j] = acc;
}

// kc + prepkv fused: writes Kc bf16 [8][256][64] and Vct bf16 [8][64][256]
__global__ __launch_bounds__(512) void kc_k(const float* __restrict__ t1, const float* __restrict__ red,
                                            unsigned short* __restrict__ Kc, unsigned short* __restrict__ Vct)
{
  const int k = blockIdx.x, which = blockIdx.y, j = threadIdx.x;
  const float* T = t1 + (which*256 + k)*256;
  const float* R = red + which*131072;
  float acc = 0.f;
  for (int c=0; c<256; ++c) acc += T[c] * R[c*512 + j];
  const int h = j >> 6, d = j & 63;
  if (which == 0) Kc [(h<<14) + (k<<6) + d] = f2bf(acc);
  else            Vct[(h<<14) + (d<<8) + k] = f2bf(acc);
}

// ---------------- fused linformer attention ----------------
__global__ __launch_bounds__(256) void attn_k(
    const unsigned short* __restrict__ Qg, const unsigned short* __restrict__ Kc,
    const unsigned short* __restrict__ Vct, unsigned short* __restrict__ ao)
{
  __shared__ unsigned short Ks[16384];   // [256 n][64 k] swizzled
  __shared__ unsigned short Vs[16384];   // [64 d][256 k] swizzled
  __shared__ unsigned short Ps[32768];   // [128 m][256 k] swizzled
  const int h = blockIdx.y;
  const long long mBase = (long long)blockIdx.x << 7;
  const int tid = threadIdx.x, lane = tid & 63, wid = tid >> 6;
  const int q = lane >> 4, r15 = lane & 15;

#pragma unroll
  for (int it=0; it<8; ++it) {
    const int dbase = (it<<8) + (wid<<6);
    const int d = dbase + lane;
    {
      const int row = d >> 3, cc = d & 7, sc = cc ^ (row & 7);
      GLD_LDS16(Kc + (h<<14) + (row<<6) + (sc<<3), Ks + (dbase<<3));
    }
    {
      const int row = d >> 5, cc = d & 31, sc = (cc & 24) | ((cc ^ (row & 7)) & 7);
      GLD_LDS16(Vct + (h<<14) + (row<<8) + (sc<<3), Vs + (dbase<<3));
    }
  }
  __syncthreads();

  f32x4 acc[2][16];
#pragma unroll
  for (int mi=0;mi<2;mi++)
#pragma unroll
    for (int ni=0;ni<16;ni++)
#pragma unroll
      for (int r=0;r<4;r++) acc[mi][ni][r] = 0.f;

#pragma unroll
  for (int ks=0; ks<2; ++ks) {
    bf16x8 af[2];
#pragma unroll
    for (int mi=0; mi<2; ++mi) {
      const long long m = mBase + (wid<<5) + (mi<<4) + r15;
      af[mi] = *(const bf16x8*)(Qg + m*1536 + (h<<6) + (ks<<5) + (q<<3));
    }
#pragma unroll
    for (int ni=0; ni<16; ++ni) {
      const int col = (ni<<4) + r15;
      const int ch = ((ks<<2)+q) ^ (col&7);
      const bf16x8 bv = *(const bf16x8*)(Ks + (col<<6) + (ch<<3));
      acc[0][ni] = __builtin_amdgcn_mfma_f32_16x16x32_bf16(af[0], bv, acc[0][ni], 0,0,0);
      acc[1][ni] = __builtin_amdgcn_mfma_f32_16x16x32_bf16(af[1], bv, acc[1][ni], 0,0,0);
    }
  }

#pragma unroll
  for (int mi=0; mi<2; ++mi) {
#pragma unroll
    for (int r=0; r<4; ++r) {
      float mx = -3.4e38f;
#pragma unroll
      for (int ni=0; ni<16; ++ni) mx = fmaxf(mx, acc[mi][ni][r]);
      mx = fmaxf(mx, __shfl_xor(mx,1,64)); mx = fmaxf(mx, __shfl_xor(mx,2,64));
      mx = fmaxf(mx, __shfl_xor(mx,4,64)); mx = fmaxf(mx, __shfl_xor(mx,8,64));
      float s = 0.f;
#pragma unroll
      for (int ni=0; ni<16; ++ni) {
        const float e = __expf((acc[mi][ni][r] - mx)*0.125f);
        acc[mi][ni][r] = e; s += e;
      }
      s += __shfl_xor(s,1,64); s += __shfl_xor(s,2,64);
      s += __shfl_xor(s,4,64); s += __shfl_xor(s,8,64);
      const float inv = 1.f / s;
      const int row = (wid<<5) + (mi<<4) + (q<<2) + r;
#pragma unroll
      for (int ni=0; ni<16; ++ni) {
        const int col = (ni<<4) + r15;
        const int ch = col >> 3;
        const int chs = (ch & 24) | ((ch ^ (row & 7)) & 7);
        Ps[(row<<8) + (chs<<3) + (col&7)] = f2bf(acc[mi][ni][r]*inv);
      }
    }
  }
  __syncthreads();

  f32x4 o[2][4];
#pragma unroll
  for (int mi=0;mi<2;mi++)
#pragma unroll
    for (int ni=0;ni<4;ni++)
#pragma unroll
      for (int r=0;r<4;r++) o[mi][ni][r] = 0.f;

#pragma unroll
  for (int kk=0; kk<8; ++kk) {
    bf16x8 pa[2];
#pragma unroll
    for (int mi=0; mi<2; ++mi) {
      const int row = (wid<<5) + (mi<<4) + r15;
      const int ch = (kk<<2) + q;
      const int chs = (ch & 24) | ((ch ^ (row & 7)) & 7);
      pa[mi] = *(const bf16x8*)(Ps + (row<<8) + (chs<<3));
    }
#pragma unroll
    for (int ni=0; ni<4; ++ni) {
      const int vrow = (ni<<4) + r15;
      const int ch = (kk<<2) + q;
      const int chs = (ch & 24) | ((ch ^ (vrow & 7)) & 7);
      const bf16x8 bv = *(const bf16x8*)(Vs + (vrow<<8) + (chs<<3));
      o[0][ni] = __builtin_amdgcn_mfma_f32_16x16x32_bf16(pa[0], bv, o[0][ni], 0,0,0);
      o[1][ni] = __builtin_amdgcn_mfma_f32_16x16x32_bf16(pa[1], bv, o[1][ni], 0,0,0);
    }
  }
#pragma unroll
  for (int mi=0; mi<2; ++mi)
#pragma unroll
    for (int ni=0; ni<4; ++ni)
#pragma unroll
      for (int r=0; r<4; ++r) {
        const long long m = mBase + (wid<<5) + (mi<<4) + (q<<2) + r;
        ao[m*512 + (h<<6) + (ni<<4) + r15] = f2bf(o[mi][ni][r]);
      }
}

// ---------------- double layernorm on (attn_out + feat) ----------------
__global__ __launch_bounds__(256) void ln2_k(
    const unsigned short* __restrict__ x1b, const unsigned short* __restrict__ x2b,
    const float* __restrict__ g1, const float* __restrict__ b1,
    const float* __restrict__ g2, const float* __restrict__ b2,
    unsigned short* __restrict__ out)
{
  __shared__ float sred[8];
  const int tid = threadIdx.x, lane = tid & 63, wid = tid >> 6;
  const long long base = (long long)blockIdx.x << 9;
  const float x0 = bf2f(x1b[base+tid])     + bf2f(x2b[base+tid]);
  const float x1 = bf2f(x1b[base+256+tid]) + bf2f(x2b[base+256+tid]);
  float s = x0+x1, qq = x0*x0 + x1*x1;
#pragma unroll
  for (int o=32;o;o>>=1){ s += __shfl_xor(s,o,64); qq += __shfl_xor(qq,o,64); }
  if (lane==0){ sred[wid]=s; sred[4+wid]=qq; }
  __syncthreads();
  float mean = (sred[0]+sred[1]+sred[2]+sred[3]) * (1.f/512.f);
  float var  = (sred[4]+sred[5]+sred[6]+sred[7]) * (1.f/512.f) - mean*mean;
  float rs = rsqrtf(var + 1e-5f);
  const float y0 = (x0-mean)*rs*g1[tid]     + b1[tid];
  const float y1 = (x1-mean)*rs*g1[tid+256] + b1[tid+256];
  __syncthreads();
  s = y0+y1; qq = y0*y0 + y1*y1;
#pragma unroll
  for (int o=32;o;o>>=1){ s += __shfl_xor(s,o,64); qq += __shfl_xor(qq,o,64); }
  if (lane==0){ sred[wid]=s; sred[4+wid]=qq; }
  __syncthreads();
  mean = (sred[0]+sred[1]+sred[2]+sred[3]) * (1.f/512.f);
  var  = (sred[4]+sred[5]+sred[6]+sred[7]) * (1.f/512.f) - mean*mean;
  rs = rsqrtf(var + 1e-5f);
  out[base+tid]     = f2bf((y0-mean)*rs*g2[tid]     + b2[tid]);
  out[base+256+tid] = f2bf((y1-mean)*rs*g2[tid+256] + b2[tid+256]);
}

// ---------------- pooling / gates / classifier ----------------
// optional zf: block zeroes its 512-float slice (used to clear scp before MoE)
__global__ __launch_bounds__(256) void wcolsum_k(const unsigned short* __restrict__ att,
                                                 const float* __restrict__ wts, float* __restrict__ part,
                                                 float* __restrict__ zf)
{
  const int c = threadIdx.x;
  if (zf) { zf[((long long)blockIdx.x<<9)+c] = 0.f; zf[((long long)blockIdx.x<<9)+c+256] = 0.f; }
  const long long r0 = (long long)blockIdx.x * 128;
  float a0=0.f, a1=0.f;
  for (int r=0;r<128;r++){
    const float w = wts ? wts[r0+r] : 1.f;
    const unsigned short* p = att + ((r0+r)<<9);
    a0 += w*bf2f(p[c]); a1 += w*bf2f(p[c+256]);
  }
  part[((long long)blockIdx.x<<9)+c]     = a0;
  part[((long long)blockIdx.x<<9)+c+256] = a1;
}

// colfin + gates fused: meanv + gate softmax
__global__ __launch_bounds__(512) void meangates_k(const float* __restrict__ part,
    const float* __restrict__ gw, const float* __restrict__ gb, float* __restrict__ gates)
{
  __shared__ float mv[512];
  __shared__ float tmp[4];
  const int t = threadIdx.x;
  float s = 0.f;
  for (int b=0;b<128;b++) s += part[(b<<9)+t];
  mv[t] = s * (1.f/16384.f);
  __syncthreads();
  if (t < 4) {
    float a = gb[t];
    for (int d=0; d<512; ++d) a += mv[d]*gw[d*4+t];
    tmp[t] = a;
  }
  __syncthreads();
  if (t == 0) {
    const float m = fmaxf(fmaxf(tmp[0],tmp[1]),fmaxf(tmp[2],tmp[3]));
    float e[4]; float ss=0.f;
    for (int i=0;i<4;i++){ e[i]=__expf(tmp[i]-m); ss+=e[i]; }
    for (int i=0;i<4;i++) gates[i] = e[i]/ss;
  }
}

__global__ __launch_bounds__(1024) void moestat_k(const float* __restrict__ sc,
                                                  float* __restrict__ mstat, float* __restrict__ sstat)
{
  __shared__ float red[1024];
  const int e = blockIdx.x, t = threadIdx.x;
  const float* p = sc + e*16384;
  float m = -3.4e38f;
  for (int n=t; n<16384; n+=1024) m = fmaxf(m, p[n]);
  red[t] = m; __syncthreads();
  for (int o=512;o;o>>=1){ if (t<o) red[t]=fmaxf(red[t],red[t+o]); __syncthreads(); }
  m = red[0]; __syncthreads();
  float s = 0.f;
  for (int n=t; n<16384; n+=1024) s += __expf(p[n]-m);
  red[t] = s; __syncthreads();
  for (int o=512;o;o>>=1){ if (t<o) red[t]+=red[t+o]; __syncthreads(); }
  if (t==0){ mstat[e]=m; sstat[e]=red[0]; }
}

__global__ __launch_bounds__(256) void attnw_k(const float* __restrict__ sc, const float* __restrict__ gates,
    const float* __restrict__ mstat, const float* __restrict__ sstat, float* __restrict__ dout)
{
  const int n = blockIdx.x*256 + threadIdx.x;
  float w = 0.f;
#pragma unroll
  for (int e=0;e<4;e++) w += gates[e]*__expf(sc[e*16384+n]-mstat[e]) / sstat[e];
  dout[514 + n] = w;
}

// colfin + classifier fused; also writes bag to dout[0:512]
__global__ __launch_bounds__(512) void cls2_k(const float* __restrict__ bagp,
    const float* __restrict__ w1, const float* __restrict__ b1,
    const float* __restrict__ w2, const float* __restrict__ b2,
    const float* __restrict__ w3, const float* __restrict__ b3, float* __restrict__ dout)
{
  __shared__ float bag[512]; __shared__ float c1[256]; __shared__ float c2[128];
  const int tid = threadIdx.x;
  float s = 0.f;
  for (int b=0;b<128;b++) s += bagp[(b<<9)+tid];
  bag[tid] = s; dout[tid] = s;
  __syncthreads();
  if (tid < 256) {
    float a = b1[tid];
    for (int d=0; d<512; ++d) a += bag[d]*w1[d*256+tid];
    c1[tid] = fmaxf(a, 0.f);
  }
  __syncthreads();
  if (tid < 128) {
    float a2 = b2[tid];
    for (int d=0; d<256; ++d) a2 += c1[d]*w2[d*128+tid];
    c2[tid] = fmaxf(a2, 0.f);
  }
  __syncthreads();
  if (tid < 2) {
    float a3 = b3[tid];
    for (int d=0; d<128; ++d) a3 += c2[d]*w3[d*2+tid];
    dout[512 + tid] = a3;
  }
}

extern "C" void kernel_launch(void* const* d_in, const int* in_sizes, int n_in,
                              void* d_out, int out_size, void* d_ws, size_t ws_size,
                              hipStream_t stream)
{
  (void)in_sizes; (void)n_in; (void)out_size; (void)ws_size;
  const float* x      = (const float*)d_in[0];
  const float* enc_w1 = (const float*)d_in[1];
  const float* enc_b1 = (const float*)d_in[2];
  const float* enc_w2 = (const float*)d_in[3];
  const float* enc_b2 = (const float*)d_in[4];
  const float* enc_w3 = (const float*)d_in[5];
  const float* enc_b3 = (const float*)d_in[6];
  const float* q_w    = (const float*)d_in[7];
  const float* q_b    = (const float*)d_in[8];
  const float* k_w    = (const float*)d_in[9];
  const float* k_b    = (const float*)d_in[10];
  const float* v_w    = (const float*)d_in[11];
  const float* v_b    = (const float*)d_in[12];
  const float* o_w    = (const float*)d_in[13];
  const float* o_b    = (const float*)d_in[14];
  const float* E_w    = (const float*)d_in[15];
  const float* F_w    = (const float*)d_in[16];
  const float* ln1_g  = (const float*)d_in[17];
  const float* ln1_b  = (const float*)d_in[18];
  const float* ln2_g  = (const float*)d_in[19];
  const float* ln2_b  = (const float*)d_in[20];
  const float* gate_w = (const float*)d_in[21];
  const float* gate_b = (const float*)d_in[22];
  const float* moe_w1 = (const float*)d_in[23];
  const float* moe_b1 = (const float*)d_in[24];
  const float* moe_w2 = (const float*)d_in[25];
  // d_in[26] = moe_b2: drops out of the row-softmax (shift invariance)
  const float* cls_w1 = (const float*)d_in[27];
  const float* cls_b1 = (const float*)d_in[28];
  const float* cls_w2 = (const float*)d_in[29];
  const float* cls_b2 = (const float*)d_in[30];
  const float* cls_w3 = (const float*)d_in[31];
  const float* cls_b3 = (const float*)d_in[32];

  char* ws = (char*)d_ws;
  const size_t MB = 1024*1024;
  // big bf16 regions (time-multiplexed)
  unsigned short* x_bf  = (unsigned short*)(ws + 0);          // [16384][2048]  64MB
  unsigned short* h1    = (unsigned short*)(ws + 64*MB);      // [16384][1024]  32MB
  unsigned short* h2    = (unsigned short*)(ws + 0);          // [16384][512]   16MB (x_bf dead)
  unsigned short* feat  = (unsigned short*)(ws + 16*MB);      // 16MB
  unsigned short* qkv   = (unsigned short*)(ws + 32*MB);      // [16384][1536]  48MB (h1 dead after enc2)
  unsigned short* ao    = (unsigned short*)(ws + 80*MB);      // 16MB
  unsigned short* attno = (unsigned short*)(ws + 0);          // 16MB (h2 dead)
  unsigned short* att   = (unsigned short*)(ws + 96*MB);      // 16MB
  // persistent weights / small buffers
  unsigned short* w1t   = (unsigned short*)(ws + 112*MB);                 // [1024][2048] 4MB
  unsigned short* w2t   = (unsigned short*)(ws + 116*MB);                 // [512][1024]  1MB
  unsigned short* w3t   = (unsigned short*)(ws + 117*MB);                 // 0.5MB
  unsigned short* qkvw  = (unsigned short*)(ws + 117*MB + 512*1024);      // [1536][512] 1.5MB
  unsigned short* owt   = (unsigned short*)(ws + 119*MB);                 // 0.5MB
  unsigned short* mwt   = (unsigned short*)(ws + 119*MB + 512*1024);      // [4][256][512] 1MB
  float*  t1b   = (float*)(ws + 120*MB + 512*1024);                       // 0.5MB
  float*  redb  = (float*)(ws + 121*MB);                                  // 1MB
  unsigned short* Kcbf  = (unsigned short*)(ws + 122*MB);                 // 256KB
  unsigned short* Vctbf = (unsigned short*)(ws + 122*MB + 256*1024);      // 256KB
  float*  colp  = (float*)(ws + 122*MB + 512*1024);                       // 256KB
  float*  bagp  = (float*)(ws + 122*MB + 768*1024);                       // 256KB
  float*  qkvb  = (float*)(ws + 123*MB);                                  // 6KB
  float*  gatesp= (float*)(ws + 123*MB + 8192);
  float*  scp   = (float*)(ws + 123*MB + 16384);                          // [4][16384] 256KB
  float*  mstat = (float*)(ws + 123*MB + 16384 + 262144);
  float*  sstat = (float*)(ws + 123*MB + 16384 + 262144 + 64);
  float*  dout  = (float*)d_out;

  // ---- conversions ----
  cvtx_k<<<16384,256,0,stream>>>(x, x_bf);
  cvtw_k<<<dim3(32,16,1),256,0,stream>>>(enc_w1, w1t, 2000,1024,2048, 0,0);
  cvtw_k<<<dim3(16, 8,1),256,0,stream>>>(enc_w2, w2t, 1024, 512,1024, 0,0);
  cvtw_k<<<dim3( 8, 8,1),256,0,stream>>>(enc_w3, w3t,  512, 512, 512, 0,0);
  cvtw_k<<<dim3( 8, 8,1),256,0,stream>>>(q_w, qkvw,              512, 512, 512, 0,0);
  cvtw_k<<<dim3( 8, 8,1),256,0,stream>>>(k_w, qkvw + 512*512,    512, 512, 512, 0,0);
  cvtw_k<<<dim3( 8, 8,1),256,0,stream>>>(v_w, qkvw + 1024*512,   512, 512, 512, 0,0);
  cvtw_k<<<dim3( 8, 8,1),256,0,stream>>>(o_w,    owt,  512, 512, 512, 0,0);
  cvtw_k<<<dim3( 8, 4,4),256,0,stream>>>(moe_w1, mwt,  512, 256, 512, 512*256, 256*512);
  catb_k<<<1,512,0,stream>>>(q_b, k_b, v_b, qkvb);
  t1_k <<<dim3(256,2),256,0,stream>>>(E_w, F_w, t1b);

  // ---- encoder ----
  gemm3_k<1><<<dim3(4,64,1),512,0,stream>>>(x_bf, w1t, enc_b1, h1, 2048,2048,2048,1024);
  gemm2_k<1,false><<<dim3(4,128,1),256,0,stream>>>(h1, w2t, enc_b2, h2,   nullptr,nullptr, 1024,1024,1024, 512, 0,0,0);
  gemm2_k<1,false><<<dim3(4,128,1),256,0,stream>>>(h2, w3t, enc_b3, feat, nullptr,nullptr,  512, 512, 512, 512, 0,0,0);
  // ---- QKV (merged, N=1536) ----
  gemm2_k<0,false><<<dim3(12,128,1),256,0,stream>>>(feat, qkvw, qkvb, qkv, nullptr,nullptr, 512,512,512,1536, 0,0,0);
  // ---- linformer projections ----
  red_k<<<dim3(256,2),512,0,stream>>>(qkv, redb);
  kc_k <<<dim3(256,2),512,0,stream>>>(t1b, redb, Kcbf, Vctbf);
  // ---- fused attention ----
  attn_k<<<dim3(128,8),256,0,stream>>>(qkv, Kcbf, Vctbf, ao);
  // ---- output projection + residual + double LN ----
  gemm2_k<0,false><<<dim3(4,128,1),256,0,stream>>>(ao, owt, o_b, attno, nullptr,nullptr, 512,512,512,512, 0,0,0);
  ln2_k<<<16384,256,0,stream>>>(attno, feat, ln1_g, ln1_b, ln2_g, ln2_b, att);
  // ---- gates (also zeroes scp for the MoE atomics) ----
  wcolsum_k<<<128,256,0,stream>>>(att, nullptr, colp, scp);
  meangates_k<<<1,512,0,stream>>>(colp, gate_w, gate_b, gatesp);
  // ---- MoE expert attention (fused tanh+dot into epilogue) ----
  gemm2_k<0,true><<<dim3(2,128,4),256,0,stream>>>(att, mwt, moe_b1, nullptr, moe_w2, scp,
                                                  512,512,512,0, 0, 131072, 256);
  moestat_k<<<4,1024,0,stream>>>(scp, mstat, sstat);
  attnw_k<<<64,256,0,stream>>>(scp, gatesp, mstat, sstat, dout);
  // ---- bag + classifier ----
  wcolsum_k<<<128,256,0,stream>>>(att, dout + 514, bagp, nullptr);
  cls2_k<<<1,512,0,stream>>>(bagp, cls_w1, cls_b1, cls_w2, cls_b2, cls_w3, cls_b3, dout);
}

// Round 4
// 496.835 us; speedup vs baseline: 2.8988x; 1.1369x over previous
//
#include <hip/hip_runtime.h>

#define DI __device__ __forceinline__

DI float bf2f(unsigned short u){ unsigned int v = ((unsigned int)u)<<16; float f; __builtin_memcpy(&f,&v,4); return f; }
DI unsigned short f2bf(float f){ unsigned int v; __builtin_memcpy(&v,&f,4); v = v + 0x7FFFu + ((v>>16)&1u); return (unsigned short)(v>>16); }

typedef __attribute__((ext_vector_type(8))) short bf16x8;
typedef __attribute__((ext_vector_type(4))) float f32x4;

#define GLD_LDS16(src, dst) __builtin_amdgcn_global_load_lds( \
    (const __attribute__((address_space(1))) void*)(src), \
    (__attribute__((address_space(3))) void*)(dst), 16, 0, 0)

DI void barrier_() { asm volatile("" ::: "memory"); __builtin_amdgcn_s_barrier(); asm volatile("" ::: "memory"); }

// ---------------- bf16 MFMA GEMM, m97 structure + XCD swizzle (N=512 GEMMs) ----------------
template<int ACT>
__global__ __launch_bounds__(256) void gemm2_k(
    const unsigned short* __restrict__ A, const unsigned short* __restrict__ Bt,
    const float* __restrict__ bias, unsigned short* __restrict__ C,
    int K, int lda, int ldb, int ldc)
{
  __shared__ unsigned short As[8192];
  __shared__ unsigned short Bs[8192];
  const int tid = threadIdx.x, lane = tid & 63, wid = tid >> 6;
  const int wm = wid >> 1, wn = wid & 1;
  const int nx = gridDim.x;
  const int bid = blockIdx.x + nx*blockIdx.y;
  const int cpx = (nx*gridDim.y) >> 3;
  const int wg = (bid & 7)*cpx + (bid >> 3);
  const long long mBase = (long long)(wg / nx) << 7;
  const long long nBase = (long long)(wg % nx) << 7;
  const int q = lane >> 4, r15 = lane & 15;

  f32x4 acc[4][4];
#pragma unroll
  for (int i=0;i<4;i++)
#pragma unroll
    for (int j=0;j<4;j++)
#pragma unroll
      for (int r=0;r<4;r++) acc[i][j][r] = 0.f;

  const int nkt = K >> 6;
  for (int kt=0; kt<nkt; ++kt) {
    const int k0 = kt << 6;
#pragma unroll
    for (int it=0; it<4; ++it) {
      const int dbase = (it<<8) + (wid<<6);
      const int d = dbase + lane;
      const int row = d >> 3, cc = d & 7, sc = cc ^ (row & 7);
      GLD_LDS16(A + (mBase + row)*(long long)lda + k0 + (sc<<3), As + (dbase<<3));
      GLD_LDS16(Bt + (nBase + row)*(long long)ldb + k0 + (sc<<3), Bs + (dbase<<3));
    }
    __syncthreads();
#pragma unroll
    for (int ks=0; ks<2; ++ks) {
      bf16x8 af[4], bfr[4];
#pragma unroll
      for (int mi=0; mi<4; ++mi) {
        const int row = (wm<<6) + (mi<<4) + r15;
        const int ch = ((ks<<2)+q) ^ (row&7);
        af[mi] = *(const bf16x8*)(As + (row<<6) + (ch<<3));
      }
#pragma unroll
      for (int ni=0; ni<4; ++ni) {
        const int col = (wn<<6) + (ni<<4) + r15;
        const int ch = ((ks<<2)+q) ^ (col&7);
        bfr[ni] = *(const bf16x8*)(Bs + (col<<6) + (ch<<3));
      }
#pragma unroll
      for (int mi=0; mi<4; ++mi)
#pragma unroll
        for (int ni=0; ni<4; ++ni)
          acc[mi][ni] = __builtin_amdgcn_mfma_f32_16x16x32_bf16(af[mi], bfr[ni], acc[mi][ni], 0, 0, 0);
    }
    __syncthreads();
  }
#pragma unroll
  for (int ni=0; ni<4; ++ni) {
    const long long n = nBase + (wn<<6) + (ni<<4) + r15;
    const float bval = bias[n];
#pragma unroll
    for (int mi=0; mi<4; ++mi) {
#pragma unroll
      for (int r=0; r<4; ++r) {
        const long long m = mBase + (wm<<6) + (mi<<4) + (q<<2) + r;
        float v = acc[mi][ni][r] + bval;
        if constexpr (ACT==1) v = fmaxf(v, 0.f);
        C[m*(long long)ldc + n] = f2bf(v);
      }
    }
  }
}

// ---------------- gemm4: 256x256 tile, 4-phase counted-vmcnt pipeline ----------------
// 512 thr = 8 waves (2M x 4N), wave tile 128x64, BK=64, double-buffered 128KiB LDS.
// Stage issue order per tile: B0,B1,B2,B3,A0,A2,A1,A3 (2 per phase).
// Collective waits: ph0 vmcnt(2)+barrier (B*+A0,A2 in), ph2 vmcnt(4)+barrier (A1,A3 in).
// MOE: instead of writing C, accumulate sum_n tanh(v+b)*w2[n] into scp[n>>8][m].
template<int ACT, bool MOE>
__global__ __launch_bounds__(512,2) void gemm4_k(
    const unsigned short* __restrict__ A, const unsigned short* __restrict__ Bt,
    const float* __restrict__ bias, unsigned short* __restrict__ C,
    const float* __restrict__ w2, float* __restrict__ scp,
    int K, int lda, int ldb, int ldc)
{
  __shared__ unsigned short As[2][16384];
  __shared__ unsigned short Bs[2][16384];
  const int tid = threadIdx.x, lane = tid & 63, wid = tid >> 6;
  const int wm = wid >> 2, wn = wid & 3;
  const int q = lane >> 4, r15 = lane & 15;
  const int nx = gridDim.x;
  const int bid = blockIdx.x + nx*blockIdx.y;
  const int cpx = (nx*gridDim.y) >> 3;
  const int wg = (bid & 7)*cpx + (bid >> 3);
  const long long mBase = (long long)(wg / nx) << 8;
  const long long nBase = (long long)(wg % nx) << 8;

  f32x4 acc[8][4];
#pragma unroll
  for (int i=0;i<8;i++)
#pragma unroll
    for (int j=0;j<4;j++)
#pragma unroll
      for (int r=0;r<4;r++) acc[i][j][r] = 0.f;

  const int NT = K >> 6;

#define G4_STA(j, nb, kk) { const int d_ = tid + ((j)<<9); const int row_ = d_>>3, c_ = d_&7, sc_ = c_ ^ (row_&7); \
    GLD_LDS16(A + (mBase+row_)*(long long)lda + (kk) + (sc_<<3), &As[nb][d_<<3]); }
#define G4_STB(j, nb, kk) { const int d_ = tid + ((j)<<9); const int row_ = d_>>3, c_ = d_&7, sc_ = c_ ^ (row_&7); \
    GLD_LDS16(Bt + (nBase+row_)*(long long)ldb + (kk) + (sc_<<3), &Bs[nb][d_<<3]); }

  // prologue: stage tile 0 in canonical issue order
  G4_STB(0,0,0); G4_STB(1,0,0); G4_STB(2,0,0); G4_STB(3,0,0);
  G4_STA(0,0,0); G4_STA(2,0,0); G4_STA(1,0,0); G4_STA(3,0,0);

  for (int t=0; t<NT; ++t) {
    const int b = t & 1, nb = b ^ 1;
    const bool more = (t+1 < NT);
    const int k1 = (t+1) << 6;
    bf16x8 aF[8], bL[4], bH[4];

    // ---- phase 0: (m-lo, n-lo) ----
    asm volatile("s_waitcnt vmcnt(2)" ::: "memory");
    barrier_();
#pragma unroll
    for (int mi=0; mi<4; ++mi)
#pragma unroll
      for (int ks=0; ks<2; ++ks) {
        const int row = (wm<<7) + (mi<<4) + r15;
        const int ch = ((ks<<2)+q) ^ (row&7);
        aF[mi*2+ks] = *(const bf16x8*)&As[b][(row<<6) + (ch<<3)];
      }
#pragma unroll
    for (int ni=0; ni<2; ++ni)
#pragma unroll
      for (int ks=0; ks<2; ++ks) {
        const int col = (wn<<6) + (ni<<4) + r15;
        const int ch = ((ks<<2)+q) ^ (col&7);
        bL[ni*2+ks] = *(const bf16x8*)&Bs[b][(col<<6) + (ch<<3)];
      }
    if (more) { G4_STB(0,nb,k1); G4_STB(1,nb,k1); }
    __builtin_amdgcn_s_setprio(1);
#pragma unroll
    for (int mi=0; mi<4; ++mi)
#pragma unroll
      for (int ni=0; ni<2; ++ni)
#pragma unroll
        for (int ks=0; ks<2; ++ks)
          acc[mi][ni] = __builtin_amdgcn_mfma_f32_16x16x32_bf16(aF[mi*2+ks], bL[ni*2+ks], acc[mi][ni], 0,0,0);
    __builtin_amdgcn_s_setprio(0);
    barrier_();

    // ---- phase 1: (m-lo, n-hi) ----
#pragma unroll
    for (int ni=0; ni<2; ++ni)
#pragma unroll
      for (int ks=0; ks<2; ++ks) {
        const int col = (wn<<6) + ((ni+2)<<4) + r15;
        const int ch = ((ks<<2)+q) ^ (col&7);
        bH[ni*2+ks] = *(const bf16x8*)&Bs[b][(col<<6) + (ch<<3)];
      }
    if (more) { G4_STB(2,nb,k1); G4_STB(3,nb,k1); }
    __builtin_amdgcn_s_setprio(1);
#pragma unroll
    for (int mi=0; mi<4; ++mi)
#pragma unroll
      for (int ni=0; ni<2; ++ni)
#pragma unroll
        for (int ks=0; ks<2; ++ks)
          acc[mi][ni+2] = __builtin_amdgcn_mfma_f32_16x16x32_bf16(aF[mi*2+ks], bH[ni*2+ks], acc[mi][ni+2], 0,0,0);
    __builtin_amdgcn_s_setprio(0);
    barrier_();

    // ---- phase 2: (m-hi, n-lo) ----
    if (more) { asm volatile("s_waitcnt vmcnt(4)" ::: "memory"); }
    else      { asm volatile("s_waitcnt vmcnt(0)" ::: "memory"); }
    barrier_();
#pragma unroll
    for (int mi=0; mi<4; ++mi)
#pragma unroll
      for (int ks=0; ks<2; ++ks) {
        const int row = (wm<<7) + ((mi+4)<<4) + r15;
        const int ch = ((ks<<2)+q) ^ (row&7);
        aF[mi*2+ks] = *(const bf16x8*)&As[b][(row<<6) + (ch<<3)];
      }
    if (more) { G4_STA(0,nb,k1); G4_STA(2,nb,k1); }
    __builtin_amdgcn_s_setprio(1);
#pragma unroll
    for (int mi=0; mi<4; ++mi)
#pragma unroll
      for (int ni=0; ni<2; ++ni)
#pragma unroll
        for (int ks=0; ks<2; ++ks)
          acc[mi+4][ni] = __builtin_amdgcn_mfma_f32_16x16x32_bf16(aF[mi*2+ks], bL[ni*2+ks], acc[mi+4][ni], 0,0,0);
    __builtin_amdgcn_s_setprio(0);
    barrier_();

    // ---- phase 3: (m-hi, n-hi) ----
    if (more) { G4_STA(1,nb,k1); G4_STA(3,nb,k1); }
    __builtin_amdgcn_s_setprio(1);
#pragma unroll
    for (int mi=0; mi<4; ++mi)
#pragma unroll
      for (int ni=0; ni<2; ++ni)
#pragma unroll
        for (int ks=0; ks<2; ++ks)
          acc[mi+4][ni+2] = __builtin_amdgcn_mfma_f32_16x16x32_bf16(aF[mi*2+ks], bH[ni*2+ks], acc[mi+4][ni+2], 0,0,0);
    __builtin_amdgcn_s_setprio(0);
    barrier_();
  }
#undef G4_STA
#undef G4_STB

  if constexpr (MOE) {
    const int e = (int)(nBase >> 8);   // 256-aligned blocks -> one expert per block
#pragma unroll
    for (int mi=0; mi<8; ++mi) {
#pragma unroll
      for (int r=0; r<4; ++r) {
        float p = 0.f;
#pragma unroll
        for (int ni=0; ni<4; ++ni) {
          const int n = (int)nBase + (wn<<6) + (ni<<4) + r15;
          const float v = acc[mi][ni][r] + bias[n];
          const float th = 1.f - 2.f/(__expf(2.f*v) + 1.f);
          p += th * w2[n];
        }
        p += __shfl_xor(p,1,64); p += __shfl_xor(p,2,64);
        p += __shfl_xor(p,4,64); p += __shfl_xor(p,8,64);
        if (r15 == 0) {
          const long long m = mBase + (wm<<7) + (mi<<4) + (q<<2) + r;
          atomicAdd(scp + ((long long)e<<14) + m, p);
        }
      }
    }
  } else {
#pragma unroll
    for (int ni=0; ni<4; ++ni) {
      const long long n = nBase + (wn<<6) + (ni<<4) + r15;
      const float bval = bias[n];
#pragma unroll
      for (int mi=0; mi<8; ++mi) {
#pragma unroll
        for (int r=0; r<4; ++r) {
          const long long m = mBase + (wm<<7) + (mi<<4) + (q<<2) + r;
          float v = acc[mi][ni][r] + bval;
          if constexpr (ACT==1) v = fmaxf(v, 0.f);
          C[m*(long long)ldc + n] = f2bf(v);
        }
      }
    }
  }
}

// ---------------- conversions ----------------
__global__ __launch_bounds__(256) void cvtx_k(const float* __restrict__ x, unsigned short* __restrict__ xb)
{
  const long long id = (long long)blockIdx.x*256 + threadIdx.x;
  const long long row = id >> 8; const int c = (int)(id & 255);
  bf16x8 v;
  if (c < 250) {
    const float* p = x + row*2000 + c*8;
    const float4 f0 = *(const float4*)p, f1 = *(const float4*)(p+4);
    v[0]=(short)f2bf(f0.x); v[1]=(short)f2bf(f0.y); v[2]=(short)f2bf(f0.z); v[3]=(short)f2bf(f0.w);
    v[4]=(short)f2bf(f1.x); v[5]=(short)f2bf(f1.y); v[6]=(short)f2bf(f1.z); v[7]=(short)f2bf(f1.w);
  } else {
#pragma unroll
    for (int j=0;j<8;j++) v[j]=0;
  }
  *(bf16x8*)(xb + (id<<3)) = v;
}

__global__ __launch_bounds__(256) void cvtw_k(const float* __restrict__ B, unsigned short* __restrict__ Bt,
    int K, int N, int Kpad, long long bszi, long long bszo)
{
  __shared__ float tile[64][65];
  const float* Bz = B + (long long)blockIdx.z*bszi;
  unsigned short* Bo = Bt + (long long)blockIdx.z*bszo;
  const int k0 = blockIdx.x<<6, n0 = blockIdx.y<<6;
  const int c = threadIdx.x & 63, rg = threadIdx.x >> 6;
#pragma unroll
  for (int j=0;j<16;j++){
    const int r = (j<<2) + rg;
    const int k = k0 + r;
    tile[r][c] = (k < K) ? Bz[(long long)k*N + n0 + c] : 0.f;
  }
  __syncthreads();
#pragma unroll
  for (int j=0;j<16;j++){
    const int nn = (j<<2) + rg;
    Bo[(long long)(n0+nn)*Kpad + k0 + c] = f2bf(tile[c][nn]);
  }
}

// five 512x512 transposes in one launch (z selects)
__global__ __launch_bounds__(256) void cvtw5_k(
    const float* __restrict__ s0, const float* __restrict__ s1, const float* __restrict__ s2,
    const float* __restrict__ s3, const float* __restrict__ s4,
    unsigned short* __restrict__ d0, unsigned short* __restrict__ d1, unsigned short* __restrict__ d2,
    unsigned short* __restrict__ d3, unsigned short* __restrict__ d4)
{
  __shared__ float tile[64][65];
  const int z = blockIdx.z;
  const float* Bz = (z==0)?s0:(z==1)?s1:(z==2)?s2:(z==3)?s3:s4;
  unsigned short* Bo = (z==0)?d0:(z==1)?d1:(z==2)?d2:(z==3)?d3:d4;
  const int k0 = blockIdx.x<<6, n0 = blockIdx.y<<6;
  const int c = threadIdx.x & 63, rg = threadIdx.x >> 6;
#pragma unroll
  for (int j=0;j<16;j++){
    const int r = (j<<2) + rg;
    tile[r][c] = Bz[(long long)(k0+r)*512 + n0 + c];
  }
  __syncthreads();
#pragma unroll
  for (int j=0;j<16;j++){
    const int nn = (j<<2) + rg;
    Bo[(long long)(n0+nn)*512 + k0 + c] = f2bf(tile[c][nn]);
  }
}

// ---------------- bilinear-resize weight generation + qkv bias concat ----------------
__global__ __launch_bounds__(256) void t1cat_k(const float* __restrict__ Ew, const float* __restrict__ Fw,
    float* __restrict__ t1, const float* __restrict__ qb, const float* __restrict__ kb,
    const float* __restrict__ vb, float* __restrict__ qkvb)
{
  const int k = blockIdx.x, which = blockIdx.y, c = threadIdx.x;
  if (which == 0 && k < 3) {
    const float* src = (k==0) ? qb : (k==1) ? kb : vb;
    qkvb[k*512 + c]       = src[c];
    qkvb[k*512 + 256 + c] = src[256 + c];
  }
  const float* W = which ? Fw : Ew;
  const float ksc = 39.0625f;
  const float inv = 1.f/39.0625f;
  const float sf = (k + 0.5f)*ksc - 0.5f;
  int ilo = (int)ceilf(sf - ksc); if (ilo < 0) ilo = 0;
  int ihi = (int)floorf(sf + ksc); if (ihi > 9999) ihi = 9999;
  float acc = 0.f, wsum = 0.f;
  for (int i=ilo; i<=ihi; ++i) {
    const float w = 1.f - fabsf(sf - (float)i)*inv;
    if (w > 0.f) { acc += w * W[c*10000 + i]; wsum += w; }
  }
  t1[(which*256 + k)*256 + c] = acc / wsum;
}

__global__ __launch_bounds__(512) void red_k(const unsigned short* __restrict__ qkv,
                                             float* __restrict__ red)
{
  const int c = blockIdx.x, which = blockIdx.y, j = threadIdx.x;
  const unsigned short* X = qkv + (which ? 1024 : 512);
  int nlo = 64*c - 32; if (nlo < 0) nlo = 0;
  int nhi = 64*c + 95; if (nhi > 16383) nhi = 16383;
  float acc = 0.f;
  for (int n=nlo; n<=nhi; ++n) {
    float sf = (n + 0.5f)*0.015625f - 0.5f;
    sf = fminf(fmaxf(sf, 0.f), 255.f);
    const int c0 = (int)sf;
    const float f = sf - (float)c0;
    float w = 0.f;
    if (c == c0) w = 1.f - f;
    else if (c == c0+1) w = f;
    if (w != 0.f) acc += w * bf2f(X[(long long)n*1536 + j]);
  }
  red[(which*256 + c)*512 + j] = acc;
}

__global__ __launch_bounds__(512) void kc_k(const float* __restrict__ t1, const float* __restrict__ red,
                                            unsigned short* __restrict__ Kc, unsigned short* __restrict__ Vct)
{
  const int k = blockIdx.x, which = blockIdx.y, j = threadIdx.x;
  const float* T = t1 + (which*256 + k)*256;
  const float* R = red + which*131072;
  float acc = 0.f;
  for (int c=0; c<256; ++c) acc += T[c] * R[c*512 + j];
  const int h = j >> 6, d = j & 63;
  if (which == 0) Kc [(h<<14) + (k<<6) + d] = f2bf(acc);
  else            Vct[(h<<14) + (d<<8) + k] = f2bf(acc);
}

// ---------------- fused linformer attention ----------------
__global__ __launch_bounds__(256) void attn_k(
    const unsigned short* __restrict__ Qg, const unsigned short* __restrict__ Kc,
    const unsigned short* __restrict__ Vct, unsigned short* __restrict__ ao)
{
  __shared__ unsigned short Ks[16384];
  __shared__ unsigned short Vs[16384];
  __shared__ unsigned short Ps[32768];
  const int h = blockIdx.y;
  const long long mBase = (long long)blockIdx.x << 7;
  const int tid = threadIdx.x, lane = tid & 63, wid = tid >> 6;
  const int q = lane >> 4, r15 = lane & 15;

#pragma unroll
  for (int it=0; it<8; ++it) {
    const int dbase = (it<<8) + (wid<<6);
    const int d = dbase + lane;
    {
      const int row = d >> 3, cc = d & 7, sc = cc ^ (row & 7);
      GLD_LDS16(Kc + (h<<14) + (row<<6) + (sc<<3), Ks + (dbase<<3));
    }
    {
      const int row = d >> 5, cc = d & 31, sc = (cc & 24) | ((cc ^ (row & 7)) & 7);
      GLD_LDS16(Vct + (h<<14) + (row<<8) + (sc<<3), Vs + (dbase<<3));
    }
  }
  __syncthreads();

  f32x4 acc[2][16];
#pragma unroll
  for (int mi=0;mi<2;mi++)
#pragma unroll
    for (int ni=0;ni<16;ni++)
#pragma unroll
      for (int r=0;r<4;r++) acc[mi][ni][r] = 0.f;

#pragma unroll
  for (int ks=0; ks<2; ++ks) {
    bf16x8 af[2];
#pragma unroll
    for (int mi=0; mi<2; ++mi) {
      const long long m = mBase + (wid<<5) + (mi<<4) + r15;
      af[mi] = *(const bf16x8*)(Qg + m*1536 + (h<<6) + (ks<<5) + (q<<3));
    }
#pragma unroll
    for (int ni=0; ni<16; ++ni) {
      const int col = (ni<<4) + r15;
      const int ch = ((ks<<2)+q) ^ (col&7);
      const bf16x8 bv = *(const bf16x8*)(Ks + (col<<6) + (ch<<3));
      acc[0][ni] = __builtin_amdgcn_mfma_f32_16x16x32_bf16(af[0], bv, acc[0][ni], 0,0,0);
      acc[1][ni] = __builtin_amdgcn_mfma_f32_16x16x32_bf16(af[1], bv, acc[1][ni], 0,0,0);
    }
  }

#pragma unroll
  for (int mi=0; mi<2; ++mi) {
#pragma unroll
    for (int r=0; r<4; ++r) {
      float mx = -3.4e38f;
#pragma unroll
      for (int ni=0; ni<16; ++ni) mx = fmaxf(mx, acc[mi][ni][r]);
      mx = fmaxf(mx, __shfl_xor(mx,1,64)); mx = fmaxf(mx, __shfl_xor(mx,2,64));
      mx = fmaxf(mx, __shfl_xor(mx,4,64)); mx = fmaxf(mx, __shfl_xor(mx,8,64));
      float s = 0.f;
#pragma unroll
      for (int ni=0; ni<16; ++ni) {
        const float e = __expf((acc[mi][ni][r] - mx)*0.125f);
        acc[mi][ni][r] = e; s += e;
      }
      s += __shfl_xor(s,1,64); s += __shfl_xor(s,2,64);
      s += __shfl_xor(s,4,64); s += __shfl_xor(s,8,64);
      const float inv = 1.f / s;
      const int row = (wid<<5) + (mi<<4) + (q<<2) + r;
#pragma unroll
      for (int ni=0; ni<16; ++ni) {
        const int col = (ni<<4) + r15;
        const int ch = col >> 3;
        const int chs = (ch & 24) | ((ch ^ (row & 7)) & 7);
        Ps[(row<<8) + (chs<<3) + (col&7)] = f2bf(acc[mi][ni][r]*inv);
      }
    }
  }
  __syncthreads();

  f32x4 o[2][4];
#pragma unroll
  for (int mi=0;mi<2;mi++)
#pragma unroll
    for (int ni=0;ni<4;ni++)
#pragma unroll
      for (int r=0;r<4;r++) o[mi][ni][r] = 0.f;

#pragma unroll
  for (int kk=0; kk<8; ++kk) {
    bf16x8 pa[2];
#pragma unroll
    for (int mi=0; mi<2; ++mi) {
      const int row = (wid<<5) + (mi<<4) + r15;
      const int ch = (kk<<2) + q;
      const int chs = (ch & 24) | ((ch ^ (row & 7)) & 7);
      pa[mi] = *(const bf16x8*)(Ps + (row<<8) + (chs<<3));
    }
#pragma unroll
    for (int ni=0; ni<4; ++ni) {
      const int vrow = (ni<<4) + r15;
      const int ch = (kk<<2) + q;
      const int chs = (ch & 24) | ((ch ^ (vrow & 7)) & 7);
      const bf16x8 bv = *(const bf16x8*)(Vs + (vrow<<8) + (chs<<3));
      o[0][ni] = __builtin_amdgcn_mfma_f32_16x16x32_bf16(pa[0], bv, o[0][ni], 0,0,0);
      o[1][ni] = __builtin_amdgcn_mfma_f32_16x16x32_bf16(pa[1], bv, o[1][ni], 0,0,0);
    }
  }
#pragma unroll
  for (int mi=0; mi<2; ++mi)
#pragma unroll
    for (int ni=0; ni<4; ++ni)
#pragma unroll
      for (int r=0; r<4; ++r) {
        const long long m = mBase + (wid<<5) + (mi<<4) + (q<<2) + r;
        ao[m*512 + (h<<6) + (ni<<4) + r15] = f2bf(o[mi][ni][r]);
      }
}

// ---------------- double layernorm on (attn_out + feat) ----------------
__global__ __launch_bounds__(256) void ln2_k(
    const unsigned short* __restrict__ x1b, const unsigned short* __restrict__ x2b,
    const float* __restrict__ g1, const float* __restrict__ b1,
    const float* __restrict__ g2, const float* __restrict__ b2,
    unsigned short* __restrict__ out)
{
  __shared__ float sred[8];
  const int tid = threadIdx.x, lane = tid & 63, wid = tid >> 6;
  const long long base = (long long)blockIdx.x << 9;
  const float x0 = bf2f(x1b[base+tid])     + bf2f(x2b[base+tid]);
  const float x1 = bf2f(x1b[base+256+tid]) + bf2f(x2b[base+256+tid]);
  float s = x0+x1, qq = x0*x0 + x1*x1;
#pragma unroll
  for (int o=32;o;o>>=1){ s += __shfl_xor(s,o,64); qq += __shfl_xor(qq,o,64); }
  if (lane==0){ sred[wid]=s; sred[4+wid]=qq; }
  __syncthreads();
  float mean = (sred[0]+sred[1]+sred[2]+sred[3]) * (1.f/512.f);
  float var  = (sred[4]+sred[5]+sred[6]+sred[7]) * (1.f/512.f) - mean*mean;
  float rs = rsqrtf(var + 1e-5f);
  const float y0 = (x0-mean)*rs*g1[tid]     + b1[tid];
  const float y1 = (x1-mean)*rs*g1[tid+256] + b1[tid+256];
  __syncthreads();
  s = y0+y1; qq = y0*y0 + y1*y1;
#pragma unroll
  for (int o=32;o;o>>=1){ s += __shfl_xor(s,o,64); qq += __shfl_xor(qq,o,64); }
  if (lane==0){ sred[wid]=s; sred[4+wid]=qq; }
  __syncthreads();
  mean = (sred[0]+sred[1]+sred[2]+sred[3]) * (1.f/512.f);
  var  = (sred[4]+sred[5]+sred[6]+sred[7]) * (1.f/512.f) - mean*mean;
  rs = rsqrtf(var + 1e-5f);
  out[base+tid]     = f2bf((y0-mean)*rs*g2[tid]     + b2[tid]);
  out[base+256+tid] = f2bf((y1-mean)*rs*g2[tid+256] + b2[tid+256]);
}

// ---------------- pooling / gates / classifier ----------------
__global__ __launch_bounds__(256) void wcolsum_k(const unsigned short* __restrict__ att,
                                                 float* __restrict__ part, float* __restrict__ zf)
{
  const int c = threadIdx.x;
  if (zf) { zf[((long long)blockIdx.x<<9)+c] = 0.f; zf[((long long)blockIdx.x<<9)+c+256] = 0.f; }
  const long long r0 = (long long)blockIdx.x * 128;
  float a0=0.f, a1=0.f;
  for (int r=0;r<128;r++){
    const unsigned short* p = att + ((r0+r)<<9);
    a0 += bf2f(p[c]); a1 += bf2f(p[c+256]);
  }
  part[((long long)blockIdx.x<<9)+c]     = a0;
  part[((long long)blockIdx.x<<9)+c+256] = a1;
}

__global__ __launch_bounds__(512) void meangates_k(const float* __restrict__ part,
    const float* __restrict__ gw, const float* __restrict__ gb, float* __restrict__ gates)
{
  __shared__ float mv[512];
  __shared__ float tmp[4];
  const int t = threadIdx.x;
  float s = 0.f;
  for (int b=0;b<128;b++) s += part[(b<<9)+t];
  mv[t] = s * (1.f/16384.f);
  __syncthreads();
  if (t < 4) {
    float a = gb[t];
    for (int d=0; d<512; ++d) a += mv[d]*gw[d*4+t];
    tmp[t] = a;
  }
  __syncthreads();
  if (t == 0) {
    const float m = fmaxf(fmaxf(tmp[0],tmp[1]),fmaxf(tmp[2],tmp[3]));
    float e[4]; float ss=0.f;
    for (int i=0;i<4;i++){ e[i]=__expf(tmp[i]-m); ss+=e[i]; }
    for (int i=0;i<4;i++) gates[i] = e[i]/ss;
  }
}

__global__ __launch_bounds__(1024) void moestat_k(const float* __restrict__ sc,
                                                  float* __restrict__ mstat, float* __restrict__ sstat)
{
  __shared__ float red[1024];
  const int e = blockIdx.x, t = threadIdx.x;
  const float* p = sc + e*16384;
  float m = -3.4e38f;
  for (int n=t; n<16384; n+=1024) m = fmaxf(m, p[n]);
  red[t] = m; __syncthreads();
  for (int o=512;o;o>>=1){ if (t<o) red[t]=fmaxf(red[t],red[t+o]); __syncthreads(); }
  m = red[0]; __syncthreads();
  float s = 0.f;
  for (int n=t; n<16384; n+=1024) s += __expf(p[n]-m);
  red[t] = s; __syncthreads();
  for (int o=512;o;o>>=1){ if (t<o) red[t]+=red[t+o]; __syncthreads(); }
  if (t==0){ mstat[e]=m; sstat[e]=red[0]; }
}

// attn-weight computation + weighted column-sum partials (fused)
__global__ __launch_bounds__(256) void wbag_k(const unsigned short* __restrict__ att,
    const float* __restrict__ scp, const float* __restrict__ gates,
    const float* __restrict__ mstat, const float* __restrict__ sstat,
    float* __restrict__ part, float* __restrict__ dout)
{
  __shared__ float wrow[128];
  const int c = threadIdx.x;
  const long long r0 = (long long)blockIdx.x * 128;
  if (c < 128) {
    const long long n = r0 + c;
    float w = 0.f;
#pragma unroll
    for (int e=0;e<4;e++) w += gates[e]*__expf(scp[((long long)e<<14)+n]-mstat[e]) / sstat[e];
    wrow[c] = w;
    dout[514 + n] = w;
  }
  __syncthreads();
  float a0=0.f, a1=0.f;
  for (int r=0;r<128;r++){
    const float w = wrow[r];
    const unsigned short* p = att + ((r0+r)<<9);
    a0 += w*bf2f(p[c]); a1 += w*bf2f(p[c+256]);
  }
  part[((long long)blockIdx.x<<9)+c]     = a0;
  part[((long long)blockIdx.x<<9)+c+256] = a1;
}

__global__ __launch_bounds__(512) void cls2_k(const float* __restrict__ bagp,
    const float* __restrict__ w1, const float* __restrict__ b1,
    const float* __restrict__ w2, const float* __restrict__ b2,
    const float* __restrict__ w3, const float* __restrict__ b3, float* __restrict__ dout)
{
  __shared__ float bag[512]; __shared__ float c1[256]; __shared__ float c2[128];
  const int tid = threadIdx.x;
  float s = 0.f;
  for (int b=0;b<128;b++) s += bagp[(b<<9)+tid];
  bag[tid] = s; dout[tid] = s;
  __syncthreads();
  if (tid < 256) {
    float a = b1[tid];
    for (int d=0; d<512; ++d) a += bag[d]*w1[d*256+tid];
    c1[tid] = fmaxf(a, 0.f);
  }
  __syncthreads();
  if (tid < 128) {
    float a2 = b2[tid];
    for (int d=0; d<256; ++d) a2 += c1[d]*w2[d*128+tid];
    c2[tid] = fmaxf(a2, 0.f);
  }
  __syncthreads();
  if (tid < 2) {
    float a3 = b3[tid];
    for (int d=0; d<128; ++d) a3 += c2[d]*w3[d*2+tid];
    dout[512 + tid] = a3;
  }
}

extern "C" void kernel_launch(void* const* d_in, const int* in_sizes, int n_in,
                              void* d_out, int out_size, void* d_ws, size_t ws_size,
                              hipStream_t stream)
{
  (void)in_sizes; (void)n_in; (void)out_size; (void)ws_size;
  const float* x      = (const float*)d_in[0];
  const float* enc_w1 = (const float*)d_in[1];
  const float* enc_b1 = (const float*)d_in[2];
  const float* enc_w2 = (const float*)d_in[3];
  const float* enc_b2 = (const float*)d_in[4];
  const float* enc_w3 = (const float*)d_in[5];
  const float* enc_b3 = (const float*)d_in[6];
  const float* q_w    = (const float*)d_in[7];
  const float* q_b    = (const float*)d_in[8];
  const float* k_w    = (const float*)d_in[9];
  const float* k_b    = (const float*)d_in[10];
  const float* v_w    = (const float*)d_in[11];
  const float* v_b    = (const float*)d_in[12];
  const float* o_w    = (const float*)d_in[13];
  const float* o_b    = (const float*)d_in[14];
  const float* E_w    = (const float*)d_in[15];
  const float* F_w    = (const float*)d_in[16];
  const float* ln1_g  = (const float*)d_in[17];
  const float* ln1_b  = (const float*)d_in[18];
  const float* ln2_g  = (const float*)d_in[19];
  const float* ln2_b  = (const float*)d_in[20];
  const float* gate_w = (const float*)d_in[21];
  const float* gate_b = (const float*)d_in[22];
  const float* moe_w1 = (const float*)d_in[23];
  const float* moe_b1 = (const float*)d_in[24];   // [4][256] flat = merged bias
  const float* moe_w2 = (const float*)d_in[25];   // [4][256] flat = merged w2
  // d_in[26] = moe_b2: drops out of the row-softmax (shift invariance)
  const float* cls_w1 = (const float*)d_in[27];
  const float* cls_b1 = (const float*)d_in[28];
  const float* cls_w2 = (const float*)d_in[29];
  const float* cls_b2 = (const float*)d_in[30];
  const float* cls_w3 = (const float*)d_in[31];
  const float* cls_b3 = (const float*)d_in[32];

  char* ws = (char*)d_ws;
  const size_t MB = 1024*1024;
  unsigned short* x_bf  = (unsigned short*)(ws + 0);          // [16384][2048]  64MB
  unsigned short* h1    = (unsigned short*)(ws + 64*MB);      // [16384][1024]  32MB
  unsigned short* h2    = (unsigned short*)(ws + 0);          // 16MB (x_bf dead)
  unsigned short* feat  = (unsigned short*)(ws + 16*MB);      // 16MB
  unsigned short* qkv   = (unsigned short*)(ws + 32*MB);      // [16384][1536]  48MB (h1 dead)
  unsigned short* ao    = (unsigned short*)(ws + 80*MB);      // 16MB
  unsigned short* attno = (unsigned short*)(ws + 0);          // 16MB (h2 dead)
  unsigned short* att   = (unsigned short*)(ws + 96*MB);      // 16MB
  unsigned short* w1t   = (unsigned short*)(ws + 112*MB);                 // [1024][2048] 4MB
  unsigned short* w2t   = (unsigned short*)(ws + 116*MB);                 // [512][1024]  1MB
  unsigned short* w3t   = (unsigned short*)(ws + 117*MB);                 // 0.5MB
  unsigned short* qkvw  = (unsigned short*)(ws + 117*MB + 512*1024);      // [1536][512] 1.5MB
  unsigned short* owt   = (unsigned short*)(ws + 119*MB);                 // 0.5MB
  unsigned short* mwt   = (unsigned short*)(ws + 119*MB + 512*1024);      // [1024][512] 1MB (merged experts)
  float*  t1b   = (float*)(ws + 120*MB + 512*1024);                       // 0.5MB
  float*  redb  = (float*)(ws + 121*MB);                                  // 1MB
  unsigned short* Kcbf  = (unsigned short*)(ws + 122*MB);                 // 256KB
  unsigned short* Vctbf = (unsigned short*)(ws + 122*MB + 256*1024);      // 256KB
  float*  colp  = (float*)(ws + 122*MB + 512*1024);                       // 256KB
  float*  bagp  = (float*)(ws + 122*MB + 768*1024);                       // 256KB
  float*  qkvb  = (float*)(ws + 123*MB);                                  // 6KB
  float*  gatesp= (float*)(ws + 123*MB + 8192);
  float*  scp   = (float*)(ws + 123*MB + 16384);                          // [4][16384] 256KB
  float*  mstat = (float*)(ws + 123*MB + 16384 + 262144);
  float*  sstat = (float*)(ws + 123*MB + 16384 + 262144 + 64);
  float*  dout  = (float*)d_out;

  // ---- conversions / prep ----
  cvtx_k<<<16384,256,0,stream>>>(x, x_bf);
  cvtw_k<<<dim3(32,16,1),256,0,stream>>>(enc_w1, w1t, 2000,1024,2048, 0,0);
  cvtw_k<<<dim3(16, 8,1),256,0,stream>>>(enc_w2, w2t, 1024, 512,1024, 0,0);
  cvtw5_k<<<dim3(8,8,5),256,0,stream>>>(enc_w3, q_w, k_w, v_w, o_w,
                                        w3t, qkvw, qkvw + 512*512, qkvw + 1024*512, owt);
  cvtw_k<<<dim3( 8, 4,4),256,0,stream>>>(moe_w1, mwt, 512, 256, 512, 512*256, 256*512);
  t1cat_k<<<dim3(256,2),256,0,stream>>>(E_w, F_w, t1b, q_b, k_b, v_b, qkvb);

  // ---- encoder ----
  gemm4_k<1,false><<<dim3(4,64,1),512,0,stream>>>(x_bf, w1t, enc_b1, h1, nullptr,nullptr, 2048,2048,2048,1024);
  gemm2_k<1><<<dim3(4,128,1),256,0,stream>>>(h1, w2t, enc_b2, h2,   1024,1024,1024, 512);
  gemm2_k<1><<<dim3(4,128,1),256,0,stream>>>(h2, w3t, enc_b3, feat,  512, 512, 512, 512);
  // ---- QKV (merged, N=1536) ----
  gemm4_k<0,false><<<dim3(6,64,1),512,0,stream>>>(feat, qkvw, qkvb, qkv, nullptr,nullptr, 512,512,512,1536);
  // ---- linformer projections ----
  red_k<<<dim3(256,2),512,0,stream>>>(qkv, redb);
  kc_k <<<dim3(256,2),512,0,stream>>>(t1b, redb, Kcbf, Vctbf);
  // ---- fused attention ----
  attn_k<<<dim3(128,8),256,0,stream>>>(qkv, Kcbf, Vctbf, ao);
  // ---- output projection + residual + double LN ----
  gemm2_k<0><<<dim3(4,128,1),256,0,stream>>>(ao, owt, o_b, attno, 512,512,512,512);
  ln2_k<<<16384,256,0,stream>>>(attno, feat, ln1_g, ln1_b, ln2_g, ln2_b, att);
  // ---- gates (also zeroes scp for the MoE atomics) ----
  wcolsum_k<<<128,256,0,stream>>>(att, colp, scp);
  meangates_k<<<1,512,0,stream>>>(colp, gate_w, gate_b, gatesp);
  // ---- MoE expert attention: ONE merged N=1024 GEMM, tanh+dot fused in epilogue ----
  gemm4_k<0,true><<<dim3(4,64,1),512,0,stream>>>(att, mwt, moe_b1, nullptr, moe_w2, scp, 512,512,512,0);
  moestat_k<<<4,1024,0,stream>>>(scp, mstat, sstat);
  // ---- attn weights + bag partials (fused) + classifier ----
  wbag_k<<<128,256,0,stream>>>(att, scp, gatesp, mstat, sstat, bagp, dout);
  cls2_k<<<1,512,0,stream>>>(bagp, cls_w1, cls_b1, cls_w2, cls_b2, cls_w3, cls_b3, dout);
}

// Round 5
// 473.819 us; speedup vs baseline: 3.0397x; 1.0486x over previous
//
#include <hip/hip_runtime.h>

#define DI __device__ __forceinline__

DI float bf2f(unsigned short u){ unsigned int v = ((unsigned int)u)<<16; float f; __builtin_memcpy(&f,&v,4); return f; }
DI unsigned short f2bf(float f){ unsigned int v; __builtin_memcpy(&v,&f,4); v = v + 0x7FFFu + ((v>>16)&1u); return (unsigned short)(v>>16); }

typedef __attribute__((ext_vector_type(8))) short bf16x8;
typedef __attribute__((ext_vector_type(4))) float f32x4;

#define GLD_LDS16(src, dst) __builtin_amdgcn_global_load_lds( \
    (const __attribute__((address_space(1))) void*)(src), \
    (__attribute__((address_space(3))) void*)(dst), 16, 0, 0)

DI void barrier_() { asm volatile("" ::: "memory"); __builtin_amdgcn_s_barrier(); asm volatile("" ::: "memory"); }

// ---------------- bf16 MFMA GEMM, m97 structure + XCD swizzle (N=512 GEMMs) ----------------
template<int ACT>
__global__ __launch_bounds__(256) void gemm2_k(
    const unsigned short* __restrict__ A, const unsigned short* __restrict__ Bt,
    const float* __restrict__ bias, unsigned short* __restrict__ C,
    int K, int lda, int ldb, int ldc)
{
  __shared__ unsigned short As[8192];
  __shared__ unsigned short Bs[8192];
  const int tid = threadIdx.x, lane = tid & 63, wid = tid >> 6;
  const int wm = wid >> 1, wn = wid & 1;
  const int nx = gridDim.x;
  const int bid = blockIdx.x + nx*blockIdx.y;
  const int cpx = (nx*gridDim.y) >> 3;
  const int wg = (bid & 7)*cpx + (bid >> 3);
  const long long mBase = (long long)(wg / nx) << 7;
  const long long nBase = (long long)(wg % nx) << 7;
  const int q = lane >> 4, r15 = lane & 15;

  f32x4 acc[4][4];
#pragma unroll
  for (int i=0;i<4;i++)
#pragma unroll
    for (int j=0;j<4;j++)
#pragma unroll
      for (int r=0;r<4;r++) acc[i][j][r] = 0.f;

  const int nkt = K >> 6;
  for (int kt=0; kt<nkt; ++kt) {
    const int k0 = kt << 6;
#pragma unroll
    for (int it=0; it<4; ++it) {
      const int dbase = (it<<8) + (wid<<6);
      const int d = dbase + lane;
      const int row = d >> 3, cc = d & 7, sc = cc ^ (row & 7);
      GLD_LDS16(A + (mBase + row)*(long long)lda + k0 + (sc<<3), As + (dbase<<3));
      GLD_LDS16(Bt + (nBase + row)*(long long)ldb + k0 + (sc<<3), Bs + (dbase<<3));
    }
    __syncthreads();
#pragma unroll
    for (int ks=0; ks<2; ++ks) {
      bf16x8 af[4], bfr[4];
#pragma unroll
      for (int mi=0; mi<4; ++mi) {
        const int row = (wm<<6) + (mi<<4) + r15;
        const int ch = ((ks<<2)+q) ^ (row&7);
        af[mi] = *(const bf16x8*)(As + (row<<6) + (ch<<3));
      }
#pragma unroll
      for (int ni=0; ni<4; ++ni) {
        const int col = (wn<<6) + (ni<<4) + r15;
        const int ch = ((ks<<2)+q) ^ (col&7);
        bfr[ni] = *(const bf16x8*)(Bs + (col<<6) + (ch<<3));
      }
#pragma unroll
      for (int mi=0; mi<4; ++mi)
#pragma unroll
        for (int ni=0; ni<4; ++ni)
          acc[mi][ni] = __builtin_amdgcn_mfma_f32_16x16x32_bf16(af[mi], bfr[ni], acc[mi][ni], 0, 0, 0);
    }
    __syncthreads();
  }
#pragma unroll
  for (int ni=0; ni<4; ++ni) {
    const long long n = nBase + (wn<<6) + (ni<<4) + r15;
    const float bval = bias[n];
#pragma unroll
    for (int mi=0; mi<4; ++mi) {
#pragma unroll
      for (int r=0; r<4; ++r) {
        const long long m = mBase + (wm<<6) + (mi<<4) + (q<<2) + r;
        float v = acc[mi][ni][r] + bval;
        if constexpr (ACT==1) v = fmaxf(v, 0.f);
        C[m*(long long)ldc + n] = f2bf(v);
      }
    }
  }
}

// ---------------- gemm4: 256x256 tile, 4-phase counted-vmcnt pipeline (trimmed barriers) ----
template<int ACT, bool MOE>
__global__ __launch_bounds__(512,2) void gemm4_k(
    const unsigned short* __restrict__ A, const unsigned short* __restrict__ Bt,
    const float* __restrict__ bias, unsigned short* __restrict__ C,
    const float* __restrict__ w2, float* __restrict__ scp,
    int K, int lda, int ldb, int ldc)
{
  __shared__ unsigned short As[2][16384];
  __shared__ unsigned short Bs[2][16384];
  const int tid = threadIdx.x, lane = tid & 63, wid = tid >> 6;
  const int wm = wid >> 2, wn = wid & 3;
  const int q = lane >> 4, r15 = lane & 15;
  const int nx = gridDim.x;
  const int bid = blockIdx.x + nx*blockIdx.y;
  const int cpx = (nx*gridDim.y) >> 3;
  const int wg = (bid & 7)*cpx + (bid >> 3);
  const long long mBase = (long long)(wg / nx) << 8;
  const long long nBase = (long long)(wg % nx) << 8;

  f32x4 acc[8][4];
#pragma unroll
  for (int i=0;i<8;i++)
#pragma unroll
    for (int j=0;j<4;j++)
#pragma unroll
      for (int r=0;r<4;r++) acc[i][j][r] = 0.f;

  const int NT = K >> 6;

#define G4_STA(j, nb, kk) { const int d_ = tid + ((j)<<9); const int row_ = d_>>3, c_ = d_&7, sc_ = c_ ^ (row_&7); \
    GLD_LDS16(A + (mBase+row_)*(long long)lda + (kk) + (sc_<<3), &As[nb][d_<<3]); }
#define G4_STB(j, nb, kk) { const int d_ = tid + ((j)<<9); const int row_ = d_>>3, c_ = d_&7, sc_ = c_ ^ (row_&7); \
    GLD_LDS16(Bt + (nBase+row_)*(long long)ldb + (kk) + (sc_<<3), &Bs[nb][d_<<3]); }

  // prologue: stage tile 0 in canonical issue order
  G4_STB(0,0,0); G4_STB(1,0,0); G4_STB(2,0,0); G4_STB(3,0,0);
  G4_STA(0,0,0); G4_STA(2,0,0); G4_STA(1,0,0); G4_STA(3,0,0);

  for (int t=0; t<NT; ++t) {
    const int b = t & 1, nb = b ^ 1;
    const bool more = (t+1 < NT);
    const int k1 = (t+1) << 6;
    bf16x8 aF[8], bL[4], bH[4];

    // ---- phase 0: (m-lo, n-lo) ----
    asm volatile("s_waitcnt vmcnt(2)" ::: "memory");
    barrier_();
#pragma unroll
    for (int mi=0; mi<4; ++mi)
#pragma unroll
      for (int ks=0; ks<2; ++ks) {
        const int row = (wm<<7) + (mi<<4) + r15;
        const int ch = ((ks<<2)+q) ^ (row&7);
        aF[mi*2+ks] = *(const bf16x8*)&As[b][(row<<6) + (ch<<3)];
      }
#pragma unroll
    for (int ni=0; ni<2; ++ni)
#pragma unroll
      for (int ks=0; ks<2; ++ks) {
        const int col = (wn<<6) + (ni<<4) + r15;
        const int ch = ((ks<<2)+q) ^ (col&7);
        bL[ni*2+ks] = *(const bf16x8*)&Bs[b][(col<<6) + (ch<<3)];
      }
    if (more) { G4_STB(0,nb,k1); G4_STB(1,nb,k1); }
    __builtin_amdgcn_s_setprio(1);
#pragma unroll
    for (int mi=0; mi<4; ++mi)
#pragma unroll
      for (int ni=0; ni<2; ++ni)
#pragma unroll
        for (int ks=0; ks<2; ++ks)
          acc[mi][ni] = __builtin_amdgcn_mfma_f32_16x16x32_bf16(aF[mi*2+ks], bL[ni*2+ks], acc[mi][ni], 0,0,0);
    __builtin_amdgcn_s_setprio(0);
    barrier_();

    // ---- phase 1: (m-lo, n-hi) ----
#pragma unroll
    for (int ni=0; ni<2; ++ni)
#pragma unroll
      for (int ks=0; ks<2; ++ks) {
        const int col = (wn<<6) + ((ni+2)<<4) + r15;
        const int ch = ((ks<<2)+q) ^ (col&7);
        bH[ni*2+ks] = *(const bf16x8*)&Bs[b][(col<<6) + (ch<<3)];
      }
    if (more) { G4_STB(2,nb,k1); G4_STB(3,nb,k1); }
    __builtin_amdgcn_s_setprio(1);
#pragma unroll
    for (int mi=0; mi<4; ++mi)
#pragma unroll
      for (int ni=0; ni<2; ++ni)
#pragma unroll
        for (int ks=0; ks<2; ++ks)
          acc[mi][ni+2] = __builtin_amdgcn_mfma_f32_16x16x32_bf16(aF[mi*2+ks], bH[ni*2+ks], acc[mi][ni+2], 0,0,0);
    __builtin_amdgcn_s_setprio(0);
    // (ph1-end barrier removed: ph2-top wait+barrier follows immediately)

    // ---- phase 2: (m-hi, n-lo) ----
    if (more) { asm volatile("s_waitcnt vmcnt(4)" ::: "memory"); }
    else      { asm volatile("s_waitcnt vmcnt(0)" ::: "memory"); }
    barrier_();
#pragma unroll
    for (int mi=0; mi<4; ++mi)
#pragma unroll
      for (int ks=0; ks<2; ++ks) {
        const int row = (wm<<7) + ((mi+4)<<4) + r15;
        const int ch = ((ks<<2)+q) ^ (row&7);
        aF[mi*2+ks] = *(const bf16x8*)&As[b][(row<<6) + (ch<<3)];
      }
    if (more) { G4_STA(0,nb,k1); G4_STA(2,nb,k1); }
    __builtin_amdgcn_s_setprio(1);
#pragma unroll
    for (int mi=0; mi<4; ++mi)
#pragma unroll
      for (int ni=0; ni<2; ++ni)
#pragma unroll
        for (int ks=0; ks<2; ++ks)
          acc[mi+4][ni] = __builtin_amdgcn_mfma_f32_16x16x32_bf16(aF[mi*2+ks], bL[ni*2+ks], acc[mi+4][ni], 0,0,0);
    __builtin_amdgcn_s_setprio(0);
    barrier_();

    // ---- phase 3: (m-hi, n-hi) ----
    if (more) { G4_STA(1,nb,k1); G4_STA(3,nb,k1); }
    __builtin_amdgcn_s_setprio(1);
#pragma unroll
    for (int mi=0; mi<4; ++mi)
#pragma unroll
      for (int ni=0; ni<2; ++ni)
#pragma unroll
        for (int ks=0; ks<2; ++ks)
          acc[mi+4][ni+2] = __builtin_amdgcn_mfma_f32_16x16x32_bf16(aF[mi*2+ks], bH[ni*2+ks], acc[mi+4][ni+2], 0,0,0);
    __builtin_amdgcn_s_setprio(0);
    // (ph3-end barrier removed: ph0-top wait+barrier follows)
  }
#undef G4_STA
#undef G4_STB

  if constexpr (MOE) {
    const int e = (int)(nBase >> 8);
#pragma unroll
    for (int mi=0; mi<8; ++mi) {
#pragma unroll
      for (int r=0; r<4; ++r) {
        float p = 0.f;
#pragma unroll
        for (int ni=0; ni<4; ++ni) {
          const int n = (int)nBase + (wn<<6) + (ni<<4) + r15;
          const float v = acc[mi][ni][r] + bias[n];
          const float th = 1.f - 2.f/(__expf(2.f*v) + 1.f);
          p += th * w2[n];
        }
        p += __shfl_xor(p,1,64); p += __shfl_xor(p,2,64);
        p += __shfl_xor(p,4,64); p += __shfl_xor(p,8,64);
        if (r15 == 0) {
          const long long m = mBase + (wm<<7) + (mi<<4) + (q<<2) + r;
          atomicAdd(scp + ((long long)e<<14) + m, p);
        }
      }
    }
  } else {
#pragma unroll
    for (int ni=0; ni<4; ++ni) {
      const long long n = nBase + (wn<<6) + (ni<<4) + r15;
      const float bval = bias[n];
#pragma unroll
      for (int mi=0; mi<8; ++mi) {
#pragma unroll
        for (int r=0; r<4; ++r) {
          const long long m = mBase + (wm<<7) + (mi<<4) + (q<<2) + r;
          float v = acc[mi][ni][r] + bval;
          if constexpr (ACT==1) v = fmaxf(v, 0.f);
          C[m*(long long)ldc + n] = f2bf(v);
        }
      }
    }
  }
}

// ---------------- mega prep: x->bf16 + all weight transposes + t1 + bias concat ----------------
DI void transpose64(const float* __restrict__ src, unsigned short* __restrict__ dst,
                    int K, int N, int Kpad, int k0, int n0, float (*tile)[65], int tid)
{
  const int c = tid & 63, rg = tid >> 6;
#pragma unroll
  for (int j=0;j<16;j++){
    const int r = (j<<2) + rg;
    const int k = k0 + r;
    tile[r][c] = (k < K) ? src[(long long)k*N + n0 + c] : 0.f;
  }
  __syncthreads();
#pragma unroll
  for (int j=0;j<16;j++){
    const int nn = (j<<2) + rg;
    dst[(long long)(n0+nn)*Kpad + k0 + c] = f2bf(tile[c][nn]);
  }
}

__global__ __launch_bounds__(256) void prep_k(
    const float* __restrict__ x, unsigned short* __restrict__ xb,
    const float* __restrict__ enc_w1, unsigned short* __restrict__ w1t,
    const float* __restrict__ enc_w2, unsigned short* __restrict__ w2t,
    const float* __restrict__ enc_w3, const float* __restrict__ q_w,
    const float* __restrict__ k_w, const float* __restrict__ v_w, const float* __restrict__ o_w,
    unsigned short* __restrict__ w3t, unsigned short* __restrict__ qkvw, unsigned short* __restrict__ owt,
    const float* __restrict__ moe_w1, unsigned short* __restrict__ mwt,
    const float* __restrict__ Ew, const float* __restrict__ Fw, float* __restrict__ t1,
    const float* __restrict__ qb, const float* __restrict__ kb, const float* __restrict__ vb,
    float* __restrict__ qkvb)
{
  __shared__ float tile[64][65];
  const int b = blockIdx.x, tid = threadIdx.x;
  if (b < 4096) {
    // x [16384][2000] f32 -> [16384][2048] bf16 (pad)
#pragma unroll
    for (int i=0;i<4;i++){
      const long long cid = (long long)b*1024 + i*256 + tid;
      const long long row = cid >> 8; const int c = (int)(cid & 255);
      bf16x8 v;
      if (c < 250) {
        const float* p = x + row*2000 + c*8;
        const float4 f0 = *(const float4*)p, f1 = *(const float4*)(p+4);
        v[0]=(short)f2bf(f0.x); v[1]=(short)f2bf(f0.y); v[2]=(short)f2bf(f0.z); v[3]=(short)f2bf(f0.w);
        v[4]=(short)f2bf(f1.x); v[5]=(short)f2bf(f1.y); v[6]=(short)f2bf(f1.z); v[7]=(short)f2bf(f1.w);
      } else {
#pragma unroll
        for (int j=0;j<8;j++) v[j]=0;
      }
      *(bf16x8*)(xb + (cid<<3)) = v;
    }
  } else if (b < 4608) {
    const int bb = b - 4096;
    transpose64(enc_w1, w1t, 2000, 1024, 2048, (bb&31)<<6, (bb>>5)<<6, tile, tid);
  } else if (b < 4736) {
    const int bb = b - 4608;
    transpose64(enc_w2, w2t, 1024, 512, 1024, (bb&15)<<6, (bb>>4)<<6, tile, tid);
  } else if (b < 5056) {
    const int bb = b - 4736;
    const int z = bb >> 6, r = bb & 63;
    const float* s = (z==0)?enc_w3:(z==1)?q_w:(z==2)?k_w:(z==3)?v_w:o_w;
    unsigned short* d = (z==0)?w3t:(z==1)?qkvw:(z==2)?(qkvw+512*512):(z==3)?(qkvw+1024*512):owt;
    transpose64(s, d, 512, 512, 512, (r&7)<<6, (r>>3)<<6, tile, tid);
  } else if (b < 5184) {
    const int bb = b - 5056;
    const int z = bb >> 5, r = bb & 31;
    transpose64(moe_w1 + (long long)z*512*256, mwt + (long long)z*256*512,
                512, 256, 512, (r&7)<<6, (r>>3)<<6, tile, tid);
  } else {
    const int bb = b - 5184;
    const int k = bb & 255, which = bb >> 8, c = tid;
    if (which == 0 && k < 3) {
      const float* src = (k==0) ? qb : (k==1) ? kb : vb;
      qkvb[k*512 + c]       = src[c];
      qkvb[k*512 + 256 + c] = src[256 + c];
    }
    const float* W = which ? Fw : Ew;
    const float ksc = 39.0625f;
    const float inv = 1.f/39.0625f;
    const float sf = (k + 0.5f)*ksc - 0.5f;
    int ilo = (int)ceilf(sf - ksc); if (ilo < 0) ilo = 0;
    int ihi = (int)floorf(sf + ksc); if (ihi > 9999) ihi = 9999;
    float acc = 0.f, wsum = 0.f;
    for (int i=ilo; i<=ihi; ++i) {
      const float w = 1.f - fabsf(sf - (float)i)*inv;
      if (w > 0.f) { acc += w * W[c*10000 + i]; wsum += w; }
    }
    t1[(which*256 + k)*256 + c] = acc / wsum;
  }
}

// ---------------- linformer projection helpers ----------------
__global__ __launch_bounds__(512) void red_k(const unsigned short* __restrict__ qkv,
                                             float* __restrict__ red)
{
  const int c = blockIdx.x, which = blockIdx.y, j = threadIdx.x;
  const unsigned short* X = qkv + (which ? 1024 : 512);
  int nlo = 64*c - 32; if (nlo < 0) nlo = 0;
  int nhi = 64*c + 95; if (nhi > 16383) nhi = 16383;
  float acc = 0.f;
  for (int n=nlo; n<=nhi; ++n) {
    float sf = (n + 0.5f)*0.015625f - 0.5f;
    sf = fminf(fmaxf(sf, 0.f), 255.f);
    const int c0 = (int)sf;
    const float f = sf - (float)c0;
    float w = 0.f;
    if (c == c0) w = 1.f - f;
    else if (c == c0+1) w = f;
    if (w != 0.f) acc += w * bf2f(X[(long long)n*1536 + j]);
  }
  red[(which*256 + c)*512 + j] = acc;
}

__global__ __launch_bounds__(512) void kc_k(const float* __restrict__ t1, const float* __restrict__ red,
                                            unsigned short* __restrict__ Kc, unsigned short* __restrict__ Vct)
{
  const int k = blockIdx.x, which = blockIdx.y, j = threadIdx.x;
  const float* T = t1 + (which*256 + k)*256;
  const float* R = red + which*131072;
  float acc = 0.f;
  for (int c=0; c<256; ++c) acc += T[c] * R[c*512 + j];
  const int h = j >> 6, d = j & 63;
  if (which == 0) Kc [(h<<14) + (k<<6) + d] = f2bf(acc);
  else            Vct[(h<<14) + (d<<8) + k] = f2bf(acc);
}

// ---------------- fused linformer attention ----------------
__global__ __launch_bounds__(256) void attn_k(
    const unsigned short* __restrict__ Qg, const unsigned short* __restrict__ Kc,
    const unsigned short* __restrict__ Vct, unsigned short* __restrict__ ao)
{
  __shared__ unsigned short Ks[16384];
  __shared__ unsigned short Vs[16384];
  __shared__ unsigned short Ps[32768];
  const int h = blockIdx.y;
  const long long mBase = (long long)blockIdx.x << 7;
  const int tid = threadIdx.x, lane = tid & 63, wid = tid >> 6;
  const int q = lane >> 4, r15 = lane & 15;

#pragma unroll
  for (int it=0; it<8; ++it) {
    const int dbase = (it<<8) + (wid<<6);
    const int d = dbase + lane;
    {
      const int row = d >> 3, cc = d & 7, sc = cc ^ (row & 7);
      GLD_LDS16(Kc + (h<<14) + (row<<6) + (sc<<3), Ks + (dbase<<3));
    }
    {
      const int row = d >> 5, cc = d & 31, sc = (cc & 24) | ((cc ^ (row & 7)) & 7);
      GLD_LDS16(Vct + (h<<14) + (row<<8) + (sc<<3), Vs + (dbase<<3));
    }
  }
  __syncthreads();

  f32x4 acc[2][16];
#pragma unroll
  for (int mi=0;mi<2;mi++)
#pragma unroll
    for (int ni=0;ni<16;ni++)
#pragma unroll
      for (int r=0;r<4;r++) acc[mi][ni][r] = 0.f;

#pragma unroll
  for (int ks=0; ks<2; ++ks) {
    bf16x8 af[2];
#pragma unroll
    for (int mi=0; mi<2; ++mi) {
      const long long m = mBase + (wid<<5) + (mi<<4) + r15;
      af[mi] = *(const bf16x8*)(Qg + m*1536 + (h<<6) + (ks<<5) + (q<<3));
    }
#pragma unroll
    for (int ni=0; ni<16; ++ni) {
      const int col = (ni<<4) + r15;
      const int ch = ((ks<<2)+q) ^ (col&7);
      const bf16x8 bv = *(const bf16x8*)(Ks + (col<<6) + (ch<<3));
      acc[0][ni] = __builtin_amdgcn_mfma_f32_16x16x32_bf16(af[0], bv, acc[0][ni], 0,0,0);
      acc[1][ni] = __builtin_amdgcn_mfma_f32_16x16x32_bf16(af[1], bv, acc[1][ni], 0,0,0);
    }
  }

#pragma unroll
  for (int mi=0; mi<2; ++mi) {
#pragma unroll
    for (int r=0; r<4; ++r) {
      float mx = -3.4e38f;
#pragma unroll
      for (int ni=0; ni<16; ++ni) mx = fmaxf(mx, acc[mi][ni][r]);
      mx = fmaxf(mx, __shfl_xor(mx,1,64)); mx = fmaxf(mx, __shfl_xor(mx,2,64));
      mx = fmaxf(mx, __shfl_xor(mx,4,64)); mx = fmaxf(mx, __shfl_xor(mx,8,64));
      float s = 0.f;
#pragma unroll
      for (int ni=0; ni<16; ++ni) {
        const float e = __expf((acc[mi][ni][r] - mx)*0.125f);
        acc[mi][ni][r] = e; s += e;
      }
      s += __shfl_xor(s,1,64); s += __shfl_xor(s,2,64);
      s += __shfl_xor(s,4,64); s += __shfl_xor(s,8,64);
      const float inv = 1.f / s;
      const int row = (wid<<5) + (mi<<4) + (q<<2) + r;
#pragma unroll
      for (int ni=0; ni<16; ++ni) {
        const int col = (ni<<4) + r15;
        const int ch = col >> 3;
        const int chs = (ch & 24) | ((ch ^ (row & 7)) & 7);
        Ps[(row<<8) + (chs<<3) + (col&7)] = f2bf(acc[mi][ni][r]*inv);
      }
    }
  }
  __syncthreads();

  f32x4 o[2][4];
#pragma unroll
  for (int mi=0;mi<2;mi++)
#pragma unroll
    for (int ni=0;ni<4;ni++)
#pragma unroll
      for (int r=0;r<4;r++) o[mi][ni][r] = 0.f;

#pragma unroll
  for (int kk=0; kk<8; ++kk) {
    bf16x8 pa[2];
#pragma unroll
    for (int mi=0; mi<2; ++mi) {
      const int row = (wid<<5) + (mi<<4) + r15;
      const int ch = (kk<<2) + q;
      const int chs = (ch & 24) | ((ch ^ (row & 7)) & 7);
      pa[mi] = *(const bf16x8*)(Ps + (row<<8) + (chs<<3));
    }
#pragma unroll
    for (int ni=0; ni<4; ++ni) {
      const int vrow = (ni<<4) + r15;
      const int ch = (kk<<2) + q;
      const int chs = (ch & 24) | ((ch ^ (vrow & 7)) & 7);
      const bf16x8 bv = *(const bf16x8*)(Vs + (vrow<<8) + (chs<<3));
      o[0][ni] = __builtin_amdgcn_mfma_f32_16x16x32_bf16(pa[0], bv, o[0][ni], 0,0,0);
      o[1][ni] = __builtin_amdgcn_mfma_f32_16x16x32_bf16(pa[1], bv, o[1][ni], 0,0,0);
    }
  }
#pragma unroll
  for (int mi=0; mi<2; ++mi)
#pragma unroll
    for (int ni=0; ni<4; ++ni)
#pragma unroll
      for (int r=0; r<4; ++r) {
        const long long m = mBase + (wid<<5) + (mi<<4) + (q<<2) + r;
        ao[m*512 + (h<<6) + (ni<<4) + r15] = f2bf(o[mi][ni][r]);
      }
}

// ---------------- double layernorm (wave-per-row) + column-sum partials + scp zero --------
__global__ __launch_bounds__(256) void ln64_k(
    const unsigned short* __restrict__ attno, const unsigned short* __restrict__ feat,
    const float* __restrict__ g1, const float* __restrict__ b1,
    const float* __restrict__ g2, const float* __restrict__ b2,
    unsigned short* __restrict__ att, float* __restrict__ colp, float* __restrict__ scp)
{
  __shared__ float cred[4][512];
  const int tid = threadIdx.x, lane = tid & 63, wid = tid >> 6;
  const int c0 = lane << 3;
  scp[((long long)blockIdx.x<<8) + tid] = 0.f;
  float g1v[8], b1v[8], g2v[8], b2v[8];
#pragma unroll
  for (int j=0;j<8;j++){ g1v[j]=g1[c0+j]; b1v[j]=b1[c0+j]; g2v[j]=g2[c0+j]; b2v[j]=b2[c0+j]; }
  float cacc[8];
#pragma unroll
  for (int j=0;j<8;j++) cacc[j]=0.f;
  for (int rr=0; rr<16; ++rr) {
    const long long row = ((long long)blockIdx.x<<6) + (rr<<2) + wid;
    const bf16x8 a = *(const bf16x8*)(attno + (row<<9) + c0);
    const bf16x8 f = *(const bf16x8*)(feat  + (row<<9) + c0);
    float xv[8]; float s=0.f, qs=0.f;
#pragma unroll
    for (int j=0;j<8;j++){ xv[j] = bf2f((unsigned short)a[j]) + bf2f((unsigned short)f[j]); s += xv[j]; qs += xv[j]*xv[j]; }
#pragma unroll
    for (int o=32;o;o>>=1){ s += __shfl_xor(s,o,64); qs += __shfl_xor(qs,o,64); }
    float m = s*(1.f/512.f);
    float rs = rsqrtf(qs*(1.f/512.f) - m*m + 1e-5f);
    float y[8]; s=0.f; qs=0.f;
#pragma unroll
    for (int j=0;j<8;j++){ y[j] = (xv[j]-m)*rs*g1v[j] + b1v[j]; s += y[j]; qs += y[j]*y[j]; }
#pragma unroll
    for (int o=32;o;o>>=1){ s += __shfl_xor(s,o,64); qs += __shfl_xor(qs,o,64); }
    m = s*(1.f/512.f);
    rs = rsqrtf(qs*(1.f/512.f) - m*m + 1e-5f);
    bf16x8 ov;
#pragma unroll
    for (int j=0;j<8;j++){ const float z = (y[j]-m)*rs*g2v[j] + b2v[j]; cacc[j] += z; ov[j] = (short)f2bf(z); }
    *(bf16x8*)(att + (row<<9) + c0) = ov;
  }
#pragma unroll
  for (int j=0;j<8;j++) cred[wid][c0+j] = cacc[j];
  __syncthreads();
  {
    const float v0 = cred[0][tid]+cred[1][tid]+cred[2][tid]+cred[3][tid];
    const float v1 = cred[0][tid+256]+cred[1][tid+256]+cred[2][tid+256]+cred[3][tid+256];
    colp[((long long)blockIdx.x<<9)+tid]     = v0;
    colp[((long long)blockIdx.x<<9)+tid+256] = v1;
  }
}

// ---------------- gates / moe stats / bag / classifier ----------------
__global__ __launch_bounds__(512) void meangates_k(const float* __restrict__ part,
    const float* __restrict__ gw, const float* __restrict__ gb, float* __restrict__ gates)
{
  __shared__ float mv[512];
  __shared__ float tmp[4];
  const int t = threadIdx.x;
  float s = 0.f;
  for (int b=0;b<256;b++) s += part[(b<<9)+t];
  mv[t] = s * (1.f/16384.f);
  __syncthreads();
  if (t < 4) {
    float a = gb[t];
    for (int d=0; d<512; ++d) a += mv[d]*gw[d*4+t];
    tmp[t] = a;
  }
  __syncthreads();
  if (t == 0) {
    const float m = fmaxf(fmaxf(tmp[0],tmp[1]),fmaxf(tmp[2],tmp[3]));
    float e[4]; float ss=0.f;
    for (int i=0;i<4;i++){ e[i]=__expf(tmp[i]-m); ss+=e[i]; }
    for (int i=0;i<4;i++) gates[i] = e[i]/ss;
  }
}

__global__ __launch_bounds__(1024) void moestat_k(const float* __restrict__ sc,
                                                  float* __restrict__ mstat, float* __restrict__ sstat)
{
  __shared__ float red[1024];
  const int e = blockIdx.x, t = threadIdx.x;
  const float* p = sc + e*16384;
  float m = -3.4e38f;
  for (int n=t; n<16384; n+=1024) m = fmaxf(m, p[n]);
  red[t] = m; __syncthreads();
  for (int o=512;o;o>>=1){ if (t<o) red[t]=fmaxf(red[t],red[t+o]); __syncthreads(); }
  m = red[0]; __syncthreads();
  float s = 0.f;
  for (int n=t; n<16384; n+=1024) s += __expf(p[n]-m);
  red[t] = s; __syncthreads();
  for (int o=512;o;o>>=1){ if (t<o) red[t]+=red[t+o]; __syncthreads(); }
  if (t==0){ mstat[e]=m; sstat[e]=red[0]; }
}

__global__ __launch_bounds__(256) void wbag_k(const unsigned short* __restrict__ att,
    const float* __restrict__ scp, const float* __restrict__ gates,
    const float* __restrict__ mstat, const float* __restrict__ sstat,
    float* __restrict__ part, float* __restrict__ dout)
{
  __shared__ float wrow[128];
  const int c = threadIdx.x;
  const long long r0 = (long long)blockIdx.x * 128;
  if (c < 128) {
    const long long n = r0 + c;
    float w = 0.f;
#pragma unroll
    for (int e=0;e<4;e++) w += gates[e]*__expf(scp[((long long)e<<14)+n]-mstat[e]) / sstat[e];
    wrow[c] = w;
    dout[514 + n] = w;
  }
  __syncthreads();
  float a0=0.f, a1=0.f;
  for (int r=0;r<128;r++){
    const float w = wrow[r];
    const unsigned short* p = att + ((r0+r)<<9);
    a0 += w*bf2f(p[c]); a1 += w*bf2f(p[c+256]);
  }
  part[((long long)blockIdx.x<<9)+c]     = a0;
  part[((long long)blockIdx.x<<9)+c+256] = a1;
}

__global__ __launch_bounds__(512) void cls2_k(const float* __restrict__ bagp,
    const float* __restrict__ w1, const float* __restrict__ b1,
    const float* __restrict__ w2, const float* __restrict__ b2,
    const float* __restrict__ w3, const float* __restrict__ b3, float* __restrict__ dout)
{
  __shared__ float bag[512]; __shared__ float c1[256]; __shared__ float c2[128];
  const int tid = threadIdx.x;
  float s = 0.f;
  for (int b=0;b<128;b++) s += bagp[(b<<9)+tid];
  bag[tid] = s; dout[tid] = s;
  __syncthreads();
  if (tid < 256) {
    float a = b1[tid];
    for (int d=0; d<512; ++d) a += bag[d]*w1[d*256+tid];
    c1[tid] = fmaxf(a, 0.f);
  }
  __syncthreads();
  if (tid < 128) {
    float a2 = b2[tid];
    for (int d=0; d<256; ++d) a2 += c1[d]*w2[d*128+tid];
    c2[tid] = fmaxf(a2, 0.f);
  }
  __syncthreads();
  if (tid < 2) {
    float a3 = b3[tid];
    for (int d=0; d<128; ++d) a3 += c2[d]*w3[d*2+tid];
    dout[512 + tid] = a3;
  }
}

extern "C" void kernel_launch(void* const* d_in, const int* in_sizes, int n_in,
                              void* d_out, int out_size, void* d_ws, size_t ws_size,
                              hipStream_t stream)
{
  (void)in_sizes; (void)n_in; (void)out_size; (void)ws_size;
  const float* x      = (const float*)d_in[0];
  const float* enc_w1 = (const float*)d_in[1];
  const float* enc_b1 = (const float*)d_in[2];
  const float* enc_w2 = (const float*)d_in[3];
  const float* enc_b2 = (const float*)d_in[4];
  const float* enc_w3 = (const float*)d_in[5];
  const float* enc_b3 = (const float*)d_in[6];
  const float* q_w    = (const float*)d_in[7];
  const float* q_b    = (const float*)d_in[8];
  const float* k_w    = (const float*)d_in[9];
  const float* k_b    = (const float*)d_in[10];
  const float* v_w    = (const float*)d_in[11];
  const float* v_b    = (const float*)d_in[12];
  const float* o_w    = (const float*)d_in[13];
  const float* o_b    = (const float*)d_in[14];
  const float* E_w    = (const float*)d_in[15];
  const float* F_w    = (const float*)d_in[16];
  const float* ln1_g  = (const float*)d_in[17];
  const float* ln1_b  = (const float*)d_in[18];
  const float* ln2_g  = (const float*)d_in[19];
  const float* ln2_b  = (const float*)d_in[20];
  const float* gate_w = (const float*)d_in[21];
  const float* gate_b = (const float*)d_in[22];
  const float* moe_w1 = (const float*)d_in[23];
  const float* moe_b1 = (const float*)d_in[24];
  const float* moe_w2 = (const float*)d_in[25];
  // d_in[26] = moe_b2: drops out of the row-softmax (shift invariance)
  const float* cls_w1 = (const float*)d_in[27];
  const float* cls_b1 = (const float*)d_in[28];
  const float* cls_w2 = (const float*)d_in[29];
  const float* cls_b2 = (const float*)d_in[30];
  const float* cls_w3 = (const float*)d_in[31];
  const float* cls_b3 = (const float*)d_in[32];

  char* ws = (char*)d_ws;
  const size_t MB = 1024*1024;
  unsigned short* x_bf  = (unsigned short*)(ws + 0);          // [16384][2048]  64MB
  unsigned short* h1    = (unsigned short*)(ws + 64*MB);      // [16384][1024]  32MB
  unsigned short* h2    = (unsigned short*)(ws + 0);          // 16MB (x_bf dead)
  unsigned short* feat  = (unsigned short*)(ws + 16*MB);      // 16MB
  unsigned short* qkv   = (unsigned short*)(ws + 32*MB);      // [16384][1536]  48MB (h1 dead)
  unsigned short* ao    = (unsigned short*)(ws + 80*MB);      // 16MB
  unsigned short* attno = (unsigned short*)(ws + 0);          // 16MB (h2 dead)
  unsigned short* att   = (unsigned short*)(ws + 96*MB);      // 16MB
  unsigned short* w1t   = (unsigned short*)(ws + 112*MB);                 // [1024][2048] 4MB
  unsigned short* w2t   = (unsigned short*)(ws + 116*MB);                 // 1MB
  unsigned short* w3t   = (unsigned short*)(ws + 117*MB);                 // 0.5MB
  unsigned short* qkvw  = (unsigned short*)(ws + 117*MB + 512*1024);      // 1.5MB
  unsigned short* owt   = (unsigned short*)(ws + 119*MB);                 // 0.5MB
  unsigned short* mwt   = (unsigned short*)(ws + 119*MB + 512*1024);      // 1MB
  float*  t1b   = (float*)(ws + 120*MB + 512*1024);                       // 0.5MB
  float*  redb  = (float*)(ws + 121*MB);                                  // 1MB
  unsigned short* Kcbf  = (unsigned short*)(ws + 122*MB);                 // 256KB
  unsigned short* Vctbf = (unsigned short*)(ws + 122*MB + 256*1024);      // 256KB
  float*  colp  = (float*)(ws + 122*MB + 512*1024);                       // [256][512] 512KB
  float*  bagp  = (float*)(ws + 123*MB);                                  // [128][512] 256KB
  float*  qkvb  = (float*)(ws + 123*MB + 256*1024);                       // 6KB
  float*  gatesp= (float*)(ws + 123*MB + 264*1024);
  float*  scp   = (float*)(ws + 123*MB + 268*1024);                       // [4][16384] 256KB
  float*  mstat = (float*)(ws + 123*MB + 524*1024);
  float*  sstat = (float*)(ws + 123*MB + 524*1024 + 64);
  float*  dout  = (float*)d_out;

  // ---- mega prep (x conversion + all weight transposes + t1 + bias concat) ----
  prep_k<<<5696,256,0,stream>>>(x, x_bf, enc_w1, w1t, enc_w2, w2t,
                                enc_w3, q_w, k_w, v_w, o_w, w3t, qkvw, owt,
                                moe_w1, mwt, E_w, F_w, t1b, q_b, k_b, v_b, qkvb);

  // ---- encoder ----
  gemm4_k<1,false><<<dim3(4,64,1),512,0,stream>>>(x_bf, w1t, enc_b1, h1, nullptr,nullptr, 2048,2048,2048,1024);
  gemm2_k<1><<<dim3(4,128,1),256,0,stream>>>(h1, w2t, enc_b2, h2,   1024,1024,1024, 512);
  gemm2_k<1><<<dim3(4,128,1),256,0,stream>>>(h2, w3t, enc_b3, feat,  512, 512, 512, 512);
  // ---- QKV (merged, N=1536) ----
  gemm4_k<0,false><<<dim3(6,64,1),512,0,stream>>>(feat, qkvw, qkvb, qkv, nullptr,nullptr, 512,512,512,1536);
  // ---- linformer projections ----
  red_k<<<dim3(256,2),512,0,stream>>>(qkv, redb);
  kc_k <<<dim3(256,2),512,0,stream>>>(t1b, redb, Kcbf, Vctbf);
  // ---- fused attention ----
  attn_k<<<dim3(128,8),256,0,stream>>>(qkv, Kcbf, Vctbf, ao);
  // ---- output projection + residual + double LN (+ colsum partials + scp zero) ----
  gemm2_k<0><<<dim3(4,128,1),256,0,stream>>>(ao, owt, o_b, attno, 512,512,512,512);
  ln64_k<<<256,256,0,stream>>>(attno, feat, ln1_g, ln1_b, ln2_g, ln2_b, att, colp, scp);
  meangates_k<<<1,512,0,stream>>>(colp, gate_w, gate_b, gatesp);
  // ---- MoE expert attention: ONE merged N=1024 GEMM, tanh+dot fused in epilogue ----
  gemm4_k<0,true><<<dim3(4,64,1),512,0,stream>>>(att, mwt, moe_b1, nullptr, moe_w2, scp, 512,512,512,0);
  moestat_k<<<4,1024,0,stream>>>(scp, mstat, sstat);
  // ---- attn weights + bag partials (fused) + classifier ----
  wbag_k<<<128,256,0,stream>>>(att, scp, gatesp, mstat, sstat, bagp, dout);
  cls2_k<<<1,512,0,stream>>>(bagp, cls_w1, cls_b1, cls_w2, cls_b2, cls_w3, cls_b3, dout);
}

// Round 6
// 431.765 us; speedup vs baseline: 3.3357x; 1.0974x over previous
//
#include <hip/hip_runtime.h>

#define DI __device__ __forceinline__

DI float bf2f(unsigned short u){ unsigned int v = ((unsigned int)u)<<16; float f; __builtin_memcpy(&f,&v,4); return f; }
DI unsigned short f2bf(float f){ unsigned int v; __builtin_memcpy(&v,&f,4); v = v + 0x7FFFu + ((v>>16)&1u); return (unsigned short)(v>>16); }

typedef __attribute__((ext_vector_type(8))) short bf16x8;
typedef __attribute__((ext_vector_type(4))) float f32x4;

#define GLD_LDS16(src, dst) __builtin_amdgcn_global_load_lds( \
    (const __attribute__((address_space(1))) void*)(src), \
    (__attribute__((address_space(3))) void*)(dst), 16, 0, 0)

DI void barrier_() { asm volatile("" ::: "memory"); __builtin_amdgcn_s_barrier(); asm volatile("" ::: "memory"); }

// ---------------- gemm5: 128x128 tile, 4-phase counted-vmcnt pipeline ----------------
// 256 thr = 4 waves (2M x 2N), wave tile 64x64, BK=64, dbuf 64KiB LDS (2 blocks/CU).
// Issue order per tile: B0,B2 | B1,B3 | A0,A2 | A1,A3 (2/phase).
// Waits: ph0 vmcnt(2)+barrier, ph2 vmcnt(4)+barrier. 4 barriers/tile.
template<int ACT>
__global__ __launch_bounds__(256,2) void gemm5_k(
    const unsigned short* __restrict__ A, const unsigned short* __restrict__ Bt,
    const float* __restrict__ bias, unsigned short* __restrict__ C,
    int K, int lda, int ldb, int ldc)
{
  __shared__ unsigned short As[2][8192];
  __shared__ unsigned short Bs[2][8192];
  const int tid = threadIdx.x, lane = tid & 63, wid = tid >> 6;
  const int wm = wid >> 1, wn = wid & 1;
  const int q = lane >> 4, r15 = lane & 15;
  const int nx = gridDim.x;
  const int bid = blockIdx.x + nx*blockIdx.y;
  const int cpx = (nx*gridDim.y) >> 3;
  const int wg = (bid & 7)*cpx + (bid >> 3);
  const long long mBase = (long long)(wg / nx) << 7;
  const long long nBase = (long long)(wg % nx) << 7;

  f32x4 acc[4][4];
#pragma unroll
  for (int i=0;i<4;i++)
#pragma unroll
    for (int j=0;j<4;j++)
#pragma unroll
      for (int r=0;r<4;r++) acc[i][j][r] = 0.f;

  const int NT = K >> 6;

#define G5_STA(j, nb, kk) { const int d_ = tid + ((j)<<8); const int row_ = d_>>3, c_ = d_&7, sc_ = c_ ^ (row_&7); \
    GLD_LDS16(A + (mBase+row_)*(long long)lda + (kk) + (sc_<<3), &As[nb][d_<<3]); }
#define G5_STB(j, nb, kk) { const int d_ = tid + ((j)<<8); const int row_ = d_>>3, c_ = d_&7, sc_ = c_ ^ (row_&7); \
    GLD_LDS16(Bt + (nBase+row_)*(long long)ldb + (kk) + (sc_<<3), &Bs[nb][d_<<3]); }

  // prologue: stage tile 0 in canonical issue order
  G5_STB(0,0,0); G5_STB(2,0,0); G5_STB(1,0,0); G5_STB(3,0,0);
  G5_STA(0,0,0); G5_STA(2,0,0); G5_STA(1,0,0); G5_STA(3,0,0);

  for (int t=0; t<NT; ++t) {
    const int b = t & 1, nb = b ^ 1;
    const bool more = (t+1 < NT);
    const int k1 = (t+1) << 6;
    bf16x8 aL[4], aH[4], bL[4], bH[4];

    // ---- phase 0: (m-lo, n-lo) ----
    asm volatile("s_waitcnt vmcnt(2)" ::: "memory");
    barrier_();
#pragma unroll
    for (int mi=0; mi<2; ++mi)
#pragma unroll
      for (int ks=0; ks<2; ++ks) {
        const int row = (wm<<6) + (mi<<4) + r15;
        const int ch = ((ks<<2)+q) ^ (row&7);
        aL[mi*2+ks] = *(const bf16x8*)&As[b][(row<<6) + (ch<<3)];
      }
#pragma unroll
    for (int ni=0; ni<2; ++ni)
#pragma unroll
      for (int ks=0; ks<2; ++ks) {
        const int col = (wn<<6) + (ni<<4) + r15;
        const int ch = ((ks<<2)+q) ^ (col&7);
        bL[ni*2+ks] = *(const bf16x8*)&Bs[b][(col<<6) + (ch<<3)];
      }
    if (more) { G5_STB(0,nb,k1); G5_STB(2,nb,k1); }
    __builtin_amdgcn_s_setprio(1);
#pragma unroll
    for (int mi=0; mi<2; ++mi)
#pragma unroll
      for (int ni=0; ni<2; ++ni)
#pragma unroll
        for (int ks=0; ks<2; ++ks)
          acc[mi][ni] = __builtin_amdgcn_mfma_f32_16x16x32_bf16(aL[mi*2+ks], bL[ni*2+ks], acc[mi][ni], 0,0,0);
    __builtin_amdgcn_s_setprio(0);
    barrier_();

    // ---- phase 1: (m-lo, n-hi) ----
#pragma unroll
    for (int ni=0; ni<2; ++ni)
#pragma unroll
      for (int ks=0; ks<2; ++ks) {
        const int col = (wn<<6) + ((ni+2)<<4) + r15;
        const int ch = ((ks<<2)+q) ^ (col&7);
        bH[ni*2+ks] = *(const bf16x8*)&Bs[b][(col<<6) + (ch<<3)];
      }
    if (more) { G5_STB(1,nb,k1); G5_STB(3,nb,k1); }
    __builtin_amdgcn_s_setprio(1);
#pragma unroll
    for (int mi=0; mi<2; ++mi)
#pragma unroll
      for (int ni=0; ni<2; ++ni)
#pragma unroll
        for (int ks=0; ks<2; ++ks)
          acc[mi][ni+2] = __builtin_amdgcn_mfma_f32_16x16x32_bf16(aL[mi*2+ks], bH[ni*2+ks], acc[mi][ni+2], 0,0,0);
    __builtin_amdgcn_s_setprio(0);

    // ---- phase 2: (m-hi, n-lo) ----
    if (more) { asm volatile("s_waitcnt vmcnt(4)" ::: "memory"); }
    else      { asm volatile("s_waitcnt vmcnt(0)" ::: "memory"); }
    barrier_();
#pragma unroll
    for (int mi=0; mi<2; ++mi)
#pragma unroll
      for (int ks=0; ks<2; ++ks) {
        const int row = (wm<<6) + ((mi+2)<<4) + r15;
        const int ch = ((ks<<2)+q) ^ (row&7);
        aH[mi*2+ks] = *(const bf16x8*)&As[b][(row<<6) + (ch<<3)];
      }
    if (more) { G5_STA(0,nb,k1); G5_STA(2,nb,k1); }
    __builtin_amdgcn_s_setprio(1);
#pragma unroll
    for (int mi=0; mi<2; ++mi)
#pragma unroll
      for (int ni=0; ni<2; ++ni)
#pragma unroll
        for (int ks=0; ks<2; ++ks)
          acc[mi+2][ni] = __builtin_amdgcn_mfma_f32_16x16x32_bf16(aH[mi*2+ks], bL[ni*2+ks], acc[mi+2][ni], 0,0,0);
    __builtin_amdgcn_s_setprio(0);
    barrier_();

    // ---- phase 3: (m-hi, n-hi) ----
    if (more) { G5_STA(1,nb,k1); G5_STA(3,nb,k1); }
    __builtin_amdgcn_s_setprio(1);
#pragma unroll
    for (int mi=0; mi<2; ++mi)
#pragma unroll
      for (int ni=0; ni<2; ++ni)
#pragma unroll
        for (int ks=0; ks<2; ++ks)
          acc[mi+2][ni+2] = __builtin_amdgcn_mfma_f32_16x16x32_bf16(aH[mi*2+ks], bH[ni*2+ks], acc[mi+2][ni+2], 0,0,0);
    __builtin_amdgcn_s_setprio(0);
  }
#undef G5_STA
#undef G5_STB

#pragma unroll
  for (int ni=0; ni<4; ++ni) {
    const long long n = nBase + (wn<<6) + (ni<<4) + r15;
    const float bval = bias[n];
#pragma unroll
    for (int mi=0; mi<4; ++mi) {
#pragma unroll
      for (int r=0; r<4; ++r) {
        const long long m = mBase + (wm<<6) + (mi<<4) + (q<<2) + r;
        float v = acc[mi][ni][r] + bval;
        if constexpr (ACT==1) v = fmaxf(v, 0.f);
        C[m*(long long)ldc + n] = f2bf(v);
      }
    }
  }
}

// ---------------- gemm4: 256x256 tile, 4-phase counted-vmcnt pipeline ----------------
template<int ACT, bool MOE>
__global__ __launch_bounds__(512,2) void gemm4_k(
    const unsigned short* __restrict__ A, const unsigned short* __restrict__ Bt,
    const float* __restrict__ bias, unsigned short* __restrict__ C,
    const float* __restrict__ w2, float* __restrict__ scp,
    int K, int lda, int ldb, int ldc)
{
  __shared__ unsigned short As[2][16384];
  __shared__ unsigned short Bs[2][16384];
  const int tid = threadIdx.x, lane = tid & 63, wid = tid >> 6;
  const int wm = wid >> 2, wn = wid & 3;
  const int q = lane >> 4, r15 = lane & 15;
  const int nx = gridDim.x;
  const int bid = blockIdx.x + nx*blockIdx.y;
  const int cpx = (nx*gridDim.y) >> 3;
  const int wg = (bid & 7)*cpx + (bid >> 3);
  const long long mBase = (long long)(wg / nx) << 8;
  const long long nBase = (long long)(wg % nx) << 8;

  f32x4 acc[8][4];
#pragma unroll
  for (int i=0;i<8;i++)
#pragma unroll
    for (int j=0;j<4;j++)
#pragma unroll
      for (int r=0;r<4;r++) acc[i][j][r] = 0.f;

  const int NT = K >> 6;

#define G4_STA(j, nb, kk) { const int d_ = tid + ((j)<<9); const int row_ = d_>>3, c_ = d_&7, sc_ = c_ ^ (row_&7); \
    GLD_LDS16(A + (mBase+row_)*(long long)lda + (kk) + (sc_<<3), &As[nb][d_<<3]); }
#define G4_STB(j, nb, kk) { const int d_ = tid + ((j)<<9); const int row_ = d_>>3, c_ = d_&7, sc_ = c_ ^ (row_&7); \
    GLD_LDS16(Bt + (nBase+row_)*(long long)ldb + (kk) + (sc_<<3), &Bs[nb][d_<<3]); }

  G4_STB(0,0,0); G4_STB(1,0,0); G4_STB(2,0,0); G4_STB(3,0,0);
  G4_STA(0,0,0); G4_STA(2,0,0); G4_STA(1,0,0); G4_STA(3,0,0);

  for (int t=0; t<NT; ++t) {
    const int b = t & 1, nb = b ^ 1;
    const bool more = (t+1 < NT);
    const int k1 = (t+1) << 6;
    bf16x8 aF[8], bL[4], bH[4];

    // ---- phase 0 ----
    asm volatile("s_waitcnt vmcnt(2)" ::: "memory");
    barrier_();
#pragma unroll
    for (int mi=0; mi<4; ++mi)
#pragma unroll
      for (int ks=0; ks<2; ++ks) {
        const int row = (wm<<7) + (mi<<4) + r15;
        const int ch = ((ks<<2)+q) ^ (row&7);
        aF[mi*2+ks] = *(const bf16x8*)&As[b][(row<<6) + (ch<<3)];
      }
#pragma unroll
    for (int ni=0; ni<2; ++ni)
#pragma unroll
      for (int ks=0; ks<2; ++ks) {
        const int col = (wn<<6) + (ni<<4) + r15;
        const int ch = ((ks<<2)+q) ^ (col&7);
        bL[ni*2+ks] = *(const bf16x8*)&Bs[b][(col<<6) + (ch<<3)];
      }
    if (more) { G4_STB(0,nb,k1); G4_STB(1,nb,k1); }
    __builtin_amdgcn_s_setprio(1);
#pragma unroll
    for (int mi=0; mi<4; ++mi)
#pragma unroll
      for (int ni=0; ni<2; ++ni)
#pragma unroll
        for (int ks=0; ks<2; ++ks)
          acc[mi][ni] = __builtin_amdgcn_mfma_f32_16x16x32_bf16(aF[mi*2+ks], bL[ni*2+ks], acc[mi][ni], 0,0,0);
    __builtin_amdgcn_s_setprio(0);
    barrier_();

    // ---- phase 1 ----
#pragma unroll
    for (int ni=0; ni<2; ++ni)
#pragma unroll
      for (int ks=0; ks<2; ++ks) {
        const int col = (wn<<6) + ((ni+2)<<4) + r15;
        const int ch = ((ks<<2)+q) ^ (col&7);
        bH[ni*2+ks] = *(const bf16x8*)&Bs[b][(col<<6) + (ch<<3)];
      }
    if (more) { G4_STB(2,nb,k1); G4_STB(3,nb,k1); }
    __builtin_amdgcn_s_setprio(1);
#pragma unroll
    for (int mi=0; mi<4; ++mi)
#pragma unroll
      for (int ni=0; ni<2; ++ni)
#pragma unroll
        for (int ks=0; ks<2; ++ks)
          acc[mi][ni+2] = __builtin_amdgcn_mfma_f32_16x16x32_bf16(aF[mi*2+ks], bH[ni*2+ks], acc[mi][ni+2], 0,0,0);
    __builtin_amdgcn_s_setprio(0);

    // ---- phase 2 ----
    if (more) { asm volatile("s_waitcnt vmcnt(4)" ::: "memory"); }
    else      { asm volatile("s_waitcnt vmcnt(0)" ::: "memory"); }
    barrier_();
#pragma unroll
    for (int mi=0; mi<4; ++mi)
#pragma unroll
      for (int ks=0; ks<2; ++ks) {
        const int row = (wm<<7) + ((mi+4)<<4) + r15;
        const int ch = ((ks<<2)+q) ^ (row&7);
        aF[mi*2+ks] = *(const bf16x8*)&As[b][(row<<6) + (ch<<3)];
      }
    if (more) { G4_STA(0,nb,k1); G4_STA(2,nb,k1); }
    __builtin_amdgcn_s_setprio(1);
#pragma unroll
    for (int mi=0; mi<4; ++mi)
#pragma unroll
      for (int ni=0; ni<2; ++ni)
#pragma unroll
        for (int ks=0; ks<2; ++ks)
          acc[mi+4][ni] = __builtin_amdgcn_mfma_f32_16x16x32_bf16(aF[mi*2+ks], bL[ni*2+ks], acc[mi+4][ni], 0,0,0);
    __builtin_amdgcn_s_setprio(0);
    barrier_();

    // ---- phase 3 ----
    if (more) { G4_STA(1,nb,k1); G4_STA(3,nb,k1); }
    __builtin_amdgcn_s_setprio(1);
#pragma unroll
    for (int mi=0; mi<4; ++mi)
#pragma unroll
      for (int ni=0; ni<2; ++ni)
#pragma unroll
        for (int ks=0; ks<2; ++ks)
          acc[mi+4][ni+2] = __builtin_amdgcn_mfma_f32_16x16x32_bf16(aF[mi*2+ks], bH[ni*2+ks], acc[mi+4][ni+2], 0,0,0);
    __builtin_amdgcn_s_setprio(0);
  }
#undef G4_STA
#undef G4_STB

  if constexpr (MOE) {
    const int e = (int)(nBase >> 8);
#pragma unroll
    for (int mi=0; mi<8; ++mi) {
#pragma unroll
      for (int r=0; r<4; ++r) {
        float p = 0.f;
#pragma unroll
        for (int ni=0; ni<4; ++ni) {
          const int n = (int)nBase + (wn<<6) + (ni<<4) + r15;
          const float v = acc[mi][ni][r] + bias[n];
          const float th = 1.f - 2.f/(__expf(2.f*v) + 1.f);
          p += th * w2[n];
        }
        p += __shfl_xor(p,1,64); p += __shfl_xor(p,2,64);
        p += __shfl_xor(p,4,64); p += __shfl_xor(p,8,64);
        if (r15 == 0) {
          const long long m = mBase + (wm<<7) + (mi<<4) + (q<<2) + r;
          atomicAdd(scp + ((long long)e<<14) + m, p);
        }
      }
    }
  } else {
#pragma unroll
    for (int ni=0; ni<4; ++ni) {
      const long long n = nBase + (wn<<6) + (ni<<4) + r15;
      const float bval = bias[n];
#pragma unroll
      for (int mi=0; mi<8; ++mi) {
#pragma unroll
        for (int r=0; r<4; ++r) {
          const long long m = mBase + (wm<<7) + (mi<<4) + (q<<2) + r;
          float v = acc[mi][ni][r] + bval;
          if constexpr (ACT==1) v = fmaxf(v, 0.f);
          C[m*(long long)ldc + n] = f2bf(v);
        }
      }
    }
  }
}

// ---------------- mega prep: t1 first (long pole), then transposes, then x ----------------
DI void transpose64(const float* __restrict__ src, unsigned short* __restrict__ dst,
                    int K, int N, int Kpad, int k0, int n0, float (*tile)[65], int tid)
{
  const int c = tid & 63, rg = tid >> 6;
#pragma unroll
  for (int j=0;j<16;j++){
    const int r = (j<<2) + rg;
    const int k = k0 + r;
    tile[r][c] = (k < K) ? src[(long long)k*N + n0 + c] : 0.f;
  }
  __syncthreads();
#pragma unroll
  for (int j=0;j<16;j++){
    const int nn = (j<<2) + rg;
    dst[(long long)(n0+nn)*Kpad + k0 + c] = f2bf(tile[c][nn]);
  }
}

__global__ __launch_bounds__(256) void prep_k(
    const float* __restrict__ x, unsigned short* __restrict__ xb,
    const float* __restrict__ enc_w1, unsigned short* __restrict__ w1t,
    const float* __restrict__ enc_w2, unsigned short* __restrict__ w2t,
    const float* __restrict__ enc_w3, const float* __restrict__ q_w,
    const float* __restrict__ k_w, const float* __restrict__ v_w, const float* __restrict__ o_w,
    unsigned short* __restrict__ w3t, unsigned short* __restrict__ qkvw, unsigned short* __restrict__ owt,
    const float* __restrict__ moe_w1, unsigned short* __restrict__ mwt,
    const float* __restrict__ Ew, const float* __restrict__ Fw, float* __restrict__ t1,
    const float* __restrict__ qb, const float* __restrict__ kb, const float* __restrict__ vb,
    float* __restrict__ qkvb)
{
  __shared__ float tile[64][65];
  const int b = blockIdx.x, tid = threadIdx.x;
  if (b < 512) {
    // t1 (latency-bound band reduction) -- 8-way unrolled for MLP
    const int k = b & 255, which = b >> 8, c = tid;
    const float* Wr = (which ? Fw : Ew) + (long long)c*10000;
    const float ksc = 39.0625f, inv = 1.f/39.0625f;
    const float sf = (k + 0.5f)*ksc - 0.5f;
    int ilo = (int)ceilf(sf - ksc); if (ilo < 0) ilo = 0;
    int ihi = (int)floorf(sf + ksc); if (ihi > 9999) ihi = 9999;
    float acc = 0.f, wsum = 0.f;
    int i = ilo;
    for (; i + 8 <= ihi + 1; i += 8) {
      float v[8], w[8];
#pragma unroll
      for (int j=0;j<8;j++) v[j] = Wr[i+j];
#pragma unroll
      for (int j=0;j<8;j++){
        w[j] = fmaxf(1.f - fabsf(sf - (float)(i+j))*inv, 0.f);
        acc += w[j]*v[j]; wsum += w[j];
      }
    }
    for (; i <= ihi; ++i) {
      const float w = fmaxf(1.f - fabsf(sf - (float)i)*inv, 0.f);
      acc += w * Wr[i]; wsum += w;
    }
    t1[(which*256 + k)*256 + c] = acc / wsum;
  } else if (b < 1024) {
    const int bb = b - 512;
    transpose64(enc_w1, w1t, 2000, 1024, 2048, (bb&31)<<6, (bb>>5)<<6, tile, tid);
  } else if (b < 1152) {
    const int bb = b - 1024;
    transpose64(enc_w2, w2t, 1024, 512, 1024, (bb&15)<<6, (bb>>4)<<6, tile, tid);
  } else if (b < 1472) {
    const int bb = b - 1152;
    const int z = bb >> 6, r = bb & 63;
    const float* s = (z==0)?enc_w3:(z==1)?q_w:(z==2)?k_w:(z==3)?v_w:o_w;
    unsigned short* d = (z==0)?w3t:(z==1)?qkvw:(z==2)?(qkvw+512*512):(z==3)?(qkvw+1024*512):owt;
    transpose64(s, d, 512, 512, 512, (r&7)<<6, (r>>3)<<6, tile, tid);
  } else if (b < 1600) {
    const int bb = b - 1472;
    const int z = bb >> 5, r = bb & 31;
    transpose64(moe_w1 + (long long)z*512*256, mwt + (long long)z*256*512,
                512, 256, 512, (r&7)<<6, (r>>3)<<6, tile, tid);
  } else if (b == 1600) {
#pragma unroll
    for (int i=0;i<6;i++){
      const int idx = i*256 + tid;
      const int wq = idx >> 9, off = idx & 511;
      const float* src = (wq==0)?qb:(wq==1)?kb:vb;
      qkvb[idx] = src[off];
    }
  } else {
    // x [16384][2000] f32 -> [16384][2048] bf16: 4 rows/block, 8 loads in flight
    const int bb = b - 1601;
    const long long r0 = (long long)bb << 2;
    const int c = tid;
    if (c < 250) {
      const float* p = x + r0*2000 + c*8;
      float4 fa[4], fb[4];
#pragma unroll
      for (int rr=0; rr<4; ++rr){ fa[rr] = *(const float4*)(p + rr*2000); fb[rr] = *(const float4*)(p + rr*2000 + 4); }
#pragma unroll
      for (int rr=0; rr<4; ++rr){
        bf16x8 v;
        v[0]=(short)f2bf(fa[rr].x); v[1]=(short)f2bf(fa[rr].y); v[2]=(short)f2bf(fa[rr].z); v[3]=(short)f2bf(fa[rr].w);
        v[4]=(short)f2bf(fb[rr].x); v[5]=(short)f2bf(fb[rr].y); v[6]=(short)f2bf(fb[rr].z); v[7]=(short)f2bf(fb[rr].w);
        *(bf16x8*)(xb + (r0+rr)*2048 + (long long)c*8) = v;
      }
    } else {
      bf16x8 z8;
#pragma unroll
      for (int j=0;j<8;j++) z8[j]=0;
#pragma unroll
      for (int rr=0; rr<4; ++rr) *(bf16x8*)(xb + (r0+rr)*2048 + (long long)c*8) = z8;
    }
  }
}

// ---------------- linformer projection helpers ----------------
__global__ __launch_bounds__(512) void red_k(const unsigned short* __restrict__ qkv,
                                             float* __restrict__ red)
{
  const int c = blockIdx.x, which = blockIdx.y, j = threadIdx.x;
  const unsigned short* X = qkv + (which ? 1024 : 512);
  int nlo = 64*c - 32; if (nlo < 0) nlo = 0;
  int nhi = 64*c + 95; if (nhi > 16383) nhi = 16383;
  float acc = 0.f;
  for (int n=nlo; n<=nhi; ++n) {
    float sf = (n + 0.5f)*0.015625f - 0.5f;
    sf = fminf(fmaxf(sf, 0.f), 255.f);
    const int c0 = (int)sf;
    const float f = sf - (float)c0;
    float w = 0.f;
    if (c == c0) w = 1.f - f;
    else if (c == c0+1) w = f;
    if (w != 0.f) acc += w * bf2f(X[(long long)n*1536 + j]);
  }
  red[(which*256 + c)*512 + j] = acc;
}

__global__ __launch_bounds__(512) void kc_k(const float* __restrict__ t1, const float* __restrict__ red,
                                            unsigned short* __restrict__ Kc, unsigned short* __restrict__ Vct)
{
  const int k = blockIdx.x, which = blockIdx.y, j = threadIdx.x;
  const float* T = t1 + (which*256 + k)*256;
  const float* R = red + which*131072;
  float acc = 0.f;
  for (int c=0; c<256; ++c) acc += T[c] * R[c*512 + j];
  const int h = j >> 6, d = j & 63;
  if (which == 0) Kc [(h<<14) + (k<<6) + d] = f2bf(acc);
  else            Vct[(h<<14) + (d<<8) + k] = f2bf(acc);
}

// ---------------- fused linformer attention ----------------
__global__ __launch_bounds__(256) void attn_k(
    const unsigned short* __restrict__ Qg, const unsigned short* __restrict__ Kc,
    const unsigned short* __restrict__ Vct, unsigned short* __restrict__ ao)
{
  __shared__ unsigned short Ks[16384];
  __shared__ unsigned short Vs[16384];
  __shared__ unsigned short Ps[32768];
  const int h = blockIdx.y;
  const long long mBase = (long long)blockIdx.x << 7;
  const int tid = threadIdx.x, lane = tid & 63, wid = tid >> 6;
  const int q = lane >> 4, r15 = lane & 15;

#pragma unroll
  for (int it=0; it<8; ++it) {
    const int dbase = (it<<8) + (wid<<6);
    const int d = dbase + lane;
    {
      const int row = d >> 3, cc = d & 7, sc = cc ^ (row & 7);
      GLD_LDS16(Kc + (h<<14) + (row<<6) + (sc<<3), Ks + (dbase<<3));
    }
    {
      const int row = d >> 5, cc = d & 31, sc = (cc & 24) | ((cc ^ (row & 7)) & 7);
      GLD_LDS16(Vct + (h<<14) + (row<<8) + (sc<<3), Vs + (dbase<<3));
    }
  }
  __syncthreads();

  f32x4 acc[2][16];
#pragma unroll
  for (int mi=0;mi<2;mi++)
#pragma unroll
    for (int ni=0;ni<16;ni++)
#pragma unroll
      for (int r=0;r<4;r++) acc[mi][ni][r] = 0.f;

#pragma unroll
  for (int ks=0; ks<2; ++ks) {
    bf16x8 af[2];
#pragma unroll
    for (int mi=0; mi<2; ++mi) {
      const long long m = mBase + (wid<<5) + (mi<<4) + r15;
      af[mi] = *(const bf16x8*)(Qg + m*1536 + (h<<6) + (ks<<5) + (q<<3));
    }
#pragma unroll
    for (int ni=0; ni<16; ++ni) {
      const int col = (ni<<4) + r15;
      const int ch = ((ks<<2)+q) ^ (col&7);
      const bf16x8 bv = *(const bf16x8*)(Ks + (col<<6) + (ch<<3));
      acc[0][ni] = __builtin_amdgcn_mfma_f32_16x16x32_bf16(af[0], bv, acc[0][ni], 0,0,0);
      acc[1][ni] = __builtin_amdgcn_mfma_f32_16x16x32_bf16(af[1], bv, acc[1][ni], 0,0,0);
    }
  }

#pragma unroll
  for (int mi=0; mi<2; ++mi) {
#pragma unroll
    for (int r=0; r<4; ++r) {
      float mx = -3.4e38f;
#pragma unroll
      for (int ni=0; ni<16; ++ni) mx = fmaxf(mx, acc[mi][ni][r]);
      mx = fmaxf(mx, __shfl_xor(mx,1,64)); mx = fmaxf(mx, __shfl_xor(mx,2,64));
      mx = fmaxf(mx, __shfl_xor(mx,4,64)); mx = fmaxf(mx, __shfl_xor(mx,8,64));
      float s = 0.f;
#pragma unroll
      for (int ni=0; ni<16; ++ni) {
        const float e = __expf((acc[mi][ni][r] - mx)*0.125f);
        acc[mi][ni][r] = e; s += e;
      }
      s += __shfl_xor(s,1,64); s += __shfl_xor(s,2,64);
      s += __shfl_xor(s,4,64); s += __shfl_xor(s,8,64);
      const float inv = 1.f / s;
      const int row = (wid<<5) + (mi<<4) + (q<<2) + r;
#pragma unroll
      for (int ni=0; ni<16; ++ni) {
        const int col = (ni<<4) + r15;
        const int ch = col >> 3;
        const int chs = (ch & 24) | ((ch ^ (row & 7)) & 7);
        Ps[(row<<8) + (chs<<3) + (col&7)] = f2bf(acc[mi][ni][r]*inv);
      }
    }
  }
  __syncthreads();

  f32x4 o[2][4];
#pragma unroll
  for (int mi=0;mi<2;mi++)
#pragma unroll
    for (int ni=0;ni<4;ni++)
#pragma unroll
      for (int r=0;r<4;r++) o[mi][ni][r] = 0.f;

#pragma unroll
  for (int kk=0; kk<8; ++kk) {
    bf16x8 pa[2];
#pragma unroll
    for (int mi=0; mi<2; ++mi) {
      const int row = (wid<<5) + (mi<<4) + r15;
      const int ch = (kk<<2) + q;
      const int chs = (ch & 24) | ((ch ^ (row & 7)) & 7);
      pa[mi] = *(const bf16x8*)(Ps + (row<<8) + (chs<<3));
    }
#pragma unroll
    for (int ni=0; ni<4; ++ni) {
      const int vrow = (ni<<4) + r15;
      const int ch = (kk<<2) + q;
      const int chs = (ch & 24) | ((ch ^ (vrow & 7)) & 7);
      const bf16x8 bv = *(const bf16x8*)(Vs + (vrow<<8) + (chs<<3));
      o[0][ni] = __builtin_amdgcn_mfma_f32_16x16x32_bf16(pa[0], bv, o[0][ni], 0,0,0);
      o[1][ni] = __builtin_amdgcn_mfma_f32_16x16x32_bf16(pa[1], bv, o[1][ni], 0,0,0);
    }
  }
#pragma unroll
  for (int mi=0; mi<2; ++mi)
#pragma unroll
    for (int ni=0; ni<4; ++ni)
#pragma unroll
      for (int r=0; r<4; ++r) {
        const long long m = mBase + (wid<<5) + (mi<<4) + (q<<2) + r;
        ao[m*512 + (h<<6) + (ni<<4) + r15] = f2bf(o[mi][ni][r]);
      }
}

// ---------------- double layernorm (wave-per-row) + column-sum partials + scp zero --------
__global__ __launch_bounds__(256) void ln64_k(
    const unsigned short* __restrict__ attno, const unsigned short* __restrict__ feat,
    const float* __restrict__ g1, const float* __restrict__ b1,
    const float* __restrict__ g2, const float* __restrict__ b2,
    unsigned short* __restrict__ att, float* __restrict__ colp, float* __restrict__ scp)
{
  __shared__ float cred[4][512];
  const int tid = threadIdx.x, lane = tid & 63, wid = tid >> 6;
  const int c0 = lane << 3;
  scp[((long long)blockIdx.x<<8) + tid] = 0.f;
  float g1v[8], b1v[8], g2v[8], b2v[8];
#pragma unroll
  for (int j=0;j<8;j++){ g1v[j]=g1[c0+j]; b1v[j]=b1[c0+j]; g2v[j]=g2[c0+j]; b2v[j]=b2[c0+j]; }
  float cacc[8];
#pragma unroll
  for (int j=0;j<8;j++) cacc[j]=0.f;
  for (int rr=0; rr<16; ++rr) {
    const long long row = ((long long)blockIdx.x<<6) + (rr<<2) + wid;
    const bf16x8 a = *(const bf16x8*)(attno + (row<<9) + c0);
    const bf16x8 f = *(const bf16x8*)(feat  + (row<<9) + c0);
    float xv[8]; float s=0.f, qs=0.f;
#pragma unroll
    for (int j=0;j<8;j++){ xv[j] = bf2f((unsigned short)a[j]) + bf2f((unsigned short)f[j]); s += xv[j]; qs += xv[j]*xv[j]; }
#pragma unroll
    for (int o=32;o;o>>=1){ s += __shfl_xor(s,o,64); qs += __shfl_xor(qs,o,64); }
    float m = s*(1.f/512.f);
    float rs = rsqrtf(qs*(1.f/512.f) - m*m + 1e-5f);
    float y[8]; s=0.f; qs=0.f;
#pragma unroll
    for (int j=0;j<8;j++){ y[j] = (xv[j]-m)*rs*g1v[j] + b1v[j]; s += y[j]; qs += y[j]*y[j]; }
#pragma unroll
    for (int o=32;o;o>>=1){ s += __shfl_xor(s,o,64); qs += __shfl_xor(qs,o,64); }
    m = s*(1.f/512.f);
    rs = rsqrtf(qs*(1.f/512.f) - m*m + 1e-5f);
    bf16x8 ov;
#pragma unroll
    for (int j=0;j<8;j++){ const float z = (y[j]-m)*rs*g2v[j] + b2v[j]; cacc[j] += z; ov[j] = (short)f2bf(z); }
    *(bf16x8*)(att + (row<<9) + c0) = ov;
  }
#pragma unroll
  for (int j=0;j<8;j++) cred[wid][c0+j] = cacc[j];
  __syncthreads();
  {
    const float v0 = cred[0][tid]+cred[1][tid]+cred[2][tid]+cred[3][tid];
    const float v1 = cred[0][tid+256]+cred[1][tid+256]+cred[2][tid+256]+cred[3][tid+256];
    colp[((long long)blockIdx.x<<9)+tid]     = v0;
    colp[((long long)blockIdx.x<<9)+tid+256] = v1;
  }
}

// ---------------- gates / moe stats / bag / classifier ----------------
__global__ __launch_bounds__(512) void meangates_k(const float* __restrict__ part,
    const float* __restrict__ gw, const float* __restrict__ gb, float* __restrict__ gates)
{
  __shared__ float mv[512];
  __shared__ float tmp[4];
  const int t = threadIdx.x;
  float s = 0.f;
  for (int b=0;b<256;b++) s += part[(b<<9)+t];
  mv[t] = s * (1.f/16384.f);
  __syncthreads();
  if (t < 4) {
    float a = gb[t];
    for (int d=0; d<512; ++d) a += mv[d]*gw[d*4+t];
    tmp[t] = a;
  }
  __syncthreads();
  if (t == 0) {
    const float m = fmaxf(fmaxf(tmp[0],tmp[1]),fmaxf(tmp[2],tmp[3]));
    float e[4]; float ss=0.f;
    for (int i=0;i<4;i++){ e[i]=__expf(tmp[i]-m); ss+=e[i]; }
    for (int i=0;i<4;i++) gates[i] = e[i]/ss;
  }
}

__global__ __launch_bounds__(1024) void moestat_k(const float* __restrict__ sc,
                                                  float* __restrict__ mstat, float* __restrict__ sstat)
{
  __shared__ float red[1024];
  const int e = blockIdx.x, t = threadIdx.x;
  const float* p = sc + e*16384;
  float m = -3.4e38f;
  for (int n=t; n<16384; n+=1024) m = fmaxf(m, p[n]);
  red[t] = m; __syncthreads();
  for (int o=512;o;o>>=1){ if (t<o) red[t]=fmaxf(red[t],red[t+o]); __syncthreads(); }
  m = red[0]; __syncthreads();
  float s = 0.f;
  for (int n=t; n<16384; n+=1024) s += __expf(p[n]-m);
  red[t] = s; __syncthreads();
  for (int o=512;o;o>>=1){ if (t<o) red[t]+=red[t+o]; __syncthreads(); }
  if (t==0){ mstat[e]=m; sstat[e]=red[0]; }
}

__global__ __launch_bounds__(256) void wbag_k(const unsigned short* __restrict__ att,
    const float* __restrict__ scp, const float* __restrict__ gates,
    const float* __restrict__ mstat, const float* __restrict__ sstat,
    float* __restrict__ part, float* __restrict__ dout)
{
  __shared__ float wrow[128];
  const int c = threadIdx.x;
  const long long r0 = (long long)blockIdx.x * 128;
  if (c < 128) {
    const long long n = r0 + c;
    float w = 0.f;
#pragma unroll
    for (int e=0;e<4;e++) w += gates[e]*__expf(scp[((long long)e<<14)+n]-mstat[e]) / sstat[e];
    wrow[c] = w;
    dout[514 + n] = w;
  }
  __syncthreads();
  float a0=0.f, a1=0.f;
  for (int r=0;r<128;r++){
    const float w = wrow[r];
    const unsigned short* p = att + ((r0+r)<<9);
    a0 += w*bf2f(p[c]); a1 += w*bf2f(p[c+256]);
  }
  part[((long long)blockIdx.x<<9)+c]     = a0;
  part[((long long)blockIdx.x<<9)+c+256] = a1;
}

__global__ __launch_bounds__(512) void cls2_k(const float* __restrict__ bagp,
    const float* __restrict__ w1, const float* __restrict__ b1,
    const float* __restrict__ w2, const float* __restrict__ b2,
    const float* __restrict__ w3, const float* __restrict__ b3, float* __restrict__ dout)
{
  __shared__ float bag[512]; __shared__ float c1[256]; __shared__ float c2[128];
  const int tid = threadIdx.x;
  float s = 0.f;
  for (int b=0;b<128;b++) s += bagp[(b<<9)+tid];
  bag[tid] = s; dout[tid] = s;
  __syncthreads();
  if (tid < 256) {
    float a = b1[tid];
    for (int d=0; d<512; ++d) a += bag[d]*w1[d*256+tid];
    c1[tid] = fmaxf(a, 0.f);
  }
  __syncthreads();
  if (tid < 128) {
    float a2 = b2[tid];
    for (int d=0; d<256; ++d) a2 += c1[d]*w2[d*128+tid];
    c2[tid] = fmaxf(a2, 0.f);
  }
  __syncthreads();
  if (tid < 2) {
    float a3 = b3[tid];
    for (int d=0; d<128; ++d) a3 += c2[d]*w3[d*2+tid];
    dout[512 + tid] = a3;
  }
}

extern "C" void kernel_launch(void* const* d_in, const int* in_sizes, int n_in,
                              void* d_out, int out_size, void* d_ws, size_t ws_size,
                              hipStream_t stream)
{
  (void)in_sizes; (void)n_in; (void)out_size; (void)ws_size;
  const float* x      = (const float*)d_in[0];
  const float* enc_w1 = (const float*)d_in[1];
  const float* enc_b1 = (const float*)d_in[2];
  const float* enc_w2 = (const float*)d_in[3];
  const float* enc_b2 = (const float*)d_in[4];
  const float* enc_w3 = (const float*)d_in[5];
  const float* enc_b3 = (const float*)d_in[6];
  const float* q_w    = (const float*)d_in[7];
  const float* q_b    = (const float*)d_in[8];
  const float* k_w    = (const float*)d_in[9];
  const float* k_b    = (const float*)d_in[10];
  const float* v_w    = (const float*)d_in[11];
  const float* v_b    = (const float*)d_in[12];
  const float* o_w    = (const float*)d_in[13];
  const float* o_b    = (const float*)d_in[14];
  const float* E_w    = (const float*)d_in[15];
  const float* F_w    = (const float*)d_in[16];
  const float* ln1_g  = (const float*)d_in[17];
  const float* ln1_b  = (const float*)d_in[18];
  const float* ln2_g  = (const float*)d_in[19];
  const float* ln2_b  = (const float*)d_in[20];
  const float* gate_w = (const float*)d_in[21];
  const float* gate_b = (const float*)d_in[22];
  const float* moe_w1 = (const float*)d_in[23];
  const float* moe_b1 = (const float*)d_in[24];
  const float* moe_w2 = (const float*)d_in[25];
  // d_in[26] = moe_b2: drops out of the row-softmax (shift invariance)
  const float* cls_w1 = (const float*)d_in[27];
  const float* cls_b1 = (const float*)d_in[28];
  const float* cls_w2 = (const float*)d_in[29];
  const float* cls_b2 = (const float*)d_in[30];
  const float* cls_w3 = (const float*)d_in[31];
  const float* cls_b3 = (const float*)d_in[32];

  char* ws = (char*)d_ws;
  const size_t MB = 1024*1024;
  unsigned short* x_bf  = (unsigned short*)(ws + 0);          // [16384][2048]  64MB
  unsigned short* h1    = (unsigned short*)(ws + 64*MB);      // [16384][1024]  32MB
  unsigned short* h2    = (unsigned short*)(ws + 0);          // 16MB (x_bf dead)
  unsigned short* feat  = (unsigned short*)(ws + 16*MB);      // 16MB
  unsigned short* qkv   = (unsigned short*)(ws + 32*MB);      // [16384][1536]  48MB (h1 dead)
  unsigned short* ao    = (unsigned short*)(ws + 80*MB);      // 16MB
  unsigned short* attno = (unsigned short*)(ws + 0);          // 16MB (h2 dead)
  unsigned short* att   = (unsigned short*)(ws + 96*MB);      // 16MB
  unsigned short* w1t   = (unsigned short*)(ws + 112*MB);                 // [1024][2048] 4MB
  unsigned short* w2t   = (unsigned short*)(ws + 116*MB);                 // 1MB
  unsigned short* w3t   = (unsigned short*)(ws + 117*MB);                 // 0.5MB
  unsigned short* qkvw  = (unsigned short*)(ws + 117*MB + 512*1024);      // 1.5MB
  unsigned short* owt   = (unsigned short*)(ws + 119*MB);                 // 0.5MB
  unsigned short* mwt   = (unsigned short*)(ws + 119*MB + 512*1024);      // 1MB
  float*  t1b   = (float*)(ws + 120*MB + 512*1024);                       // 0.5MB
  float*  redb  = (float*)(ws + 121*MB);                                  // 1MB
  unsigned short* Kcbf  = (unsigned short*)(ws + 122*MB);                 // 256KB
  unsigned short* Vctbf = (unsigned short*)(ws + 122*MB + 256*1024);      // 256KB
  float*  colp  = (float*)(ws + 122*MB + 512*1024);                       // [256][512] 512KB
  float*  bagp  = (float*)(ws + 123*MB);                                  // [128][512] 256KB
  float*  qkvb  = (float*)(ws + 123*MB + 256*1024);                       // 6KB
  float*  gatesp= (float*)(ws + 123*MB + 264*1024);
  float*  scp   = (float*)(ws + 123*MB + 268*1024);                       // [4][16384] 256KB
  float*  mstat = (float*)(ws + 123*MB + 524*1024);
  float*  sstat = (float*)(ws + 123*MB + 524*1024 + 64);
  float*  dout  = (float*)d_out;

  // ---- mega prep (t1 first = long pole; x conversion last) ----
  prep_k<<<5697,256,0,stream>>>(x, x_bf, enc_w1, w1t, enc_w2, w2t,
                                enc_w3, q_w, k_w, v_w, o_w, w3t, qkvw, owt,
                                moe_w1, mwt, E_w, F_w, t1b, q_b, k_b, v_b, qkvb);

  // ---- encoder ----
  gemm4_k<1,false><<<dim3(4,64,1),512,0,stream>>>(x_bf, w1t, enc_b1, h1, nullptr,nullptr, 2048,2048,2048,1024);
  gemm5_k<1><<<dim3(4,128,1),256,0,stream>>>(h1, w2t, enc_b2, h2,   1024,1024,1024, 512);
  gemm5_k<1><<<dim3(4,128,1),256,0,stream>>>(h2, w3t, enc_b3, feat,  512, 512, 512, 512);
  // ---- QKV (merged, N=1536) ----
  gemm5_k<0><<<dim3(12,128,1),256,0,stream>>>(feat, qkvw, qkvb, qkv, 512,512,512,1536);
  // ---- linformer projections ----
  red_k<<<dim3(256,2),512,0,stream>>>(qkv, redb);
  kc_k <<<dim3(256,2),512,0,stream>>>(t1b, redb, Kcbf, Vctbf);
  // ---- fused attention ----
  attn_k<<<dim3(128,8),256,0,stream>>>(qkv, Kcbf, Vctbf, ao);
  // ---- output projection + residual + double LN (+ colsum partials + scp zero) ----
  gemm5_k<0><<<dim3(4,128,1),256,0,stream>>>(ao, owt, o_b, attno, 512,512,512,512);
  ln64_k<<<256,256,0,stream>>>(attno, feat, ln1_g, ln1_b, ln2_g, ln2_b, att, colp, scp);
  meangates_k<<<1,512,0,stream>>>(colp, gate_w, gate_b, gatesp);
  // ---- MoE expert attention: ONE merged N=1024 GEMM, tanh+dot fused in epilogue ----
  gemm4_k<0,true><<<dim3(4,64,1),512,0,stream>>>(att, mwt, moe_b1, nullptr, moe_w2, scp, 512,512,512,0);
  moestat_k<<<4,1024,0,stream>>>(scp, mstat, sstat);
  // ---- attn weights + bag partials (fused) + classifier ----
  wbag_k<<<128,256,0,stream>>>(att, scp, gatesp, mstat, sstat, bagp, dout);
  cls2_k<<<1,512,0,stream>>>(bagp, cls_w1, cls_b1, cls_w2, cls_b2, cls_w3, cls_b3, dout);
}